// Round 4
// baseline (932.373 us; speedup 1.0000x reference)
//
#include <hip/hip_runtime.h>

#define IN_SIZE 256
#define HIDDEN 16
#define OUT_SIZE 64
#define NBUCK 512      // buckets; bucket = row >> 8 (256 rows each, n <= 131072)
#define BSHIFT 8
#define EB 4096        // edges per bin block
#define EBH 16384      // edges per bhist block

// ---------------- zero ----------------
__global__ __launch_bounds__(256) void zero_int_kernel(int* __restrict__ a, long n) {
    long i = (long)blockIdx.x * 256 + threadIdx.x;
    long stride = (long)gridDim.x * 256;
    for (; i < n; i += stride) a[i] = 0;
}

// ---------------- H1 = X @ W1^T + b1  [n,16] ----------------
__global__ __launch_bounds__(256) void dense1_kernel(
    const float* __restrict__ X, const float* __restrict__ W1,
    const float* __restrict__ b1, float* __restrict__ H1, int n) {
    __shared__ float w[HIDDEN * IN_SIZE];  // w[k*16 + h] = W1[h][k]
    for (int i = threadIdx.x; i < HIDDEN * IN_SIZE; i += 256) {
        int h = i >> 8;
        int k = i & 255;
        w[k * HIDDEN + h] = W1[i];
    }
    __syncthreads();
    int t = threadIdx.x;
    int node = blockIdx.x * 16 + (t >> 4);
    int h = t & 15;
    if (node >= n) return;
    const float4* xr = reinterpret_cast<const float4*>(X + (size_t)node * IN_SIZE);
    float acc = b1[h];
#pragma unroll 8
    for (int kk = 0; kk < IN_SIZE / 4; ++kk) {
        float4 x = xr[kk];
        const float* wr = &w[(kk * 4) * HIDDEN + h];
        acc += x.x * wr[0 * HIDDEN] + x.y * wr[1 * HIDDEN] +
               x.z * wr[2 * HIDDEN] + x.w * wr[3 * HIDDEN];
    }
    H1[(size_t)node * HIDDEN + h] = acc;
}

// ---------------- bucket histogram (LDS-merged) ----------------
__global__ __launch_bounds__(256) void bhist_kernel(
    const int* __restrict__ row, int* __restrict__ bcnt, long nedges) {
    __shared__ int bh[NBUCK];
    for (int i = threadIdx.x; i < NBUCK; i += 256) bh[i] = 0;
    __syncthreads();
    long base = (long)blockIdx.x * EBH;
    long end = base + EBH;
    if (end > nedges) end = nedges;
    for (long e = base + threadIdx.x; e < end; e += 256)
        atomicAdd(&bh[row[e] >> BSHIFT], 1);
    __syncthreads();
    for (int i = threadIdx.x; i < NBUCK; i += 256)
        if (bh[i]) atomicAdd(&bcnt[i], bh[i]);
}

// ---------------- bucket exclusive scan -> bstart (fixed) + bcur (cursor) ---
__global__ __launch_bounds__(512) void bucket_scan_kernel(
    const int* __restrict__ bcnt, int* __restrict__ bstart,
    int* __restrict__ bcur, long nedges) {
    __shared__ int s[NBUCK];
    int tid = threadIdx.x;
    int x = bcnt[tid];
    s[tid] = x;
    __syncthreads();
    for (int off = 1; off < NBUCK; off <<= 1) {
        int t = (tid >= off) ? s[tid - off] : 0;
        __syncthreads();
        s[tid] += t;
        __syncthreads();
    }
    int e = s[tid] - x;  // exclusive
    bstart[tid] = e;
    bcur[tid] = e;
    if (tid == NBUCK - 1) bstart[NBUCK] = (int)nedges;
}

// ---------------- bin edges bucket-major (12-B records, coalesced runs) -----
__global__ __launch_bounds__(256) void bin_kernel(
    const int* __restrict__ row, const int* __restrict__ col,
    const float* __restrict__ val, int* __restrict__ bcur,
    int* __restrict__ bin, long nedges) {
    __shared__ int hist[NBUCK];
    __shared__ int cnt2[NBUCK];
    __shared__ int lbase[NBUCK];
    __shared__ int shiftd[NBUCK];
    __shared__ int s[256];
    __shared__ int staged[EB * 3];
    long base = (long)blockIdx.x * EB;
    int ecount = (int)((nedges - base < (long)EB) ? (nedges - base) : (long)EB);
    int tid = threadIdx.x;
    for (int i = tid; i < NBUCK; i += 256) { hist[i] = 0; cnt2[i] = 0; }
    __syncthreads();
    // A: count buckets in this block
    for (int k = tid; k < ecount; k += 256)
        atomicAdd(&hist[row[base + k] >> BSHIFT], 1);
    __syncthreads();
    // scan 512 buckets with 256 threads (pairwise)
    int a = hist[2 * tid], b = hist[2 * tid + 1];
    int ps = a + b;
    s[tid] = ps;
    __syncthreads();
    for (int off = 1; off < 256; off <<= 1) {
        int t = (tid >= off) ? s[tid - off] : 0;
        __syncthreads();
        s[tid] += t;
        __syncthreads();
    }
    int excl = s[tid] - ps;
    lbase[2 * tid] = excl;
    lbase[2 * tid + 1] = excl + a;
    // reserve global space per bucket
    if (a > 0) {
        int g = atomicAdd(&bcur[2 * tid], a);
        shiftd[2 * tid] = 3 * (g - excl);
    }
    if (b > 0) {
        int g = atomicAdd(&bcur[2 * tid + 1], b);
        shiftd[2 * tid + 1] = 3 * (g - (excl + a));
    }
    __syncthreads();
    // B: stage bucket-major in LDS
    for (int k = tid; k < ecount; k += 256) {
        long e = base + k;
        int r = row[e];
        int bb = r >> BSHIFT;
        int p = lbase[bb] + atomicAdd(&cnt2[bb], 1);
        staged[3 * p]     = r;
        staged[3 * p + 1] = col[e];
        staged[3 * p + 2] = __float_as_int(val[e]);
    }
    __syncthreads();
    // C: copy LDS -> global at reserved offsets (runs of ~8 edges = 96 B)
    int nd = 3 * ecount;
    for (int j = tid; j < nd; j += 256) {
        int i = j / 3;
        int bb = staged[3 * i] >> BSHIFT;
        bin[(long)j + shiftd[bb]] = staged[j];
    }
}

// ---------------- spmm over one bucket: LDS accumulators, no row sort -------
// block b owns rows [b*256, b*256+256); 1024 threads: 64 edges x 16 feats/iter
__global__ __launch_bounds__(1024) void spmm_bucket_kernel(
    const int* __restrict__ bin, const int* __restrict__ bstart,
    const float* __restrict__ Hin, float* __restrict__ Sout,
    float* __restrict__ deg, int n, int relu_out) {
    __shared__ float acc[256 * 17];  // padded: row stride 17 banks
    __shared__ float dacc[256];
    int b = blockIdx.x, tid = threadIdx.x;
    int r0 = b << BSHIFT;
    for (int i = tid; i < 256 * 17; i += 1024) acc[i] = 0.f;
    if (tid < 256) dacc[tid] = 0.f;
    __syncthreads();
    int e0 = bstart[b], e1 = bstart[b + 1];
    int k = tid & 15, j = tid >> 4;
    for (int e = e0 + j; e < e1; e += 64) {
        int r = bin[3 * e];          // 16 lanes broadcast
        int c = bin[3 * e + 1];
        float v = __int_as_float(bin[3 * e + 2]);
        float x = Hin[((size_t)c << 4) + k];   // one 64-B line per edge
        atomicAdd(&acc[(r - r0) * 17 + k], v * x);
        if (k == 0) atomicAdd(&dacc[r - r0], v);
    }
    __syncthreads();
    int rows = n - r0;
    if (rows > 256) rows = 256;
    for (int i = tid; i < rows * 16; i += 1024) {
        float x = acc[(i >> 4) * 17 + (i & 15)];
        Sout[((size_t)r0 << 4) + i] = relu_out ? fmaxf(x, 0.f) : x;
    }
    if (deg != nullptr)
        for (int i = tid; i < rows; i += 1024) deg[r0 + i] = dacc[i];
}

// ---------------- atomic push spmm (fallback only) ----------------
__global__ __launch_bounds__(256) void spmm16_kernel(
    const int* __restrict__ row, const int* __restrict__ col,
    const float* __restrict__ val, const float* __restrict__ Hin,
    float* __restrict__ Sout, float* __restrict__ deg, long nedges, int relu_in) {
    long t = (long)blockIdx.x * 256 + threadIdx.x;
    long e = t >> 4;
    if (e >= nedges) return;
    int k = (int)(t & 15);
    int r = row[e];
    int c = col[e];
    float v = val[e];
    float x = Hin[(size_t)c * HIDDEN + k];
    if (relu_in) x = fmaxf(x, 0.0f);
    atomicAdd(&Sout[(size_t)r * HIDDEN + k], v * x);
    if (deg != nullptr && k == 0) atomicAdd(&deg[r], v);
}

// ---------------- out = relu(T @ W2^T + deg*b2)  [n,64] ----------------
__global__ __launch_bounds__(256) void dense2_kernel(
    const float* __restrict__ T, const float* __restrict__ deg,
    const float* __restrict__ W2, const float* __restrict__ b2,
    float* __restrict__ out, int n) {
    __shared__ float w[OUT_SIZE * HIDDEN];
    for (int i = threadIdx.x; i < OUT_SIZE * HIDDEN; i += 256) {
        int o = i / HIDDEN;
        int h = i % HIDDEN;
        w[h * OUT_SIZE + o] = W2[i];
    }
    __syncthreads();
    int node = blockIdx.x * 4 + (threadIdx.x >> 6);
    int o = threadIdx.x & 63;
    if (node >= n) return;
    float acc = deg[node] * b2[o];
#pragma unroll
    for (int h = 0; h < HIDDEN; ++h)
        acc += T[(size_t)node * HIDDEN + h] * w[h * OUT_SIZE + o];
    out[(size_t)node * OUT_SIZE + o] = fmaxf(acc, 0.0f);
}

static inline char* align_up(char* p, size_t a) {
    return (char*)(((uintptr_t)p + a - 1) & ~(uintptr_t)(a - 1));
}

extern "C" void kernel_launch(void* const* d_in, const int* in_sizes, int n_in,
                              void* d_out, int out_size, void* d_ws, size_t ws_size,
                              hipStream_t stream) {
    const int*   index = (const int*)d_in[0];
    const float* value = (const float*)d_in[1];
    const float* X     = (const float*)d_in[4];
    const float* W1    = (const float*)d_in[5];
    const float* b1    = (const float*)d_in[6];
    const float* W2    = (const float*)d_in[7];
    const float* b2    = (const float*)d_in[8];
    float* out = (float*)d_out;

    long nedges = in_sizes[1];
    int  n      = in_sizes[4] / IN_SIZE;
    const int* row = index;
    const int* col = index + nedges;

    size_t need = (size_t)nedges * 12 + (size_t)(3 * NBUCK + 1) * 4 +
                  ((size_t)n * 2 * HIDDEN + n) * 4 + 1024;

    if (ws_size >= need && n <= (NBUCK << BSHIFT)) {
        char* p = (char*)d_ws;
        int* bin    = (int*)p;   p += (size_t)nedges * 12;
        int* bcnt   = (int*)p;   p += NBUCK * 4;
        int* bstart = (int*)p;   p += (NBUCK + 1) * 4;
        int* bcur   = (int*)p;   p += NBUCK * 4;
        p = align_up(p, 64);
        float* H1  = (float*)p;  p += (size_t)n * HIDDEN * 4;  // reused as T
        float* A   = (float*)p;  p += (size_t)n * HIDDEN * 4;  // relu(S1)
        float* deg = (float*)p;

        int nbuck_used = (n + 255) >> BSHIFT;

        zero_int_kernel<<<1, 256, 0, stream>>>(bcnt, NBUCK);
        bhist_kernel<<<(int)((nedges + EBH - 1) / EBH), 256, 0, stream>>>(row, bcnt, nedges);
        bucket_scan_kernel<<<1, NBUCK, 0, stream>>>(bcnt, bstart, bcur, nedges);
        bin_kernel<<<(int)((nedges + EB - 1) / EB), 256, 0, stream>>>(
            row, col, value, bcur, bin, nedges);

        dense1_kernel<<<(n + 15) / 16, 256, 0, stream>>>(X, W1, b1, H1, n);

        // pass 1: A = relu(spmm(H1)), deg
        spmm_bucket_kernel<<<nbuck_used, 1024, 0, stream>>>(bin, bstart, H1, A, deg, n, 1);
        // pass 2: T = spmm(A)  (reuse H1 buffer)
        float* T = H1;
        spmm_bucket_kernel<<<nbuck_used, 1024, 0, stream>>>(bin, bstart, A, T, nullptr, n, 0);

        dense2_kernel<<<(n + 3) / 4, 256, 0, stream>>>(T, deg, W2, b2, out, n);
    } else {
        // atomic push fallback
        float* ws = (float*)d_ws;
        float* H1  = ws;
        float* S1  = H1 + (size_t)n * HIDDEN;
        float* T   = S1 + (size_t)n * HIDDEN;
        float* deg = T + (size_t)n * HIDDEN;
        zero_int_kernel<<<2048, 256, 0, stream>>>((int*)S1, (long)n * (2 * HIDDEN + 1));
        dense1_kernel<<<(n + 15) / 16, 256, 0, stream>>>(X, W1, b1, H1, n);
        long thr1 = nedges * HIDDEN;
        spmm16_kernel<<<(int)((thr1 + 255) / 256), 256, 0, stream>>>(
            row, col, value, H1, S1, deg, nedges, 0);
        spmm16_kernel<<<(int)((thr1 + 255) / 256), 256, 0, stream>>>(
            row, col, value, S1, T, nullptr, nedges, 1);
        dense2_kernel<<<(n + 3) / 4, 256, 0, stream>>>(T, deg, W2, b2, out, n);
    }
}

// Round 5
// 865.854 us; speedup vs baseline: 1.0768x; 1.0768x over previous
//
#include <hip/hip_runtime.h>
#include <hip/hip_fp16.h>

#define IN_SIZE 256
#define HIDDEN 16
#define OUT_SIZE 64
#define NBUCK 512      // bucket = row >> 8 (256 rows each, n <= 131072)
#define BSHIFT 8
#define EB 4096        // edges per bin block
#define EBH 8192       // edges per bhist block

// ---------------- zero ----------------
__global__ __launch_bounds__(256) void zero_int_kernel(int* __restrict__ a, long n) {
    long i = (long)blockIdx.x * 256 + threadIdx.x;
    long stride = (long)gridDim.x * 256;
    for (; i < n; i += stride) a[i] = 0;
}

// ---------------- H1(fp16) = X @ W1^T + b1  [n,16] ----------------
// 256 thr -> 32 nodes x 8 feature-pairs; stores __half2 (coalesced 4B/lane)
__global__ __launch_bounds__(256) void dense1_half_kernel(
    const float* __restrict__ X, const float* __restrict__ W1,
    const float* __restrict__ b1, __half2* __restrict__ H1, int n) {
    __shared__ float w[IN_SIZE * HIDDEN];  // w[k*16+h] = W1[h][k]
    for (int i = threadIdx.x; i < HIDDEN * IN_SIZE; i += 256) {
        int h = i >> 8;
        int k = i & 255;
        w[k * HIDDEN + h] = W1[i];
    }
    __syncthreads();
    int node = blockIdx.x * 32 + (threadIdx.x >> 3);
    int hp = threadIdx.x & 7;
    if (node >= n) return;
    const float4* xr = reinterpret_cast<const float4*>(X + (size_t)node * IN_SIZE);
    float a0 = b1[2 * hp], a1 = b1[2 * hp + 1];
#pragma unroll 8
    for (int kk = 0; kk < IN_SIZE / 4; ++kk) {
        float4 x = xr[kk];
        const float* w0 = &w[(4 * kk) * HIDDEN + 2 * hp];
        a0 += x.x * w0[0] + x.y * w0[HIDDEN] + x.z * w0[2 * HIDDEN] + x.w * w0[3 * HIDDEN];
        a1 += x.x * w0[1] + x.y * w0[HIDDEN + 1] + x.z * w0[2 * HIDDEN + 1] + x.w * w0[3 * HIDDEN + 1];
    }
    H1[(size_t)node * 8 + hp] = __floats2half2_rn(a0, a1);
}

// ---------------- fp32 dense1 (fallback path only) ----------------
__global__ __launch_bounds__(256) void dense1_kernel(
    const float* __restrict__ X, const float* __restrict__ W1,
    const float* __restrict__ b1, float* __restrict__ H1, int n) {
    __shared__ float w[HIDDEN * IN_SIZE];
    for (int i = threadIdx.x; i < HIDDEN * IN_SIZE; i += 256) {
        int h = i >> 8;
        int k = i & 255;
        w[k * HIDDEN + h] = W1[i];
    }
    __syncthreads();
    int t = threadIdx.x;
    int node = blockIdx.x * 16 + (t >> 4);
    int h = t & 15;
    if (node >= n) return;
    const float4* xr = reinterpret_cast<const float4*>(X + (size_t)node * IN_SIZE);
    float acc = b1[h];
#pragma unroll 8
    for (int kk = 0; kk < IN_SIZE / 4; ++kk) {
        float4 x = xr[kk];
        const float* wr = &w[(kk * 4) * HIDDEN + h];
        acc += x.x * wr[0] + x.y * wr[HIDDEN] + x.z * wr[2 * HIDDEN] + x.w * wr[3 * HIDDEN];
    }
    H1[(size_t)node * HIDDEN + h] = acc;
}

// ---------------- bucket histogram (LDS-merged) ----------------
__global__ __launch_bounds__(256) void bhist_kernel(
    const int* __restrict__ row, int* __restrict__ bcnt, long nedges) {
    __shared__ int bh[NBUCK];
    for (int i = threadIdx.x; i < NBUCK; i += 256) bh[i] = 0;
    __syncthreads();
    long base = (long)blockIdx.x * EBH;
    long end = base + EBH;
    if (end > nedges) end = nedges;
    for (long e = base + threadIdx.x; e < end; e += 256)
        atomicAdd(&bh[row[e] >> BSHIFT], 1);
    __syncthreads();
    for (int i = threadIdx.x; i < NBUCK; i += 256)
        if (bh[i]) atomicAdd(&bcnt[i], bh[i]);
}

// ---------------- bucket exclusive scan ----------------
__global__ __launch_bounds__(512) void bucket_scan_kernel(
    const int* __restrict__ bcnt, int* __restrict__ bstart,
    int* __restrict__ bcur, long nedges) {
    __shared__ int s[NBUCK];
    int tid = threadIdx.x;
    int x = bcnt[tid];
    s[tid] = x;
    __syncthreads();
    for (int off = 1; off < NBUCK; off <<= 1) {
        int t = (tid >= off) ? s[tid - off] : 0;
        __syncthreads();
        s[tid] += t;
        __syncthreads();
    }
    int e = s[tid] - x;
    bstart[tid] = e;
    bcur[tid] = e;
    if (tid == NBUCK - 1) bstart[NBUCK] = (int)nedges;
}

// ---------------- bin edges bucket-major, 8-B records ----------------
// record: x = (local_row<<24)|col, y = val bits
__global__ __launch_bounds__(256) void bin_kernel(
    const int* __restrict__ row, const int* __restrict__ col,
    const float* __restrict__ val, int* __restrict__ bcur,
    unsigned int* __restrict__ bin, long nedges) {
    __shared__ int hist[NBUCK];
    __shared__ int cnt2[NBUCK];
    __shared__ int lbase[NBUCK];
    __shared__ int shiftd[NBUCK];
    __shared__ int s[256];
    __shared__ unsigned int staged[EB * 2];
    __shared__ unsigned short sbuck[EB];
    long base = (long)blockIdx.x * EB;
    int ecount = (int)((nedges - base < (long)EB) ? (nedges - base) : (long)EB);
    int tid = threadIdx.x;
    for (int i = tid; i < NBUCK; i += 256) { hist[i] = 0; cnt2[i] = 0; }
    __syncthreads();
    for (int k = tid; k < ecount; k += 256)
        atomicAdd(&hist[row[base + k] >> BSHIFT], 1);
    __syncthreads();
    // pairwise scan of 512 buckets with 256 threads
    int a = hist[2 * tid], b = hist[2 * tid + 1];
    int ps = a + b;
    s[tid] = ps;
    __syncthreads();
    for (int off = 1; off < 256; off <<= 1) {
        int t = (tid >= off) ? s[tid - off] : 0;
        __syncthreads();
        s[tid] += t;
        __syncthreads();
    }
    int excl = s[tid] - ps;
    lbase[2 * tid] = excl;
    lbase[2 * tid + 1] = excl + a;
    if (a > 0) {
        int g = atomicAdd(&bcur[2 * tid], a);
        shiftd[2 * tid] = 2 * (g - excl);
    }
    if (b > 0) {
        int g = atomicAdd(&bcur[2 * tid + 1], b);
        shiftd[2 * tid + 1] = 2 * (g - (excl + a));
    }
    __syncthreads();
    // stage bucket-major in LDS
    for (int k = tid; k < ecount; k += 256) {
        long e = base + k;
        int r = row[e];
        int bb = r >> BSHIFT;
        int p = lbase[bb] + atomicAdd(&cnt2[bb], 1);
        staged[2 * p]     = ((unsigned int)(r & 255) << 24) | (unsigned int)col[e];
        staged[2 * p + 1] = __float_as_uint(val[e]);
        sbuck[p] = (unsigned short)bb;
    }
    __syncthreads();
    // copy to global at reserved offsets
    int nd = 2 * ecount;
    for (int j = tid; j < nd; j += 256) {
        int bb = sbuck[j >> 1];
        bin[(long)j + shiftd[bb]] = staged[j];
    }
}

// ---------------- spmm over one bucket, fp16 gather, LDS fp32 acc ----------
// 1024 thr: 128 edges x 8 feature-pairs per iteration
__global__ __launch_bounds__(1024) void spmm_bucket_h_kernel(
    const uint2* __restrict__ bin, const int* __restrict__ bstart,
    const __half2* __restrict__ Hin, void* __restrict__ Sout,
    float* __restrict__ deg, int n, int relu_out, int out_half) {
    __shared__ float acc[256 * 17];  // row stride 17 banks
    __shared__ float dacc[256];
    int b = blockIdx.x, tid = threadIdx.x;
    int r0 = b << BSHIFT;
    for (int i = tid; i < 256 * 17; i += 1024) acc[i] = 0.f;
    if (tid < 256) dacc[tid] = 0.f;
    __syncthreads();
    int e0 = bstart[b], e1 = bstart[b + 1];
    int kp = tid & 7, j = tid >> 3;
    for (int e = e0 + j; e < e1; e += 128) {
        uint2 rec = bin[e];              // 8 lanes broadcast
        int lr = rec.x >> 24;
        int c  = rec.x & 0xFFFFFF;
        float v = __uint_as_float(rec.y);
        float2 x = __half22float2(Hin[(size_t)c * 8 + kp]);  // 32B/edge, L2-resident
        atomicAdd(&acc[lr * 17 + 2 * kp], v * x.x);
        atomicAdd(&acc[lr * 17 + 2 * kp + 1], v * x.y);
        if (deg != nullptr && kp == 0) atomicAdd(&dacc[lr], v);
    }
    __syncthreads();
    int rows = n - r0;
    if (rows > 256) rows = 256;
    if (out_half) {
        __half2* O = (__half2*)Sout + (size_t)r0 * 8;
        for (int i = tid; i < rows * 8; i += 1024) {
            float f0 = acc[(i >> 3) * 17 + 2 * (i & 7)];
            float f1 = acc[(i >> 3) * 17 + 2 * (i & 7) + 1];
            if (relu_out) { f0 = fmaxf(f0, 0.f); f1 = fmaxf(f1, 0.f); }
            O[i] = __floats2half2_rn(f0, f1);
        }
    } else {
        float* O = (float*)Sout + (size_t)r0 * 16;
        for (int i = tid; i < rows * 16; i += 1024) {
            float f = acc[(i >> 4) * 17 + (i & 15)];
            O[i] = relu_out ? fmaxf(f, 0.f) : f;
        }
    }
    if (deg != nullptr)
        for (int i = tid; i < rows; i += 1024) deg[r0 + i] = dacc[i];
}

// ---------------- atomic push spmm (fallback only) ----------------
__global__ __launch_bounds__(256) void spmm16_kernel(
    const int* __restrict__ row, const int* __restrict__ col,
    const float* __restrict__ val, const float* __restrict__ Hin,
    float* __restrict__ Sout, float* __restrict__ deg, long nedges, int relu_in) {
    long t = (long)blockIdx.x * 256 + threadIdx.x;
    long e = t >> 4;
    if (e >= nedges) return;
    int k = (int)(t & 15);
    int r = row[e];
    int c = col[e];
    float v = val[e];
    float x = Hin[(size_t)c * HIDDEN + k];
    if (relu_in) x = fmaxf(x, 0.0f);
    atomicAdd(&Sout[(size_t)r * HIDDEN + k], v * x);
    if (deg != nullptr && k == 0) atomicAdd(&deg[r], v);
}

// ---------------- out = relu(T @ W2^T + deg*b2)  [n,64] ----------------
__global__ __launch_bounds__(256) void dense2_kernel(
    const float* __restrict__ T, const float* __restrict__ deg,
    const float* __restrict__ W2, const float* __restrict__ b2,
    float* __restrict__ out, int n) {
    __shared__ float w[OUT_SIZE * HIDDEN];
    for (int i = threadIdx.x; i < OUT_SIZE * HIDDEN; i += 256) {
        int o = i / HIDDEN;
        int h = i % HIDDEN;
        w[h * OUT_SIZE + o] = W2[i];
    }
    __syncthreads();
    int node = blockIdx.x * 4 + (threadIdx.x >> 6);
    int o = threadIdx.x & 63;
    if (node >= n) return;
    float acc = deg[node] * b2[o];
#pragma unroll
    for (int h = 0; h < HIDDEN; ++h)
        acc += T[(size_t)node * HIDDEN + h] * w[h * OUT_SIZE + o];
    out[(size_t)node * OUT_SIZE + o] = fmaxf(acc, 0.0f);
}

static inline char* align_up(char* p, size_t a) {
    return (char*)(((uintptr_t)p + a - 1) & ~(uintptr_t)(a - 1));
}

extern "C" void kernel_launch(void* const* d_in, const int* in_sizes, int n_in,
                              void* d_out, int out_size, void* d_ws, size_t ws_size,
                              hipStream_t stream) {
    const int*   index = (const int*)d_in[0];
    const float* value = (const float*)d_in[1];
    const float* X     = (const float*)d_in[4];
    const float* W1    = (const float*)d_in[5];
    const float* b1    = (const float*)d_in[6];
    const float* W2    = (const float*)d_in[7];
    const float* b2    = (const float*)d_in[8];
    float* out = (float*)d_out;

    long nedges = in_sizes[1];
    int  n      = in_sizes[4] / IN_SIZE;
    const int* row = index;
    const int* col = index + nedges;

    // ws: bin[nedges]u2 | bcnt/bstart/bcur | H1h[32n B] | Ah[32n B] | T[64n B] | deg[4n B]
    size_t need = (size_t)nedges * 8 + (size_t)(3 * NBUCK + 1) * 4 +
                  (size_t)n * (32 + 32 + 64 + 4) + 1024;

    if (ws_size >= need && n <= (NBUCK << BSHIFT)) {
        char* p = (char*)d_ws;
        unsigned int* bin = (unsigned int*)p;  p += (size_t)nedges * 8;
        int* bcnt   = (int*)p;   p += NBUCK * 4;
        int* bstart = (int*)p;   p += (NBUCK + 1) * 4;
        int* bcur   = (int*)p;   p += NBUCK * 4;
        p = align_up(p, 64);
        __half2* H1h = (__half2*)p;  p += (size_t)n * 32;
        __half2* Ah  = (__half2*)p;  p += (size_t)n * 32;
        float* T     = (float*)p;    p += (size_t)n * 64;
        float* deg   = (float*)p;

        int nbuck_used = (n + 255) >> BSHIFT;

        zero_int_kernel<<<1, 256, 0, stream>>>(bcnt, NBUCK);
        bhist_kernel<<<(int)((nedges + EBH - 1) / EBH), 256, 0, stream>>>(row, bcnt, nedges);
        bucket_scan_kernel<<<1, NBUCK, 0, stream>>>(bcnt, bstart, bcur, nedges);
        bin_kernel<<<(int)((nedges + EB - 1) / EB), 256, 0, stream>>>(
            row, col, value, bcur, bin, nedges);

        dense1_half_kernel<<<(n + 31) / 32, 256, 0, stream>>>(X, W1, b1, H1h, n);

        // pass 1: Ah = relu(spmm(H1h)) in fp16, deg
        spmm_bucket_h_kernel<<<nbuck_used, 1024, 0, stream>>>(
            (const uint2*)bin, bstart, H1h, (void*)Ah, deg, n, 1, 1);
        // pass 2: T = spmm(Ah) in fp32
        spmm_bucket_h_kernel<<<nbuck_used, 1024, 0, stream>>>(
            (const uint2*)bin, bstart, Ah, (void*)T, nullptr, n, 0, 0);

        dense2_kernel<<<(n + 3) / 4, 256, 0, stream>>>(T, deg, W2, b2, out, n);
    } else {
        // atomic push fallback (fp32 end-to-end)
        float* ws = (float*)d_ws;
        float* H1  = ws;
        float* S1  = H1 + (size_t)n * HIDDEN;
        float* T   = S1 + (size_t)n * HIDDEN;
        float* deg = T + (size_t)n * HIDDEN;
        zero_int_kernel<<<2048, 256, 0, stream>>>((int*)S1, (long)n * (2 * HIDDEN + 1));
        dense1_kernel<<<(n + 15) / 16, 256, 0, stream>>>(X, W1, b1, H1, n);
        long thr1 = nedges * HIDDEN;
        spmm16_kernel<<<(int)((thr1 + 255) / 256), 256, 0, stream>>>(
            row, col, value, H1, S1, deg, nedges, 0);
        spmm16_kernel<<<(int)((thr1 + 255) / 256), 256, 0, stream>>>(
            row, col, value, S1, T, nullptr, nedges, 1);
        dense2_kernel<<<(n + 3) / 4, 256, 0, stream>>>(T, deg, W2, b2, out, n);
    }
}

// Round 6
// 264.555 us; speedup vs baseline: 3.5243x; 3.2729x over previous
//
#include <hip/hip_runtime.h>
#include <hip/hip_fp16.h>

#define IN_SIZE 256
#define HIDDEN 16
#define OUT_SIZE 64
#define NBUCK 512      // bucket = row >> 8 (256 rows each, n <= 131072)
#define BSHIFT 8
#define EB 4096        // edges per bin block
#define EBH 8192       // edges per bhist block

// ---------------- zero ----------------
__global__ __launch_bounds__(256) void zero_int_kernel(int* __restrict__ a, long n) {
    long i = (long)blockIdx.x * 256 + threadIdx.x;
    long stride = (long)gridDim.x * 256;
    for (; i < n; i += stride) a[i] = 0;
}

// ---------------- H1(fp16) = X @ W1^T + b1  [n,16] ----------------
__global__ __launch_bounds__(256) void dense1_half_kernel(
    const float* __restrict__ X, const float* __restrict__ W1,
    const float* __restrict__ b1, __half2* __restrict__ H1, int n) {
    __shared__ float w[IN_SIZE * HIDDEN];  // w[k*16+h] = W1[h][k]
    for (int i = threadIdx.x; i < HIDDEN * IN_SIZE; i += 256) {
        int h = i >> 8;
        int k = i & 255;
        w[k * HIDDEN + h] = W1[i];
    }
    __syncthreads();
    int node = blockIdx.x * 32 + (threadIdx.x >> 3);
    int hp = threadIdx.x & 7;
    if (node >= n) return;
    const float4* xr = reinterpret_cast<const float4*>(X + (size_t)node * IN_SIZE);
    float a0 = b1[2 * hp], a1 = b1[2 * hp + 1];
#pragma unroll 8
    for (int kk = 0; kk < IN_SIZE / 4; ++kk) {
        float4 x = xr[kk];
        const float* w0 = &w[(4 * kk) * HIDDEN + 2 * hp];
        a0 += x.x * w0[0] + x.y * w0[HIDDEN] + x.z * w0[2 * HIDDEN] + x.w * w0[3 * HIDDEN];
        a1 += x.x * w0[1] + x.y * w0[HIDDEN + 1] + x.z * w0[2 * HIDDEN + 1] + x.w * w0[3 * HIDDEN + 1];
    }
    H1[(size_t)node * 8 + hp] = __floats2half2_rn(a0, a1);
}

// ---------------- fp32 dense1 (fallback path only) ----------------
__global__ __launch_bounds__(256) void dense1_kernel(
    const float* __restrict__ X, const float* __restrict__ W1,
    const float* __restrict__ b1, float* __restrict__ H1, int n) {
    __shared__ float w[HIDDEN * IN_SIZE];
    for (int i = threadIdx.x; i < HIDDEN * IN_SIZE; i += 256) {
        int h = i >> 8;
        int k = i & 255;
        w[k * HIDDEN + h] = W1[i];
    }
    __syncthreads();
    int t = threadIdx.x;
    int node = blockIdx.x * 16 + (t >> 4);
    int h = t & 15;
    if (node >= n) return;
    const float4* xr = reinterpret_cast<const float4*>(X + (size_t)node * IN_SIZE);
    float acc = b1[h];
#pragma unroll 8
    for (int kk = 0; kk < IN_SIZE / 4; ++kk) {
        float4 x = xr[kk];
        const float* wr = &w[(kk * 4) * HIDDEN + h];
        acc += x.x * wr[0] + x.y * wr[HIDDEN] + x.z * wr[2 * HIDDEN] + x.w * wr[3 * HIDDEN];
    }
    H1[(size_t)node * HIDDEN + h] = acc;
}

// ---------------- bucket histogram (LDS-merged) ----------------
__global__ __launch_bounds__(256) void bhist_kernel(
    const int* __restrict__ row, int* __restrict__ bcnt, long nedges) {
    __shared__ int bh[NBUCK];
    for (int i = threadIdx.x; i < NBUCK; i += 256) bh[i] = 0;
    __syncthreads();
    long base = (long)blockIdx.x * EBH;
    long end = base + EBH;
    if (end > nedges) end = nedges;
    for (long e = base + threadIdx.x; e < end; e += 256)
        atomicAdd(&bh[row[e] >> BSHIFT], 1);
    __syncthreads();
    for (int i = threadIdx.x; i < NBUCK; i += 256)
        if (bh[i]) atomicAdd(&bcnt[i], bh[i]);
}

// ---------------- bucket exclusive scan ----------------
__global__ __launch_bounds__(512) void bucket_scan_kernel(
    const int* __restrict__ bcnt, int* __restrict__ bstart,
    int* __restrict__ bcur, long nedges) {
    __shared__ int s[NBUCK];
    int tid = threadIdx.x;
    int x = bcnt[tid];
    s[tid] = x;
    __syncthreads();
    for (int off = 1; off < NBUCK; off <<= 1) {
        int t = (tid >= off) ? s[tid - off] : 0;
        __syncthreads();
        s[tid] += t;
        __syncthreads();
    }
    int e = s[tid] - x;
    bstart[tid] = e;
    bcur[tid] = e;
    if (tid == NBUCK - 1) bstart[NBUCK] = (int)nedges;
}

// ---------------- bin edges bucket-major, 8-B records ----------------
// record: x = (local_row<<24)|col, y = val bits
__global__ __launch_bounds__(256) void bin_kernel(
    const int* __restrict__ row, const int* __restrict__ col,
    const float* __restrict__ val, int* __restrict__ bcur,
    unsigned int* __restrict__ bin, long nedges) {
    __shared__ int hist[NBUCK];
    __shared__ int cnt2[NBUCK];
    __shared__ int lbase[NBUCK];
    __shared__ int shiftd[NBUCK];
    __shared__ int s[256];
    __shared__ unsigned int staged[EB * 2];
    __shared__ unsigned short sbuck[EB];
    long base = (long)blockIdx.x * EB;
    int ecount = (int)((nedges - base < (long)EB) ? (nedges - base) : (long)EB);
    int tid = threadIdx.x;
    for (int i = tid; i < NBUCK; i += 256) { hist[i] = 0; cnt2[i] = 0; }
    __syncthreads();
    for (int k = tid; k < ecount; k += 256)
        atomicAdd(&hist[row[base + k] >> BSHIFT], 1);
    __syncthreads();
    int a = hist[2 * tid], b = hist[2 * tid + 1];
    int ps = a + b;
    s[tid] = ps;
    __syncthreads();
    for (int off = 1; off < 256; off <<= 1) {
        int t = (tid >= off) ? s[tid - off] : 0;
        __syncthreads();
        s[tid] += t;
        __syncthreads();
    }
    int excl = s[tid] - ps;
    lbase[2 * tid] = excl;
    lbase[2 * tid + 1] = excl + a;
    if (a > 0) {
        int g = atomicAdd(&bcur[2 * tid], a);
        shiftd[2 * tid] = 2 * (g - excl);
    }
    if (b > 0) {
        int g = atomicAdd(&bcur[2 * tid + 1], b);
        shiftd[2 * tid + 1] = 2 * (g - (excl + a));
    }
    __syncthreads();
    for (int k = tid; k < ecount; k += 256) {
        long e = base + k;
        int r = row[e];
        int bb = r >> BSHIFT;
        int p = lbase[bb] + atomicAdd(&cnt2[bb], 1);
        staged[2 * p]     = ((unsigned int)(r & 255) << 24) | (unsigned int)col[e];
        staged[2 * p + 1] = __float_as_uint(val[e]);
        sbuck[p] = (unsigned short)bb;
    }
    __syncthreads();
    int nd = 2 * ecount;
    for (int j = tid; j < nd; j += 256) {
        int bb = sbuck[j >> 1];
        bin[(long)j + shiftd[bb]] = staged[j];
    }
}

// ---------------- per-bucket LDS counting sort -> row-sorted epack + row_ptr
__global__ __launch_bounds__(256) void csort_kernel(
    const uint2* __restrict__ bin, const int* __restrict__ bstart,
    int* __restrict__ row_ptr, uint2* __restrict__ epack, int n, long nedges) {
    __shared__ int cnt[256];
    __shared__ int cur[256];
    __shared__ int s[256];
    int b = blockIdx.x, tid = threadIdx.x;
    int e0 = bstart[b], e1 = bstart[b + 1];
    cnt[tid] = 0;
    __syncthreads();
    for (int e = e0 + tid; e < e1; e += 256)
        atomicAdd(&cnt[bin[e].x >> 24], 1);
    __syncthreads();
    int x = cnt[tid];
    s[tid] = x;
    __syncthreads();
    for (int off = 1; off < 256; off <<= 1) {
        int t = (tid >= off) ? s[tid - off] : 0;
        __syncthreads();
        s[tid] += t;
        __syncthreads();
    }
    int excl = s[tid] - x;
    int grow = (b << BSHIFT) + tid;
    if (grow < n) row_ptr[grow] = e0 + excl;
    cur[tid] = e0 + excl;
    if (b == 0 && tid == 0) row_ptr[n] = (int)nedges;
    __syncthreads();
    for (int e = e0 + tid; e < e1; e += 256) {
        uint2 rec = bin[e];               // L2-hot (just read above)
        int lr = rec.x >> 24;
        int p = atomicAdd(&cur[lr], 1);
        epack[p] = make_uint2(rec.x & 0xFFFFFF, rec.y);  // 64KB window scatter
    }
}

// ---------------- pull spmm, fp16 gather, register acc, 4-way unroll -------
// 4 lanes/row; lane q owns features 4q..4q+3 (one uint2 = 4 halves)
__device__ __forceinline__ void fma_h(float4& a, uint2 h, float v) {
    __half2 lo = *reinterpret_cast<const __half2*>(&h.x);
    __half2 hi = *reinterpret_cast<const __half2*>(&h.y);
    float2 f0 = __half22float2(lo), f1 = __half22float2(hi);
    a.x += v * f0.x; a.y += v * f0.y; a.z += v * f1.x; a.w += v * f1.y;
}

__global__ __launch_bounds__(256) void spmm_pull_h_kernel(
    const int* __restrict__ row_ptr, const uint2* __restrict__ epack,
    const uint2* __restrict__ Hin, void* __restrict__ Sout,
    float* __restrict__ deg, int n, int relu_out, int out_half) {
    int t = blockIdx.x * 256 + threadIdx.x;
    int r = t >> 2, q = t & 3;
    if (r >= n) return;
    int e0 = row_ptr[r], e1 = row_ptr[r + 1];
    float4 a0 = {0,0,0,0}, a1 = {0,0,0,0}, a2 = {0,0,0,0}, a3 = {0,0,0,0};
    float d = 0.f;
    int e = e0;
    for (; e + 4 <= e1; e += 4) {
        uint2 r0 = epack[e], r1 = epack[e + 1], r2 = epack[e + 2], r3 = epack[e + 3];
        uint2 h0 = Hin[(size_t)r0.x * 4 + q];
        uint2 h1 = Hin[(size_t)r1.x * 4 + q];
        uint2 h2 = Hin[(size_t)r2.x * 4 + q];
        uint2 h3 = Hin[(size_t)r3.x * 4 + q];
        float v0 = __uint_as_float(r0.y), v1 = __uint_as_float(r1.y);
        float v2 = __uint_as_float(r2.y), v3 = __uint_as_float(r3.y);
        fma_h(a0, h0, v0); fma_h(a1, h1, v1);
        fma_h(a2, h2, v2); fma_h(a3, h3, v3);
        d += v0 + v1 + v2 + v3;
    }
    for (; e < e1; ++e) {
        uint2 rr = epack[e];
        uint2 h = Hin[(size_t)rr.x * 4 + q];
        float v = __uint_as_float(rr.y);
        fma_h(a0, h, v);
        d += v;
    }
    a0.x += a1.x + a2.x + a3.x;
    a0.y += a1.y + a2.y + a3.y;
    a0.z += a1.z + a2.z + a3.z;
    a0.w += a1.w + a2.w + a3.w;
    if (relu_out) {
        a0.x = fmaxf(a0.x, 0.f); a0.y = fmaxf(a0.y, 0.f);
        a0.z = fmaxf(a0.z, 0.f); a0.w = fmaxf(a0.w, 0.f);
    }
    if (out_half) {
        __half2* O = (__half2*)Sout;
        O[(size_t)r * 8 + 2 * q]     = __floats2half2_rn(a0.x, a0.y);
        O[(size_t)r * 8 + 2 * q + 1] = __floats2half2_rn(a0.z, a0.w);
    } else {
        reinterpret_cast<float4*>((float*)Sout + (size_t)r * 16)[q] = a0;
    }
    if (deg != nullptr && q == 0) deg[r] = d;
}

// ---------------- atomic push spmm (fallback only) ----------------
__global__ __launch_bounds__(256) void spmm16_kernel(
    const int* __restrict__ row, const int* __restrict__ col,
    const float* __restrict__ val, const float* __restrict__ Hin,
    float* __restrict__ Sout, float* __restrict__ deg, long nedges, int relu_in) {
    long t = (long)blockIdx.x * 256 + threadIdx.x;
    long e = t >> 4;
    if (e >= nedges) return;
    int k = (int)(t & 15);
    int r = row[e];
    int c = col[e];
    float v = val[e];
    float x = Hin[(size_t)c * HIDDEN + k];
    if (relu_in) x = fmaxf(x, 0.0f);
    atomicAdd(&Sout[(size_t)r * HIDDEN + k], v * x);
    if (deg != nullptr && k == 0) atomicAdd(&deg[r], v);
}

// ---------------- out = relu(T @ W2^T + deg*b2)  [n,64] ----------------
__global__ __launch_bounds__(256) void dense2_kernel(
    const float* __restrict__ T, const float* __restrict__ deg,
    const float* __restrict__ W2, const float* __restrict__ b2,
    float* __restrict__ out, int n) {
    __shared__ float w[OUT_SIZE * HIDDEN];
    for (int i = threadIdx.x; i < OUT_SIZE * HIDDEN; i += 256) {
        int o = i / HIDDEN;
        int h = i % HIDDEN;
        w[h * OUT_SIZE + o] = W2[i];
    }
    __syncthreads();
    int node = blockIdx.x * 4 + (threadIdx.x >> 6);
    int o = threadIdx.x & 63;
    if (node >= n) return;
    float acc = deg[node] * b2[o];
#pragma unroll
    for (int h = 0; h < HIDDEN; ++h)
        acc += T[(size_t)node * HIDDEN + h] * w[h * OUT_SIZE + o];
    out[(size_t)node * OUT_SIZE + o] = fmaxf(acc, 0.0f);
}

static inline char* align_up(char* p, size_t a) {
    return (char*)(((uintptr_t)p + a - 1) & ~(uintptr_t)(a - 1));
}

extern "C" void kernel_launch(void* const* d_in, const int* in_sizes, int n_in,
                              void* d_out, int out_size, void* d_ws, size_t ws_size,
                              hipStream_t stream) {
    const int*   index = (const int*)d_in[0];
    const float* value = (const float*)d_in[1];
    const float* X     = (const float*)d_in[4];
    const float* W1    = (const float*)d_in[5];
    const float* b1    = (const float*)d_in[6];
    const float* W2    = (const float*)d_in[7];
    const float* b2    = (const float*)d_in[8];
    float* out = (float*)d_out;

    long nedges = in_sizes[1];
    int  n      = in_sizes[4] / IN_SIZE;
    const int* row = index;
    const int* col = index + nedges;

    // ws: bin[8B*E] | epack[8B*E] | bcnt/bstart/bcur | row_ptr[(n+1)] |
    //     H1h[32n] | Ah[32n] | T[64n] | deg[4n]
    size_t need = (size_t)nedges * 16 + (size_t)(3 * NBUCK + 1) * 4 +
                  (size_t)(n + 1) * 4 + (size_t)n * (32 + 32 + 64 + 4) + 1024;

    if (ws_size >= need && n <= (NBUCK << BSHIFT)) {
        char* p = (char*)d_ws;
        unsigned int* bin = (unsigned int*)p;  p += (size_t)nedges * 8;
        uint2* epack = (uint2*)p;              p += (size_t)nedges * 8;
        int* bcnt   = (int*)p;   p += NBUCK * 4;
        int* bstart = (int*)p;   p += (NBUCK + 1) * 4;
        int* bcur   = (int*)p;   p += NBUCK * 4;
        int* row_ptr = (int*)p;  p += (size_t)(n + 1) * 4;
        p = align_up(p, 64);
        __half2* H1h = (__half2*)p;  p += (size_t)n * 32;
        __half2* Ah  = (__half2*)p;  p += (size_t)n * 32;
        float* T     = (float*)p;    p += (size_t)n * 64;
        float* deg   = (float*)p;

        int nbuck_used = (n + 255) >> BSHIFT;

        zero_int_kernel<<<1, 256, 0, stream>>>(bcnt, NBUCK);
        bhist_kernel<<<(int)((nedges + EBH - 1) / EBH), 256, 0, stream>>>(row, bcnt, nedges);
        bucket_scan_kernel<<<1, NBUCK, 0, stream>>>(bcnt, bstart, bcur, nedges);
        bin_kernel<<<(int)((nedges + EB - 1) / EB), 256, 0, stream>>>(
            row, col, value, bcur, bin, nedges);
        csort_kernel<<<nbuck_used, 256, 0, stream>>>(
            (const uint2*)bin, bstart, row_ptr, epack, n, nedges);

        dense1_half_kernel<<<(n + 31) / 32, 256, 0, stream>>>(X, W1, b1, H1h, n);

        int sblocks = ((n * 4) + 255) / 256;
        // pass 1: Ah = relu(spmm(H1h)) fp16, deg
        spmm_pull_h_kernel<<<sblocks, 256, 0, stream>>>(
            row_ptr, epack, (const uint2*)H1h, (void*)Ah, deg, n, 1, 1);
        // pass 2: T = spmm(Ah) fp32
        spmm_pull_h_kernel<<<sblocks, 256, 0, stream>>>(
            row_ptr, epack, (const uint2*)Ah, (void*)T, nullptr, n, 0, 0);

        dense2_kernel<<<(n + 3) / 4, 256, 0, stream>>>(T, deg, W2, b2, out, n);
    } else {
        // atomic push fallback (fp32 end-to-end)
        float* ws = (float*)d_ws;
        float* H1  = ws;
        float* S1  = H1 + (size_t)n * HIDDEN;
        float* T   = S1 + (size_t)n * HIDDEN;
        float* deg = T + (size_t)n * HIDDEN;
        zero_int_kernel<<<2048, 256, 0, stream>>>((int*)S1, (long)n * (2 * HIDDEN + 1));
        dense1_kernel<<<(n + 15) / 16, 256, 0, stream>>>(X, W1, b1, H1, n);
        long thr1 = nedges * HIDDEN;
        spmm16_kernel<<<(int)((thr1 + 255) / 256), 256, 0, stream>>>(
            row, col, value, H1, S1, deg, nedges, 0);
        spmm16_kernel<<<(int)((thr1 + 255) / 256), 256, 0, stream>>>(
            row, col, value, S1, T, nullptr, nedges, 1);
        dense2_kernel<<<(n + 3) / 4, 256, 0, stream>>>(T, deg, W2, b2, out, n);
    }
}

// Round 7
// 233.629 us; speedup vs baseline: 3.9908x; 1.1324x over previous
//
#include <hip/hip_runtime.h>
#include <hip/hip_fp16.h>

#define IN_SIZE 256
#define HIDDEN 16
#define OUT_SIZE 64
#define NBUCK 512      // bucket = row >> 8 (256 rows each, n <= 131072)
#define BSHIFT 8
#define EB 4096        // edges per bin block
#define BINBLK 512     // threads in bin_kernel (== NBUCK)
#define EPT (EB / BINBLK)  // 8 edges per thread
#define EBH 8192       // edges per bhist block

// ---------------- zero ----------------
__global__ __launch_bounds__(256) void zero_int_kernel(int* __restrict__ a, long n) {
    long i = (long)blockIdx.x * 256 + threadIdx.x;
    long stride = (long)gridDim.x * 256;
    for (; i < n; i += stride) a[i] = 0;
}

// ---------------- H1(fp16) = X @ W1^T + b1  [n,16] ----------------
__global__ __launch_bounds__(256) void dense1_half_kernel(
    const float* __restrict__ X, const float* __restrict__ W1,
    const float* __restrict__ b1, __half2* __restrict__ H1, int n) {
    __shared__ float w[IN_SIZE * HIDDEN];  // w[k*16+h] = W1[h][k]
    for (int i = threadIdx.x; i < HIDDEN * IN_SIZE; i += 256) {
        int h = i >> 8;
        int k = i & 255;
        w[k * HIDDEN + h] = W1[i];
    }
    __syncthreads();
    int node = blockIdx.x * 32 + (threadIdx.x >> 3);
    int hp = threadIdx.x & 7;
    if (node >= n) return;
    const float4* xr = reinterpret_cast<const float4*>(X + (size_t)node * IN_SIZE);
    float a0 = b1[2 * hp], a1 = b1[2 * hp + 1];
#pragma unroll 8
    for (int kk = 0; kk < IN_SIZE / 4; ++kk) {
        float4 x = xr[kk];
        const float* w0 = &w[(4 * kk) * HIDDEN + 2 * hp];
        a0 += x.x * w0[0] + x.y * w0[HIDDEN] + x.z * w0[2 * HIDDEN] + x.w * w0[3 * HIDDEN];
        a1 += x.x * w0[1] + x.y * w0[HIDDEN + 1] + x.z * w0[2 * HIDDEN + 1] + x.w * w0[3 * HIDDEN + 1];
    }
    H1[(size_t)node * 8 + hp] = __floats2half2_rn(a0, a1);
}

// ---------------- fp32 dense1 (fallback path only) ----------------
__global__ __launch_bounds__(256) void dense1_kernel(
    const float* __restrict__ X, const float* __restrict__ W1,
    const float* __restrict__ b1, float* __restrict__ H1, int n) {
    __shared__ float w[HIDDEN * IN_SIZE];
    for (int i = threadIdx.x; i < HIDDEN * IN_SIZE; i += 256) {
        int h = i >> 8;
        int k = i & 255;
        w[k * HIDDEN + h] = W1[i];
    }
    __syncthreads();
    int t = threadIdx.x;
    int node = blockIdx.x * 16 + (t >> 4);
    int h = t & 15;
    if (node >= n) return;
    const float4* xr = reinterpret_cast<const float4*>(X + (size_t)node * IN_SIZE);
    float acc = b1[h];
#pragma unroll 8
    for (int kk = 0; kk < IN_SIZE / 4; ++kk) {
        float4 x = xr[kk];
        const float* wr = &w[(kk * 4) * HIDDEN + h];
        acc += x.x * wr[0] + x.y * wr[HIDDEN] + x.z * wr[2 * HIDDEN] + x.w * wr[3 * HIDDEN];
    }
    H1[(size_t)node * HIDDEN + h] = acc;
}

// ---------------- bucket histogram (LDS-merged) ----------------
__global__ __launch_bounds__(256) void bhist_kernel(
    const int* __restrict__ row, int* __restrict__ bcnt, long nedges) {
    __shared__ int bh[NBUCK];
    for (int i = threadIdx.x; i < NBUCK; i += 256) bh[i] = 0;
    __syncthreads();
    long base = (long)blockIdx.x * EBH;
    long end = base + EBH;
    if (end > nedges) end = nedges;
    for (long e = base + threadIdx.x; e < end; e += 256)
        atomicAdd(&bh[row[e] >> BSHIFT], 1);
    __syncthreads();
    for (int i = threadIdx.x; i < NBUCK; i += 256)
        if (bh[i]) atomicAdd(&bcnt[i], bh[i]);
}

// ---------------- bucket exclusive scan ----------------
__global__ __launch_bounds__(512) void bucket_scan_kernel(
    const int* __restrict__ bcnt, int* __restrict__ bstart,
    int* __restrict__ bcur, long nedges) {
    __shared__ int s[NBUCK];
    int tid = threadIdx.x;
    int x = bcnt[tid];
    s[tid] = x;
    __syncthreads();
    for (int off = 1; off < NBUCK; off <<= 1) {
        int t = (tid >= off) ? s[tid - off] : 0;
        __syncthreads();
        s[tid] += t;
        __syncthreads();
    }
    int e = s[tid] - x;
    bstart[tid] = e;
    bcur[tid] = e;
    if (tid == NBUCK - 1) bstart[NBUCK] = (int)nedges;
}

// ---------------- bin edges bucket-major, single global read ----------------
// record: x = (local_row<<24)|col, y = val bits
// meta reg: lr<<24 | bb<<12 | slot  (bits 21..23 always 0; sentinel = all-ones)
__global__ __launch_bounds__(BINBLK) void bin_kernel(
    const int* __restrict__ row, const int* __restrict__ col,
    const float* __restrict__ val, int* __restrict__ bcur,
    unsigned int* __restrict__ bin, long nedges) {
    __shared__ int hist[NBUCK];
    __shared__ int lbase[NBUCK];
    __shared__ int shiftd[NBUCK];
    __shared__ int s[BINBLK];
    __shared__ unsigned int staged[EB * 2];        // 32 KB
    __shared__ unsigned short sbuck[EB];           // 8 KB
    long base = (long)blockIdx.x * EB;
    int ecount = (int)((nedges - base < (long)EB) ? (nedges - base) : (long)EB);
    int tid = threadIdx.x;
    hist[tid] = 0;   // NBUCK == BINBLK
    __syncthreads();

    // fused: load edges once -> registers, count + slot-assign
    unsigned int meta[EPT], cc[EPT], vv[EPT];
#pragma unroll
    for (int i = 0; i < EPT; ++i) {
        int k = tid + i * BINBLK;
        meta[i] = 0xFFFFFFFFu;
        if (k < ecount) {
            int r = row[base + k];
            cc[i] = (unsigned int)col[base + k];
            vv[i] = __float_as_uint(val[base + k]);
            int bb = r >> BSHIFT;
            int slot = atomicAdd(&hist[bb], 1);
            meta[i] = ((unsigned int)(r & 255) << 24) |
                      ((unsigned int)bb << 12) | (unsigned int)slot;
        }
    }
    __syncthreads();
    // scan hist (512 wide), reserve global space per bucket
    int x = hist[tid];
    s[tid] = x;
    __syncthreads();
    for (int off = 1; off < BINBLK; off <<= 1) {
        int t = (tid >= off) ? s[tid - off] : 0;
        __syncthreads();
        s[tid] += t;
        __syncthreads();
    }
    int excl = s[tid] - x;
    lbase[tid] = excl;
    if (x > 0) {
        int g = atomicAdd(&bcur[tid], x);
        shiftd[tid] = 2 * (g - excl);
    }
    __syncthreads();
    // place into LDS staged (bucket-major within block)
#pragma unroll
    for (int i = 0; i < EPT; ++i) {
        if (meta[i] != 0xFFFFFFFFu) {
            int bb = (meta[i] >> 12) & 0x1FF;
            int p = lbase[bb] + (int)(meta[i] & 0xFFF);
            staged[2 * p]     = (meta[i] & 0xFF000000u) | cc[i];
            staged[2 * p + 1] = vv[i];
            sbuck[p] = (unsigned short)bb;
        }
    }
    __syncthreads();
    // copy LDS -> global at reserved offsets (coalesced runs)
    int nd = 2 * ecount;
    for (int j = tid; j < nd; j += BINBLK) {
        int bb = sbuck[j >> 1];
        bin[(long)j + shiftd[bb]] = staged[j];
    }
}

// ---------------- per-bucket LDS counting sort -> row-sorted epack + row_ptr
__global__ __launch_bounds__(512) void csort_kernel(
    const uint2* __restrict__ bin, const int* __restrict__ bstart,
    int* __restrict__ row_ptr, uint2* __restrict__ epack, int n, long nedges) {
    __shared__ int cnt[256];
    __shared__ int cur[256];
    __shared__ int s[256];
    int b = blockIdx.x, tid = threadIdx.x;
    int e0 = bstart[b], e1 = bstart[b + 1];
    if (tid < 256) cnt[tid] = 0;
    __syncthreads();
    for (int e = e0 + tid; e < e1; e += 512)
        atomicAdd(&cnt[bin[e].x >> 24], 1);
    __syncthreads();
    int x = (tid < 256) ? cnt[tid] : 0;
    if (tid < 256) s[tid] = x;
    __syncthreads();
    for (int off = 1; off < 256; off <<= 1) {
        int t = (tid >= off && tid < 256) ? s[tid - off] : 0;
        __syncthreads();
        if (tid < 256) s[tid] += t;
        __syncthreads();
    }
    if (tid < 256) {
        int excl = s[tid] - x;
        int grow = (b << BSHIFT) + tid;
        if (grow < n) row_ptr[grow] = e0 + excl;
        cur[tid] = e0 + excl;
    }
    if (b == 0 && tid == 0) row_ptr[n] = (int)nedges;
    __syncthreads();
    for (int e = e0 + tid; e < e1; e += 512) {
        uint2 rec = bin[e];               // L2-hot
        int lr = rec.x >> 24;
        int p = atomicAdd(&cur[lr], 1);
        epack[p] = make_uint2(rec.x & 0xFFFFFF, rec.y);  // 64KB window scatter
    }
}

// ---------------- pull spmm, fp16 gather, register acc, 4-way unroll -------
__device__ __forceinline__ void fma_h(float4& a, uint2 h, float v) {
    __half2 lo = *reinterpret_cast<const __half2*>(&h.x);
    __half2 hi = *reinterpret_cast<const __half2*>(&h.y);
    float2 f0 = __half22float2(lo), f1 = __half22float2(hi);
    a.x += v * f0.x; a.y += v * f0.y; a.z += v * f1.x; a.w += v * f1.y;
}

__global__ __launch_bounds__(256) void spmm_pull_h_kernel(
    const int* __restrict__ row_ptr, const uint2* __restrict__ epack,
    const uint2* __restrict__ Hin, void* __restrict__ Sout,
    float* __restrict__ deg, int n, int relu_out, int out_half) {
    int t = blockIdx.x * 256 + threadIdx.x;
    int r = t >> 2, q = t & 3;
    if (r >= n) return;
    int e0 = row_ptr[r], e1 = row_ptr[r + 1];
    float4 a0 = {0,0,0,0}, a1 = {0,0,0,0}, a2 = {0,0,0,0}, a3 = {0,0,0,0};
    float d = 0.f;
    int e = e0;
    for (; e + 4 <= e1; e += 4) {
        uint2 r0 = epack[e], r1 = epack[e + 1], r2 = epack[e + 2], r3 = epack[e + 3];
        uint2 h0 = Hin[(size_t)r0.x * 4 + q];
        uint2 h1 = Hin[(size_t)r1.x * 4 + q];
        uint2 h2 = Hin[(size_t)r2.x * 4 + q];
        uint2 h3 = Hin[(size_t)r3.x * 4 + q];
        float v0 = __uint_as_float(r0.y), v1 = __uint_as_float(r1.y);
        float v2 = __uint_as_float(r2.y), v3 = __uint_as_float(r3.y);
        fma_h(a0, h0, v0); fma_h(a1, h1, v1);
        fma_h(a2, h2, v2); fma_h(a3, h3, v3);
        d += v0 + v1 + v2 + v3;
    }
    for (; e < e1; ++e) {
        uint2 rr = epack[e];
        uint2 h = Hin[(size_t)rr.x * 4 + q];
        float v = __uint_as_float(rr.y);
        fma_h(a0, h, v);
        d += v;
    }
    a0.x += a1.x + a2.x + a3.x;
    a0.y += a1.y + a2.y + a3.y;
    a0.z += a1.z + a2.z + a3.z;
    a0.w += a1.w + a2.w + a3.w;
    if (relu_out) {
        a0.x = fmaxf(a0.x, 0.f); a0.y = fmaxf(a0.y, 0.f);
        a0.z = fmaxf(a0.z, 0.f); a0.w = fmaxf(a0.w, 0.f);
    }
    if (out_half) {
        __half2* O = (__half2*)Sout;
        O[(size_t)r * 8 + 2 * q]     = __floats2half2_rn(a0.x, a0.y);
        O[(size_t)r * 8 + 2 * q + 1] = __floats2half2_rn(a0.z, a0.w);
    } else {
        reinterpret_cast<float4*>((float*)Sout + (size_t)r * 16)[q] = a0;
    }
    if (deg != nullptr && q == 0) deg[r] = d;
}

// ---------------- atomic push spmm (fallback only) ----------------
__global__ __launch_bounds__(256) void spmm16_kernel(
    const int* __restrict__ row, const int* __restrict__ col,
    const float* __restrict__ val, const float* __restrict__ Hin,
    float* __restrict__ Sout, float* __restrict__ deg, long nedges, int relu_in) {
    long t = (long)blockIdx.x * 256 + threadIdx.x;
    long e = t >> 4;
    if (e >= nedges) return;
    int k = (int)(t & 15);
    int r = row[e];
    int c = col[e];
    float v = val[e];
    float x = Hin[(size_t)c * HIDDEN + k];
    if (relu_in) x = fmaxf(x, 0.0f);
    atomicAdd(&Sout[(size_t)r * HIDDEN + k], v * x);
    if (deg != nullptr && k == 0) atomicAdd(&deg[r], v);
}

// ---------------- out = relu(T @ W2^T + deg*b2)  [n,64] ----------------
__global__ __launch_bounds__(256) void dense2_kernel(
    const float* __restrict__ T, const float* __restrict__ deg,
    const float* __restrict__ W2, const float* __restrict__ b2,
    float* __restrict__ out, int n) {
    __shared__ float w[OUT_SIZE * HIDDEN];
    for (int i = threadIdx.x; i < OUT_SIZE * HIDDEN; i += 256) {
        int o = i / HIDDEN;
        int h = i % HIDDEN;
        w[h * OUT_SIZE + o] = W2[i];
    }
    __syncthreads();
    int node = blockIdx.x * 4 + (threadIdx.x >> 6);
    int o = threadIdx.x & 63;
    if (node >= n) return;
    float acc = deg[node] * b2[o];
#pragma unroll
    for (int h = 0; h < HIDDEN; ++h)
        acc += T[(size_t)node * HIDDEN + h] * w[h * OUT_SIZE + o];
    out[(size_t)node * OUT_SIZE + o] = fmaxf(acc, 0.0f);
}

static inline char* align_up(char* p, size_t a) {
    return (char*)(((uintptr_t)p + a - 1) & ~(uintptr_t)(a - 1));
}

extern "C" void kernel_launch(void* const* d_in, const int* in_sizes, int n_in,
                              void* d_out, int out_size, void* d_ws, size_t ws_size,
                              hipStream_t stream) {
    const int*   index = (const int*)d_in[0];
    const float* value = (const float*)d_in[1];
    const float* X     = (const float*)d_in[4];
    const float* W1    = (const float*)d_in[5];
    const float* b1    = (const float*)d_in[6];
    const float* W2    = (const float*)d_in[7];
    const float* b2    = (const float*)d_in[8];
    float* out = (float*)d_out;

    long nedges = in_sizes[1];
    int  n      = in_sizes[4] / IN_SIZE;
    const int* row = index;
    const int* col = index + nedges;

    // ws: bin[8B*E] | epack[8B*E] | bcnt/bstart/bcur | row_ptr[(n+1)] |
    //     H1h[32n] | Ah[32n] | T[64n] | deg[4n]
    size_t need = (size_t)nedges * 16 + (size_t)(3 * NBUCK + 1) * 4 +
                  (size_t)(n + 1) * 4 + (size_t)n * (32 + 32 + 64 + 4) + 1024;

    if (ws_size >= need && n <= (NBUCK << BSHIFT)) {
        char* p = (char*)d_ws;
        unsigned int* bin = (unsigned int*)p;  p += (size_t)nedges * 8;
        uint2* epack = (uint2*)p;              p += (size_t)nedges * 8;
        int* bcnt   = (int*)p;   p += NBUCK * 4;
        int* bstart = (int*)p;   p += (NBUCK + 1) * 4;
        int* bcur   = (int*)p;   p += NBUCK * 4;
        int* row_ptr = (int*)p;  p += (size_t)(n + 1) * 4;
        p = align_up(p, 64);
        __half2* H1h = (__half2*)p;  p += (size_t)n * 32;
        __half2* Ah  = (__half2*)p;  p += (size_t)n * 32;
        float* T     = (float*)p;    p += (size_t)n * 64;
        float* deg   = (float*)p;

        int nbuck_used = (n + 255) >> BSHIFT;

        zero_int_kernel<<<1, 256, 0, stream>>>(bcnt, NBUCK);
        bhist_kernel<<<(int)((nedges + EBH - 1) / EBH), 256, 0, stream>>>(row, bcnt, nedges);
        bucket_scan_kernel<<<1, NBUCK, 0, stream>>>(bcnt, bstart, bcur, nedges);
        bin_kernel<<<(int)((nedges + EB - 1) / EB), BINBLK, 0, stream>>>(
            row, col, value, bcur, bin, nedges);
        csort_kernel<<<nbuck_used, 512, 0, stream>>>(
            (const uint2*)bin, bstart, row_ptr, epack, n, nedges);

        dense1_half_kernel<<<(n + 31) / 32, 256, 0, stream>>>(X, W1, b1, H1h, n);

        int sblocks = ((n * 4) + 255) / 256;
        // pass 1: Ah = relu(spmm(H1h)) fp16, deg
        spmm_pull_h_kernel<<<sblocks, 256, 0, stream>>>(
            row_ptr, epack, (const uint2*)H1h, (void*)Ah, deg, n, 1, 1);
        // pass 2: T = spmm(Ah) fp32
        spmm_pull_h_kernel<<<sblocks, 256, 0, stream>>>(
            row_ptr, epack, (const uint2*)Ah, (void*)T, nullptr, n, 0, 0);

        dense2_kernel<<<(n + 3) / 4, 256, 0, stream>>>(T, deg, W2, b2, out, n);
    } else {
        // atomic push fallback (fp32 end-to-end)
        float* ws = (float*)d_ws;
        float* H1  = ws;
        float* S1  = H1 + (size_t)n * HIDDEN;
        float* T   = S1 + (size_t)n * HIDDEN;
        float* deg = T + (size_t)n * HIDDEN;
        zero_int_kernel<<<2048, 256, 0, stream>>>((int*)S1, (long)n * (2 * HIDDEN + 1));
        dense1_kernel<<<(n + 15) / 16, 256, 0, stream>>>(X, W1, b1, H1, n);
        long thr1 = nedges * HIDDEN;
        spmm16_kernel<<<(int)((thr1 + 255) / 256), 256, 0, stream>>>(
            row, col, value, H1, S1, deg, nedges, 0);
        spmm16_kernel<<<(int)((thr1 + 255) / 256), 256, 0, stream>>>(
            row, col, value, S1, T, nullptr, nedges, 1);
        dense2_kernel<<<(n + 3) / 4, 256, 0, stream>>>(T, deg, W2, b2, out, n);
    }
}

// Round 8
// 217.518 us; speedup vs baseline: 4.2864x; 1.0741x over previous
//
#include <hip/hip_runtime.h>
#include <hip/hip_fp16.h>

#define IN_SIZE 256
#define HIDDEN 16
#define OUT_SIZE 64
#define NBUCK 512      // bucket = row >> 8 (256 rows each, n <= 131072)
#define BSHIFT 8
#define EB 4096        // edges per bin block
#define BINBLK 512     // threads in bin_kernel (== NBUCK)
#define EPT (EB / BINBLK)  // 8 edges per thread
#define EBH 8192       // edges per bhist block
#define WSTR 20        // LDS row stride for W1 tile (80 B: b128-aligned, 2-way banks)

// ---------------- zero ----------------
__global__ __launch_bounds__(256) void zero_int_kernel(int* __restrict__ a, long n) {
    long i = (long)blockIdx.x * 256 + threadIdx.x;
    long stride = (long)gridDim.x * 256;
    for (; i < n; i += stride) a[i] = 0;
}

// ---------------- H1(fp16) = X @ W1^T + b1  [n,16] ----------------
// 4 lanes per node: lane q reads 64B chunk q of each 64B-aligned段; 16 nodes/wave
// -> 1KB distinct bytes per wave load. W1 in LDS row-stride-20 (b128, 2-way banks).
__global__ __launch_bounds__(256) void dense1_half_kernel(
    const float* __restrict__ X, const float* __restrict__ W1,
    const float* __restrict__ b1, __half2* __restrict__ H1, int n) {
    __shared__ float w[IN_SIZE * WSTR];  // w[k*20+h] = W1[h][k], 20 KB
    for (int i = threadIdx.x; i < HIDDEN * IN_SIZE; i += 256) {
        int h = i >> 8;
        int k = i & 255;
        w[k * WSTR + h] = W1[i];
    }
    __syncthreads();
    int node = blockIdx.x * 64 + (threadIdx.x >> 2);
    int q = threadIdx.x & 3;
    if (node >= n) return;           // whole 4-lane quad exits together
    float acc[16];
#pragma unroll
    for (int h = 0; h < 16; ++h) acc[h] = 0.f;
    const float4* xr = reinterpret_cast<const float4*>(X + (size_t)node * IN_SIZE);
#pragma unroll 4
    for (int kk = 0; kk < 16; ++kk) {
        float4 x = xr[q + 4 * kk];   // byte off = q*16 + kk*64 (coalesced quads)
        const float* wr = &w[(kk * 16 + q * 4) * WSTR];
#pragma unroll
        for (int j = 0; j < 4; ++j) {
            float xs = (j == 0) ? x.x : (j == 1) ? x.y : (j == 2) ? x.z : x.w;
            const float* wj = wr + j * WSTR;
#pragma unroll
            for (int h = 0; h < 16; ++h)   // 4x ds_read_b128
                acc[h] += xs * wj[h];
        }
    }
    // combine partial sums across the 4-lane quad
#pragma unroll
    for (int h = 0; h < 16; ++h) {
        acc[h] += __shfl_xor(acc[h], 1, 4);
        acc[h] += __shfl_xor(acc[h], 2, 4);
    }
    // lane q owns h = 4q..4q+3
    const float4 bb = reinterpret_cast<const float4*>(b1)[q];
    int hb = q * 4;
    __half2 o0 = __floats2half2_rn(acc[hb] + bb.x, acc[hb + 1] + bb.y);
    __half2 o1 = __floats2half2_rn(acc[hb + 2] + bb.z, acc[hb + 3] + bb.w);
    uint2 pk;
    pk.x = *reinterpret_cast<unsigned int*>(&o0);
    pk.y = *reinterpret_cast<unsigned int*>(&o1);
    reinterpret_cast<uint2*>(H1)[(size_t)node * 4 + q] = pk;  // 8B/lane coalesced
}

// ---------------- fp32 dense1 (fallback path only) ----------------
__global__ __launch_bounds__(256) void dense1_kernel(
    const float* __restrict__ X, const float* __restrict__ W1,
    const float* __restrict__ b1, float* __restrict__ H1, int n) {
    __shared__ float w[HIDDEN * IN_SIZE];
    for (int i = threadIdx.x; i < HIDDEN * IN_SIZE; i += 256) {
        int h = i >> 8;
        int k = i & 255;
        w[k * HIDDEN + h] = W1[i];
    }
    __syncthreads();
    int t = threadIdx.x;
    int node = blockIdx.x * 16 + (t >> 4);
    int h = t & 15;
    if (node >= n) return;
    const float4* xr = reinterpret_cast<const float4*>(X + (size_t)node * IN_SIZE);
    float acc = b1[h];
#pragma unroll 8
    for (int kk = 0; kk < IN_SIZE / 4; ++kk) {
        float4 x = xr[kk];
        const float* wr = &w[(kk * 4) * HIDDEN + h];
        acc += x.x * wr[0] + x.y * wr[HIDDEN] + x.z * wr[2 * HIDDEN] + x.w * wr[3 * HIDDEN];
    }
    H1[(size_t)node * HIDDEN + h] = acc;
}

// ---------------- bucket histogram (LDS-merged) ----------------
__global__ __launch_bounds__(256) void bhist_kernel(
    const int* __restrict__ row, int* __restrict__ bcnt, long nedges) {
    __shared__ int bh[NBUCK];
    for (int i = threadIdx.x; i < NBUCK; i += 256) bh[i] = 0;
    __syncthreads();
    long base = (long)blockIdx.x * EBH;
    long end = base + EBH;
    if (end > nedges) end = nedges;
    for (long e = base + threadIdx.x; e < end; e += 256)
        atomicAdd(&bh[row[e] >> BSHIFT], 1);
    __syncthreads();
    for (int i = threadIdx.x; i < NBUCK; i += 256)
        if (bh[i]) atomicAdd(&bcnt[i], bh[i]);
}

// ---------------- bucket exclusive scan ----------------
__global__ __launch_bounds__(512) void bucket_scan_kernel(
    const int* __restrict__ bcnt, int* __restrict__ bstart,
    int* __restrict__ bcur, long nedges) {
    __shared__ int s[NBUCK];
    int tid = threadIdx.x;
    int x = bcnt[tid];
    s[tid] = x;
    __syncthreads();
    for (int off = 1; off < NBUCK; off <<= 1) {
        int t = (tid >= off) ? s[tid - off] : 0;
        __syncthreads();
        s[tid] += t;
        __syncthreads();
    }
    int e = s[tid] - x;
    bstart[tid] = e;
    bcur[tid] = e;
    if (tid == NBUCK - 1) bstart[NBUCK] = (int)nedges;
}

// ---------------- bin edges bucket-major, single global read ----------------
// record: x = (local_row<<24)|col, y = val bits
// meta reg: lr<<24 | bb<<12 | slot  (bits 21..23 always 0; sentinel = all-ones)
__global__ __launch_bounds__(BINBLK) void bin_kernel(
    const int* __restrict__ row, const int* __restrict__ col,
    const float* __restrict__ val, int* __restrict__ bcur,
    unsigned int* __restrict__ bin, long nedges) {
    __shared__ int hist[NBUCK];
    __shared__ int lbase[NBUCK];
    __shared__ int shiftd[NBUCK];
    __shared__ int s[BINBLK];
    __shared__ unsigned int staged[EB * 2];        // 32 KB
    __shared__ unsigned short sbuck[EB];           // 8 KB
    long base = (long)blockIdx.x * EB;
    int ecount = (int)((nedges - base < (long)EB) ? (nedges - base) : (long)EB);
    int tid = threadIdx.x;
    hist[tid] = 0;   // NBUCK == BINBLK
    __syncthreads();

    // fused: load edges once -> registers, count + slot-assign
    unsigned int meta[EPT], cc[EPT], vv[EPT];
#pragma unroll
    for (int i = 0; i < EPT; ++i) {
        int k = tid + i * BINBLK;
        meta[i] = 0xFFFFFFFFu;
        if (k < ecount) {
            int r = row[base + k];
            cc[i] = (unsigned int)col[base + k];
            vv[i] = __float_as_uint(val[base + k]);
            int bb = r >> BSHIFT;
            int slot = atomicAdd(&hist[bb], 1);
            meta[i] = ((unsigned int)(r & 255) << 24) |
                      ((unsigned int)bb << 12) | (unsigned int)slot;
        }
    }
    __syncthreads();
    // scan hist (512 wide), reserve global space per bucket
    int x = hist[tid];
    s[tid] = x;
    __syncthreads();
    for (int off = 1; off < BINBLK; off <<= 1) {
        int t = (tid >= off) ? s[tid - off] : 0;
        __syncthreads();
        s[tid] += t;
        __syncthreads();
    }
    int excl = s[tid] - x;
    lbase[tid] = excl;
    if (x > 0) {
        int g = atomicAdd(&bcur[tid], x);
        shiftd[tid] = 2 * (g - excl);
    }
    __syncthreads();
    // place into LDS staged (bucket-major within block)
#pragma unroll
    for (int i = 0; i < EPT; ++i) {
        if (meta[i] != 0xFFFFFFFFu) {
            int bb = (meta[i] >> 12) & 0x1FF;
            int p = lbase[bb] + (int)(meta[i] & 0xFFF);
            staged[2 * p]     = (meta[i] & 0xFF000000u) | cc[i];
            staged[2 * p + 1] = vv[i];
            sbuck[p] = (unsigned short)bb;
        }
    }
    __syncthreads();
    // copy LDS -> global at reserved offsets (coalesced runs)
    int nd = 2 * ecount;
    for (int j = tid; j < nd; j += BINBLK) {
        int bb = sbuck[j >> 1];
        bin[(long)j + shiftd[bb]] = staged[j];
    }
}

// ---------------- per-bucket LDS counting sort -> row-sorted epack + row_ptr
__global__ __launch_bounds__(512) void csort_kernel(
    const uint2* __restrict__ bin, const int* __restrict__ bstart,
    int* __restrict__ row_ptr, uint2* __restrict__ epack, int n, long nedges) {
    __shared__ int cnt[256];
    __shared__ int cur[256];
    __shared__ int s[256];
    int b = blockIdx.x, tid = threadIdx.x;
    int e0 = bstart[b], e1 = bstart[b + 1];
    if (tid < 256) cnt[tid] = 0;
    __syncthreads();
    for (int e = e0 + tid; e < e1; e += 512)
        atomicAdd(&cnt[bin[e].x >> 24], 1);
    __syncthreads();
    int x = (tid < 256) ? cnt[tid] : 0;
    if (tid < 256) s[tid] = x;
    __syncthreads();
    for (int off = 1; off < 256; off <<= 1) {
        int t = (tid >= off && tid < 256) ? s[tid - off] : 0;
        __syncthreads();
        if (tid < 256) s[tid] += t;
        __syncthreads();
    }
    if (tid < 256) {
        int excl = s[tid] - x;
        int grow = (b << BSHIFT) + tid;
        if (grow < n) row_ptr[grow] = e0 + excl;
        cur[tid] = e0 + excl;
    }
    if (b == 0 && tid == 0) row_ptr[n] = (int)nedges;
    __syncthreads();
    for (int e = e0 + tid; e < e1; e += 512) {
        uint2 rec = bin[e];               // L2-hot
        int lr = rec.x >> 24;
        int p = atomicAdd(&cur[lr], 1);
        epack[p] = make_uint2(rec.x & 0xFFFFFF, rec.y);  // 64KB window scatter
    }
}

// ---------------- pull spmm, fp16 gather, register acc, 4-way unroll -------
__device__ __forceinline__ void fma_h(float4& a, uint2 h, float v) {
    __half2 lo = *reinterpret_cast<const __half2*>(&h.x);
    __half2 hi = *reinterpret_cast<const __half2*>(&h.y);
    float2 f0 = __half22float2(lo), f1 = __half22float2(hi);
    a.x += v * f0.x; a.y += v * f0.y; a.z += v * f1.x; a.w += v * f1.y;
}

__global__ __launch_bounds__(256) void spmm_pull_h_kernel(
    const int* __restrict__ row_ptr, const uint2* __restrict__ epack,
    const uint2* __restrict__ Hin, void* __restrict__ Sout,
    float* __restrict__ deg, int n, int relu_out, int out_half) {
    int t = blockIdx.x * 256 + threadIdx.x;
    int r = t >> 2, q = t & 3;
    if (r >= n) return;
    int e0 = row_ptr[r], e1 = row_ptr[r + 1];
    float4 a0 = {0,0,0,0}, a1 = {0,0,0,0}, a2 = {0,0,0,0}, a3 = {0,0,0,0};
    float d = 0.f;
    int e = e0;
    for (; e + 4 <= e1; e += 4) {
        uint2 r0 = epack[e], r1 = epack[e + 1], r2 = epack[e + 2], r3 = epack[e + 3];
        uint2 h0 = Hin[(size_t)r0.x * 4 + q];
        uint2 h1 = Hin[(size_t)r1.x * 4 + q];
        uint2 h2 = Hin[(size_t)r2.x * 4 + q];
        uint2 h3 = Hin[(size_t)r3.x * 4 + q];
        float v0 = __uint_as_float(r0.y), v1 = __uint_as_float(r1.y);
        float v2 = __uint_as_float(r2.y), v3 = __uint_as_float(r3.y);
        fma_h(a0, h0, v0); fma_h(a1, h1, v1);
        fma_h(a2, h2, v2); fma_h(a3, h3, v3);
        d += v0 + v1 + v2 + v3;
    }
    for (; e < e1; ++e) {
        uint2 rr = epack[e];
        uint2 h = Hin[(size_t)rr.x * 4 + q];
        float v = __uint_as_float(rr.y);
        fma_h(a0, h, v);
        d += v;
    }
    a0.x += a1.x + a2.x + a3.x;
    a0.y += a1.y + a2.y + a3.y;
    a0.z += a1.z + a2.z + a3.z;
    a0.w += a1.w + a2.w + a3.w;
    if (relu_out) {
        a0.x = fmaxf(a0.x, 0.f); a0.y = fmaxf(a0.y, 0.f);
        a0.z = fmaxf(a0.z, 0.f); a0.w = fmaxf(a0.w, 0.f);
    }
    if (out_half) {
        __half2* O = (__half2*)Sout;
        O[(size_t)r * 8 + 2 * q]     = __floats2half2_rn(a0.x, a0.y);
        O[(size_t)r * 8 + 2 * q + 1] = __floats2half2_rn(a0.z, a0.w);
    } else {
        reinterpret_cast<float4*>((float*)Sout + (size_t)r * 16)[q] = a0;
    }
    if (deg != nullptr && q == 0) deg[r] = d;
}

// ---------------- atomic push spmm (fallback only) ----------------
__global__ __launch_bounds__(256) void spmm16_kernel(
    const int* __restrict__ row, const int* __restrict__ col,
    const float* __restrict__ val, const float* __restrict__ Hin,
    float* __restrict__ Sout, float* __restrict__ deg, long nedges, int relu_in) {
    long t = (long)blockIdx.x * 256 + threadIdx.x;
    long e = t >> 4;
    if (e >= nedges) return;
    int k = (int)(t & 15);
    int r = row[e];
    int c = col[e];
    float v = val[e];
    float x = Hin[(size_t)c * HIDDEN + k];
    if (relu_in) x = fmaxf(x, 0.0f);
    atomicAdd(&Sout[(size_t)r * HIDDEN + k], v * x);
    if (deg != nullptr && k == 0) atomicAdd(&deg[r], v);
}

// ---------------- out = relu(T @ W2^T + deg*b2)  [n,64] ----------------
__global__ __launch_bounds__(256) void dense2_kernel(
    const float* __restrict__ T, const float* __restrict__ deg,
    const float* __restrict__ W2, const float* __restrict__ b2,
    float* __restrict__ out, int n) {
    __shared__ float w[OUT_SIZE * HIDDEN];
    for (int i = threadIdx.x; i < OUT_SIZE * HIDDEN; i += 256) {
        int o = i / HIDDEN;
        int h = i % HIDDEN;
        w[h * OUT_SIZE + o] = W2[i];
    }
    __syncthreads();
    int node = blockIdx.x * 4 + (threadIdx.x >> 6);
    int o = threadIdx.x & 63;
    if (node >= n) return;
    float acc = deg[node] * b2[o];
#pragma unroll
    for (int h = 0; h < HIDDEN; ++h)
        acc += T[(size_t)node * HIDDEN + h] * w[h * OUT_SIZE + o];
    out[(size_t)node * OUT_SIZE + o] = fmaxf(acc, 0.0f);
}

static inline char* align_up(char* p, size_t a) {
    return (char*)(((uintptr_t)p + a - 1) & ~(uintptr_t)(a - 1));
}

extern "C" void kernel_launch(void* const* d_in, const int* in_sizes, int n_in,
                              void* d_out, int out_size, void* d_ws, size_t ws_size,
                              hipStream_t stream) {
    const int*   index = (const int*)d_in[0];
    const float* value = (const float*)d_in[1];
    const float* X     = (const float*)d_in[4];
    const float* W1    = (const float*)d_in[5];
    const float* b1    = (const float*)d_in[6];
    const float* W2    = (const float*)d_in[7];
    const float* b2    = (const float*)d_in[8];
    float* out = (float*)d_out;

    long nedges = in_sizes[1];
    int  n      = in_sizes[4] / IN_SIZE;
    const int* row = index;
    const int* col = index + nedges;

    // ws: bin[8B*E] | epack[8B*E] | bcnt/bstart/bcur | row_ptr[(n+1)] |
    //     H1h[32n] | Ah[32n] | T[64n] | deg[4n]
    size_t need = (size_t)nedges * 16 + (size_t)(3 * NBUCK + 1) * 4 +
                  (size_t)(n + 1) * 4 + (size_t)n * (32 + 32 + 64 + 4) + 1024;

    if (ws_size >= need && n <= (NBUCK << BSHIFT)) {
        char* p = (char*)d_ws;
        unsigned int* bin = (unsigned int*)p;  p += (size_t)nedges * 8;
        uint2* epack = (uint2*)p;              p += (size_t)nedges * 8;
        int* bcnt   = (int*)p;   p += NBUCK * 4;
        int* bstart = (int*)p;   p += (NBUCK + 1) * 4;
        int* bcur   = (int*)p;   p += NBUCK * 4;
        int* row_ptr = (int*)p;  p += (size_t)(n + 1) * 4;
        p = align_up(p, 64);
        __half2* H1h = (__half2*)p;  p += (size_t)n * 32;
        __half2* Ah  = (__half2*)p;  p += (size_t)n * 32;
        float* T     = (float*)p;    p += (size_t)n * 64;
        float* deg   = (float*)p;

        int nbuck_used = (n + 255) >> BSHIFT;

        zero_int_kernel<<<1, 256, 0, stream>>>(bcnt, NBUCK);
        bhist_kernel<<<(int)((nedges + EBH - 1) / EBH), 256, 0, stream>>>(row, bcnt, nedges);
        bucket_scan_kernel<<<1, NBUCK, 0, stream>>>(bcnt, bstart, bcur, nedges);
        bin_kernel<<<(int)((nedges + EB - 1) / EB), BINBLK, 0, stream>>>(
            row, col, value, bcur, bin, nedges);
        csort_kernel<<<nbuck_used, 512, 0, stream>>>(
            (const uint2*)bin, bstart, row_ptr, epack, n, nedges);

        dense1_half_kernel<<<(n + 63) / 64, 256, 0, stream>>>(X, W1, b1, H1h, n);

        int sblocks = ((n * 4) + 255) / 256;
        // pass 1: Ah = relu(spmm(H1h)) fp16, deg
        spmm_pull_h_kernel<<<sblocks, 256, 0, stream>>>(
            row_ptr, epack, (const uint2*)H1h, (void*)Ah, deg, n, 1, 1);
        // pass 2: T = spmm(Ah) fp32
        spmm_pull_h_kernel<<<sblocks, 256, 0, stream>>>(
            row_ptr, epack, (const uint2*)Ah, (void*)T, nullptr, n, 0, 0);

        dense2_kernel<<<(n + 3) / 4, 256, 0, stream>>>(T, deg, W2, b2, out, n);
    } else {
        // atomic push fallback (fp32 end-to-end)
        float* ws = (float*)d_ws;
        float* H1  = ws;
        float* S1  = H1 + (size_t)n * HIDDEN;
        float* T   = S1 + (size_t)n * HIDDEN;
        float* deg = T + (size_t)n * HIDDEN;
        zero_int_kernel<<<2048, 256, 0, stream>>>((int*)S1, (long)n * (2 * HIDDEN + 1));
        dense1_kernel<<<(n + 15) / 16, 256, 0, stream>>>(X, W1, b1, H1, n);
        long thr1 = nedges * HIDDEN;
        spmm16_kernel<<<(int)((thr1 + 255) / 256), 256, 0, stream>>>(
            row, col, value, H1, S1, deg, nedges, 0);
        spmm16_kernel<<<(int)((thr1 + 255) / 256), 256, 0, stream>>>(
            row, col, value, S1, T, nullptr, nedges, 1);
        dense2_kernel<<<(n + 3) / 4, 256, 0, stream>>>(T, deg, W2, b2, out, n);
    }
}

// Round 9
// 180.268 us; speedup vs baseline: 5.1722x; 1.2066x over previous
//
#include <hip/hip_runtime.h>
#include <hip/hip_fp16.h>

#define IN_SIZE 256
#define HIDDEN 16
#define OUT_SIZE 64
#define NBUCK 512      // bucket = row >> 8 (256 rows each, n <= 131072)
#define BSHIFT 8
#define EB 4096        // edges per bin block
#define BINBLK 512     // threads in bin_kernel (== NBUCK)
#define EPT (EB / BINBLK)  // 8 edges per thread
#define EBH 8192       // edges per bhist block
#define WSTR 20        // LDS row stride (80 B: b128-aligned, 2-way banks)

// ---------------- zero ----------------
__global__ __launch_bounds__(256) void zero_int_kernel(int* __restrict__ a, long n) {
    long i = (long)blockIdx.x * 256 + threadIdx.x;
    long stride = (long)gridDim.x * 256;
    for (; i < n; i += stride) a[i] = 0;
}

// ---------------- H1(fp16) = X @ W1^T + b1  [n,16] ----------------
// 4 lanes per node; W1 in LDS row-stride-20 (b128-aligned, 2-way banks)
__global__ __launch_bounds__(256) void dense1_half_kernel(
    const float* __restrict__ X, const float* __restrict__ W1,
    const float* __restrict__ b1, __half2* __restrict__ H1, int n) {
    __shared__ float w[IN_SIZE * WSTR];  // w[k*20+h] = W1[h][k], 20 KB
    for (int i = threadIdx.x; i < HIDDEN * IN_SIZE; i += 256) {
        int h = i >> 8;
        int k = i & 255;
        w[k * WSTR + h] = W1[i];
    }
    __syncthreads();
    int node = blockIdx.x * 64 + (threadIdx.x >> 2);
    int q = threadIdx.x & 3;
    if (node >= n) return;
    float acc[16];
#pragma unroll
    for (int h = 0; h < 16; ++h) acc[h] = 0.f;
    const float4* xr = reinterpret_cast<const float4*>(X + (size_t)node * IN_SIZE);
#pragma unroll 4
    for (int kk = 0; kk < 16; ++kk) {
        float4 x = xr[q + 4 * kk];
        const float* wr = &w[(kk * 16 + q * 4) * WSTR];
#pragma unroll
        for (int j = 0; j < 4; ++j) {
            float xs = (j == 0) ? x.x : (j == 1) ? x.y : (j == 2) ? x.z : x.w;
            const float* wj = wr + j * WSTR;
#pragma unroll
            for (int h = 0; h < 16; ++h)
                acc[h] += xs * wj[h];
        }
    }
#pragma unroll
    for (int h = 0; h < 16; ++h) {
        acc[h] += __shfl_xor(acc[h], 1, 4);
        acc[h] += __shfl_xor(acc[h], 2, 4);
    }
    const float4 bb = reinterpret_cast<const float4*>(b1)[q];
    int hb = q * 4;
    __half2 o0 = __floats2half2_rn(acc[hb] + bb.x, acc[hb + 1] + bb.y);
    __half2 o1 = __floats2half2_rn(acc[hb + 2] + bb.z, acc[hb + 3] + bb.w);
    uint2 pk;
    pk.x = *reinterpret_cast<unsigned int*>(&o0);
    pk.y = *reinterpret_cast<unsigned int*>(&o1);
    reinterpret_cast<uint2*>(H1)[(size_t)node * 4 + q] = pk;
}

// ---------------- fp32 dense1 (fallback path only) ----------------
__global__ __launch_bounds__(256) void dense1_kernel(
    const float* __restrict__ X, const float* __restrict__ W1,
    const float* __restrict__ b1, float* __restrict__ H1, int n) {
    __shared__ float w[HIDDEN * IN_SIZE];
    for (int i = threadIdx.x; i < HIDDEN * IN_SIZE; i += 256) {
        int h = i >> 8;
        int k = i & 255;
        w[k * HIDDEN + h] = W1[i];
    }
    __syncthreads();
    int t = threadIdx.x;
    int node = blockIdx.x * 16 + (t >> 4);
    int h = t & 15;
    if (node >= n) return;
    const float4* xr = reinterpret_cast<const float4*>(X + (size_t)node * IN_SIZE);
    float acc = b1[h];
#pragma unroll 8
    for (int kk = 0; kk < IN_SIZE / 4; ++kk) {
        float4 x = xr[kk];
        const float* wr = &w[(kk * 4) * HIDDEN + h];
        acc += x.x * wr[0] + x.y * wr[HIDDEN] + x.z * wr[2 * HIDDEN] + x.w * wr[3 * HIDDEN];
    }
    H1[(size_t)node * HIDDEN + h] = acc;
}

// ---------------- bucket histogram (LDS-merged, int4 loads) ----------------
__global__ __launch_bounds__(256) void bhist_kernel(
    const int* __restrict__ row, int* __restrict__ bcnt, long nedges) {
    __shared__ int bh[NBUCK];
    for (int i = threadIdx.x; i < NBUCK; i += 256) bh[i] = 0;
    __syncthreads();
    long base = (long)blockIdx.x * EBH;
    long end = base + EBH;
    if (end > nedges) end = nedges;
    long e = base + (long)threadIdx.x * 4;
    for (; e + 4 <= end; e += 1024) {
        int4 rr = *reinterpret_cast<const int4*>(row + e);
        atomicAdd(&bh[rr.x >> BSHIFT], 1);
        atomicAdd(&bh[rr.y >> BSHIFT], 1);
        atomicAdd(&bh[rr.z >> BSHIFT], 1);
        atomicAdd(&bh[rr.w >> BSHIFT], 1);
    }
    if (e < end) {
        long lim = e + 4 < end ? e + 4 : end;
        for (long x = e; x < lim; ++x) atomicAdd(&bh[row[x] >> BSHIFT], 1);
    }
    __syncthreads();
    for (int i = threadIdx.x; i < NBUCK; i += 256)
        if (bh[i]) atomicAdd(&bcnt[i], bh[i]);
}

// ---------------- bucket exclusive scan ----------------
__global__ __launch_bounds__(512) void bucket_scan_kernel(
    const int* __restrict__ bcnt, int* __restrict__ bstart,
    int* __restrict__ bcur, long nedges) {
    __shared__ int s[NBUCK];
    int tid = threadIdx.x;
    int x = bcnt[tid];
    s[tid] = x;
    __syncthreads();
    for (int off = 1; off < NBUCK; off <<= 1) {
        int t = (tid >= off) ? s[tid - off] : 0;
        __syncthreads();
        s[tid] += t;
        __syncthreads();
    }
    int e = s[tid] - x;
    bstart[tid] = e;
    bcur[tid] = e;
    if (tid == NBUCK - 1) bstart[NBUCK] = (int)nedges;
}

// ---------------- bin edges bucket-major, vectorized single read ----------
// record: x = (local_row<<24)|col, y = val bits
// meta: lr<<24 | bb<<12 | slot
__global__ __launch_bounds__(BINBLK) void bin_kernel(
    const int* __restrict__ row, const int* __restrict__ col,
    const float* __restrict__ val, int* __restrict__ bcur,
    unsigned int* __restrict__ bin, long nedges) {
    __shared__ int hist[NBUCK];
    __shared__ int lbase[NBUCK];
    __shared__ int shiftr[NBUCK];                  // record-unit shift
    __shared__ int s[BINBLK];
    __shared__ unsigned int staged[EB * 2];        // 32 KB
    __shared__ unsigned short sbuck[EB];           // 8 KB
    long base = (long)blockIdx.x * EB;
    int ecount = (int)((nedges - base < (long)EB) ? (nedges - base) : (long)EB);
    int tid = threadIdx.x;
    hist[tid] = 0;   // NBUCK == BINBLK
    __syncthreads();

    unsigned int meta[EPT], cc[EPT], vv[EPT];
    if (ecount == EB) {
        // vector path: 8 consecutive edges per thread (32B-aligned loads)
        long e8 = base + (long)tid * EPT;
        int4 ra = *reinterpret_cast<const int4*>(row + e8);
        int4 rb = *reinterpret_cast<const int4*>(row + e8 + 4);
        int4 ca = *reinterpret_cast<const int4*>(col + e8);
        int4 cb = *reinterpret_cast<const int4*>(col + e8 + 4);
        float4 va = *reinterpret_cast<const float4*>(val + e8);
        float4 vb = *reinterpret_cast<const float4*>(val + e8 + 4);
        int rr[8] = {ra.x, ra.y, ra.z, ra.w, rb.x, rb.y, rb.z, rb.w};
        int cr[8] = {ca.x, ca.y, ca.z, ca.w, cb.x, cb.y, cb.z, cb.w};
        float vr[8] = {va.x, va.y, va.z, va.w, vb.x, vb.y, vb.z, vb.w};
#pragma unroll
        for (int i = 0; i < EPT; ++i) {
            int r = rr[i];
            int bb = r >> BSHIFT;
            int slot = atomicAdd(&hist[bb], 1);
            meta[i] = ((unsigned int)(r & 255) << 24) |
                      ((unsigned int)bb << 12) | (unsigned int)slot;
            cc[i] = (unsigned int)cr[i];
            vv[i] = __float_as_uint(vr[i]);
        }
    } else {
#pragma unroll
        for (int i = 0; i < EPT; ++i) {
            int k = tid * EPT + i;
            meta[i] = 0xFFFFFFFFu;
            if (k < ecount) {
                int r = row[base + k];
                cc[i] = (unsigned int)col[base + k];
                vv[i] = __float_as_uint(val[base + k]);
                int bb = r >> BSHIFT;
                int slot = atomicAdd(&hist[bb], 1);
                meta[i] = ((unsigned int)(r & 255) << 24) |
                          ((unsigned int)bb << 12) | (unsigned int)slot;
            }
        }
    }
    __syncthreads();
    // scan hist (512 wide), reserve global space per bucket
    int x = hist[tid];
    s[tid] = x;
    __syncthreads();
    for (int off = 1; off < BINBLK; off <<= 1) {
        int t = (tid >= off) ? s[tid - off] : 0;
        __syncthreads();
        s[tid] += t;
        __syncthreads();
    }
    int excl = s[tid] - x;
    lbase[tid] = excl;
    if (x > 0) {
        int g = atomicAdd(&bcur[tid], x);
        shiftr[tid] = g - excl;
    }
    __syncthreads();
    // place into LDS staged (bucket-major within block)
#pragma unroll
    for (int i = 0; i < EPT; ++i) {
        if (meta[i] != 0xFFFFFFFFu) {
            int bb = (meta[i] >> 12) & 0x1FF;
            int p = lbase[bb] + (int)(meta[i] & 0xFFF);
            staged[2 * p]     = (meta[i] & 0xFF000000u) | cc[i];
            staged[2 * p + 1] = vv[i];
            sbuck[p] = (unsigned short)bb;
        }
    }
    __syncthreads();
    // copy LDS -> global as 8B records at reserved offsets (coalesced runs)
    uint2* bout = reinterpret_cast<uint2*>(bin);
    for (int j = tid; j < ecount; j += BINBLK) {
        int bb = sbuck[j];
        uint2 rec = make_uint2(staged[2 * j], staged[2 * j + 1]);  // ds_read_b64
        bout[(long)j + shiftr[bb]] = rec;
    }
}

// ---------------- per-bucket LDS counting sort -> row-sorted epack + row_ptr
__global__ __launch_bounds__(512) void csort_kernel(
    const uint2* __restrict__ bin, const int* __restrict__ bstart,
    int* __restrict__ row_ptr, uint2* __restrict__ epack, int n, long nedges) {
    __shared__ int cnt[256];
    __shared__ int cur[256];
    __shared__ int s[256];
    int b = blockIdx.x, tid = threadIdx.x;
    int e0 = bstart[b], e1 = bstart[b + 1];
    if (tid < 256) cnt[tid] = 0;
    __syncthreads();
    for (int e = e0 + tid; e < e1; e += 512)
        atomicAdd(&cnt[bin[e].x >> 24], 1);
    __syncthreads();
    int x = (tid < 256) ? cnt[tid] : 0;
    if (tid < 256) s[tid] = x;
    __syncthreads();
    for (int off = 1; off < 256; off <<= 1) {
        int t = (tid >= off && tid < 256) ? s[tid - off] : 0;
        __syncthreads();
        if (tid < 256) s[tid] += t;
        __syncthreads();
    }
    if (tid < 256) {
        int excl = s[tid] - x;
        int grow = (b << BSHIFT) + tid;
        if (grow < n) row_ptr[grow] = e0 + excl;
        cur[tid] = e0 + excl;
    }
    if (b == 0 && tid == 0) row_ptr[n] = (int)nedges;
    __syncthreads();
    for (int e = e0 + tid; e < e1; e += 512) {
        uint2 rec = bin[e];               // L2-hot
        int lr = rec.x >> 24;
        int p = atomicAdd(&cur[lr], 1);
        epack[p] = make_uint2(rec.x & 0xFFFFFF, rec.y);  // 64KB window scatter
    }
}

// ---------------- pull spmm pass 1: Ah = relu(spmm(H1h)) fp16, deg --------
__device__ __forceinline__ void fma_h(float4& a, uint2 h, float v) {
    __half2 lo = *reinterpret_cast<const __half2*>(&h.x);
    __half2 hi = *reinterpret_cast<const __half2*>(&h.y);
    float2 f0 = __half22float2(lo), f1 = __half22float2(hi);
    a.x += v * f0.x; a.y += v * f0.y; a.z += v * f1.x; a.w += v * f1.y;
}

__global__ __launch_bounds__(256) void spmm_pull_h_kernel(
    const int* __restrict__ row_ptr, const uint2* __restrict__ epack,
    const uint2* __restrict__ Hin, void* __restrict__ Sout,
    float* __restrict__ deg, int n, int relu_out, int out_half) {
    int t = blockIdx.x * 256 + threadIdx.x;
    int r = t >> 2, q = t & 3;
    if (r >= n) return;
    int e0 = row_ptr[r], e1 = row_ptr[r + 1];
    float4 a0 = {0,0,0,0}, a1 = {0,0,0,0}, a2 = {0,0,0,0}, a3 = {0,0,0,0};
    float d = 0.f;
    int e = e0;
    for (; e + 4 <= e1; e += 4) {
        uint2 r0 = epack[e], r1 = epack[e + 1], r2 = epack[e + 2], r3 = epack[e + 3];
        uint2 h0 = Hin[(size_t)r0.x * 4 + q];
        uint2 h1 = Hin[(size_t)r1.x * 4 + q];
        uint2 h2 = Hin[(size_t)r2.x * 4 + q];
        uint2 h3 = Hin[(size_t)r3.x * 4 + q];
        float v0 = __uint_as_float(r0.y), v1 = __uint_as_float(r1.y);
        float v2 = __uint_as_float(r2.y), v3 = __uint_as_float(r3.y);
        fma_h(a0, h0, v0); fma_h(a1, h1, v1);
        fma_h(a2, h2, v2); fma_h(a3, h3, v3);
        d += v0 + v1 + v2 + v3;
    }
    for (; e < e1; ++e) {
        uint2 rr = epack[e];
        uint2 h = Hin[(size_t)rr.x * 4 + q];
        float v = __uint_as_float(rr.y);
        fma_h(a0, h, v);
        d += v;
    }
    a0.x += a1.x + a2.x + a3.x;
    a0.y += a1.y + a2.y + a3.y;
    a0.z += a1.z + a2.z + a3.z;
    a0.w += a1.w + a2.w + a3.w;
    if (relu_out) {
        a0.x = fmaxf(a0.x, 0.f); a0.y = fmaxf(a0.y, 0.f);
        a0.z = fmaxf(a0.z, 0.f); a0.w = fmaxf(a0.w, 0.f);
    }
    if (out_half) {
        __half2* O = (__half2*)Sout;
        O[(size_t)r * 8 + 2 * q]     = __floats2half2_rn(a0.x, a0.y);
        O[(size_t)r * 8 + 2 * q + 1] = __floats2half2_rn(a0.z, a0.w);
    } else {
        reinterpret_cast<float4*>((float*)Sout + (size_t)r * 16)[q] = a0;
    }
    if (deg != nullptr && q == 0) deg[r] = d;
}

// ---------------- fused pass 2: out = relu(spmm(Ah) @ W2^T + deg*b2) ------
__global__ __launch_bounds__(256) void spmm2_out_kernel(
    const int* __restrict__ row_ptr, const uint2* __restrict__ epack,
    const uint2* __restrict__ Hin, const float* __restrict__ W2,
    const float* __restrict__ b2, const float* __restrict__ deg,
    float* __restrict__ out, int n) {
    __shared__ float w2[HIDDEN * OUT_SIZE];   // w2[h*64+o] = W2[o][h], 4 KB
    __shared__ float b2s[OUT_SIZE];
    __shared__ float tT[64 * WSTR];           // 5 KB, b128-aligned rows
    int tid = threadIdx.x;
    for (int i = tid; i < HIDDEN * OUT_SIZE; i += 256)
        w2[(i & 15) * OUT_SIZE + (i >> 4)] = W2[i];
    if (tid < OUT_SIZE) b2s[tid] = b2[tid];
    int t = blockIdx.x * 256 + tid;
    int r = t >> 2, q = t & 3, lr = tid >> 2;
    if (r < n) {
        int e0 = row_ptr[r], e1 = row_ptr[r + 1];
        float4 a0 = {0,0,0,0}, a1 = {0,0,0,0}, a2 = {0,0,0,0}, a3 = {0,0,0,0};
        int e = e0;
        for (; e + 4 <= e1; e += 4) {
            uint2 r0 = epack[e], r1 = epack[e + 1], r2 = epack[e + 2], r3 = epack[e + 3];
            uint2 h0 = Hin[(size_t)r0.x * 4 + q];
            uint2 h1 = Hin[(size_t)r1.x * 4 + q];
            uint2 h2 = Hin[(size_t)r2.x * 4 + q];
            uint2 h3 = Hin[(size_t)r3.x * 4 + q];
            fma_h(a0, h0, __uint_as_float(r0.y));
            fma_h(a1, h1, __uint_as_float(r1.y));
            fma_h(a2, h2, __uint_as_float(r2.y));
            fma_h(a3, h3, __uint_as_float(r3.y));
        }
        for (; e < e1; ++e) {
            uint2 rr = epack[e];
            uint2 h = Hin[(size_t)rr.x * 4 + q];
            fma_h(a0, h, __uint_as_float(rr.y));
        }
        a0.x += a1.x + a2.x + a3.x;
        a0.y += a1.y + a2.y + a3.y;
        a0.z += a1.z + a2.z + a3.z;
        a0.w += a1.w + a2.w + a3.w;
        *reinterpret_cast<float4*>(&tT[lr * WSTR + 4 * q]) = a0;  // 16B aligned
    }
    __syncthreads();
    if (r < n) {
        float dg = deg[r];
        int ob = q * 16;
        const float4* bp = reinterpret_cast<const float4*>(&b2s[ob]);
        float4 c0 = bp[0], c1 = bp[1], c2 = bp[2], c3 = bp[3];
        c0.x *= dg; c0.y *= dg; c0.z *= dg; c0.w *= dg;
        c1.x *= dg; c1.y *= dg; c1.z *= dg; c1.w *= dg;
        c2.x *= dg; c2.y *= dg; c2.z *= dg; c2.w *= dg;
        c3.x *= dg; c3.y *= dg; c3.z *= dg; c3.w *= dg;
#pragma unroll
        for (int h = 0; h < 16; ++h) {
            float th = tT[lr * WSTR + h];          // quad-broadcast
            const float4* wp = reinterpret_cast<const float4*>(&w2[h * OUT_SIZE + ob]);
            float4 w0 = wp[0], w1 = wp[1], w2v = wp[2], w3 = wp[3];
            c0.x += th * w0.x; c0.y += th * w0.y; c0.z += th * w0.z; c0.w += th * w0.w;
            c1.x += th * w1.x; c1.y += th * w1.y; c1.z += th * w1.z; c1.w += th * w1.w;
            c2.x += th * w2v.x; c2.y += th * w2v.y; c2.z += th * w2v.z; c2.w += th * w2v.w;
            c3.x += th * w3.x; c3.y += th * w3.y; c3.z += th * w3.z; c3.w += th * w3.w;
        }
        c0.x = fmaxf(c0.x, 0.f); c0.y = fmaxf(c0.y, 0.f); c0.z = fmaxf(c0.z, 0.f); c0.w = fmaxf(c0.w, 0.f);
        c1.x = fmaxf(c1.x, 0.f); c1.y = fmaxf(c1.y, 0.f); c1.z = fmaxf(c1.z, 0.f); c1.w = fmaxf(c1.w, 0.f);
        c2.x = fmaxf(c2.x, 0.f); c2.y = fmaxf(c2.y, 0.f); c2.z = fmaxf(c2.z, 0.f); c2.w = fmaxf(c2.w, 0.f);
        c3.x = fmaxf(c3.x, 0.f); c3.y = fmaxf(c3.y, 0.f); c3.z = fmaxf(c3.z, 0.f); c3.w = fmaxf(c3.w, 0.f);
        float4* op = reinterpret_cast<float4*>(out + (size_t)r * OUT_SIZE + ob);
        op[0] = c0; op[1] = c1; op[2] = c2; op[3] = c3;
    }
}

// ---------------- atomic push spmm (fallback only) ----------------
__global__ __launch_bounds__(256) void spmm16_kernel(
    const int* __restrict__ row, const int* __restrict__ col,
    const float* __restrict__ val, const float* __restrict__ Hin,
    float* __restrict__ Sout, float* __restrict__ deg, long nedges, int relu_in) {
    long t = (long)blockIdx.x * 256 + threadIdx.x;
    long e = t >> 4;
    if (e >= nedges) return;
    int k = (int)(t & 15);
    int r = row[e];
    int c = col[e];
    float v = val[e];
    float x = Hin[(size_t)c * HIDDEN + k];
    if (relu_in) x = fmaxf(x, 0.0f);
    atomicAdd(&Sout[(size_t)r * HIDDEN + k], v * x);
    if (deg != nullptr && k == 0) atomicAdd(&deg[r], v);
}

// ---------------- out = relu(T @ W2^T + deg*b2)  (fallback only) ----------
__global__ __launch_bounds__(256) void dense2_kernel(
    const float* __restrict__ T, const float* __restrict__ deg,
    const float* __restrict__ W2, const float* __restrict__ b2,
    float* __restrict__ out, int n) {
    __shared__ float w[OUT_SIZE * HIDDEN];
    for (int i = threadIdx.x; i < OUT_SIZE * HIDDEN; i += 256) {
        int o = i / HIDDEN;
        int h = i % HIDDEN;
        w[h * OUT_SIZE + o] = W2[i];
    }
    __syncthreads();
    int node = blockIdx.x * 4 + (threadIdx.x >> 6);
    int o = threadIdx.x & 63;
    if (node >= n) return;
    float acc = deg[node] * b2[o];
#pragma unroll
    for (int h = 0; h < HIDDEN; ++h)
        acc += T[(size_t)node * HIDDEN + h] * w[h * OUT_SIZE + o];
    out[(size_t)node * OUT_SIZE + o] = fmaxf(acc, 0.0f);
}

static inline char* align_up(char* p, size_t a) {
    return (char*)(((uintptr_t)p + a - 1) & ~(uintptr_t)(a - 1));
}

extern "C" void kernel_launch(void* const* d_in, const int* in_sizes, int n_in,
                              void* d_out, int out_size, void* d_ws, size_t ws_size,
                              hipStream_t stream) {
    const int*   index = (const int*)d_in[0];
    const float* value = (const float*)d_in[1];
    const float* X     = (const float*)d_in[4];
    const float* W1    = (const float*)d_in[5];
    const float* b1    = (const float*)d_in[6];
    const float* W2    = (const float*)d_in[7];
    const float* b2    = (const float*)d_in[8];
    float* out = (float*)d_out;

    long nedges = in_sizes[1];
    int  n      = in_sizes[4] / IN_SIZE;
    const int* row = index;
    const int* col = index + nedges;

    // ws: bin[8B*E] | epack[8B*E] | bcnt/bstart/bcur | row_ptr[(n+1)] |
    //     H1h[32n] | Ah[32n] | deg[4n]
    size_t need = (size_t)nedges * 16 + (size_t)(3 * NBUCK + 1) * 4 +
                  (size_t)(n + 1) * 4 + (size_t)n * (32 + 32 + 4) + 1024;

    if (ws_size >= need && n <= (NBUCK << BSHIFT)) {
        char* p = (char*)d_ws;
        unsigned int* bin = (unsigned int*)p;  p += (size_t)nedges * 8;
        uint2* epack = (uint2*)p;              p += (size_t)nedges * 8;
        int* bcnt   = (int*)p;   p += NBUCK * 4;
        int* bstart = (int*)p;   p += (NBUCK + 1) * 4;
        int* bcur   = (int*)p;   p += NBUCK * 4;
        int* row_ptr = (int*)p;  p += (size_t)(n + 1) * 4;
        p = align_up(p, 64);
        __half2* H1h = (__half2*)p;  p += (size_t)n * 32;
        __half2* Ah  = (__half2*)p;  p += (size_t)n * 32;
        float* deg   = (float*)p;

        int nbuck_used = (n + 255) >> BSHIFT;

        zero_int_kernel<<<1, 256, 0, stream>>>(bcnt, NBUCK);
        bhist_kernel<<<(int)((nedges + EBH - 1) / EBH), 256, 0, stream>>>(row, bcnt, nedges);
        bucket_scan_kernel<<<1, NBUCK, 0, stream>>>(bcnt, bstart, bcur, nedges);
        bin_kernel<<<(int)((nedges + EB - 1) / EB), BINBLK, 0, stream>>>(
            row, col, value, bcur, bin, nedges);
        csort_kernel<<<nbuck_used, 512, 0, stream>>>(
            (const uint2*)bin, bstart, row_ptr, epack, n, nedges);

        dense1_half_kernel<<<(n + 63) / 64, 256, 0, stream>>>(X, W1, b1, H1h, n);

        int sblocks = ((n * 4) + 255) / 256;
        // pass 1: Ah = relu(spmm(H1h)) fp16, deg
        spmm_pull_h_kernel<<<sblocks, 256, 0, stream>>>(
            row_ptr, epack, (const uint2*)H1h, (void*)Ah, deg, n, 1, 1);
        // pass 2 fused with dense2: out = relu(spmm(Ah) @ W2^T + deg*b2)
        spmm2_out_kernel<<<sblocks, 256, 0, stream>>>(
            row_ptr, epack, (const uint2*)Ah, W2, b2, deg, out, n);
    } else {
        // atomic push fallback (fp32 end-to-end)
        float* ws = (float*)d_ws;
        float* H1  = ws;
        float* S1  = H1 + (size_t)n * HIDDEN;
        float* T   = S1 + (size_t)n * HIDDEN;
        float* deg = T + (size_t)n * HIDDEN;
        zero_int_kernel<<<2048, 256, 0, stream>>>((int*)S1, (long)n * (2 * HIDDEN + 1));
        dense1_kernel<<<(n + 15) / 16, 256, 0, stream>>>(X, W1, b1, H1, n);
        long thr1 = nedges * HIDDEN;
        spmm16_kernel<<<(int)((thr1 + 255) / 256), 256, 0, stream>>>(
            row, col, value, H1, S1, deg, nedges, 0);
        spmm16_kernel<<<(int)((thr1 + 255) / 256), 256, 0, stream>>>(
            row, col, value, S1, T, nullptr, nedges, 1);
        dense2_kernel<<<(n + 3) / 4, 256, 0, stream>>>(T, deg, W2, b2, out, n);
    }
}

// Round 10
// 163.103 us; speedup vs baseline: 5.7164x; 1.1052x over previous
//
#include <hip/hip_runtime.h>
#include <hip/hip_fp16.h>

#define IN_SIZE 256
#define HIDDEN 16
#define OUT_SIZE 64
#define BSHIFT 7            // bucket = row >> 7 (128 rows each)
#define BROWS 128
#define NBUCK 1024          // supports n <= 131072
#define EB 4096             // edges per bin block
#define BINBLK 512
#define EPT (EB / BINBLK)   // 8 edges per thread
#define EBH 8192            // edges per bhist block
#define WSTR 20             // LDS row stride (80 B: b128-aligned, 2-way banks)
#define CAP 6144            // max LDS-resident records per bucket (49 KB)

// ---------------- zero ----------------
__global__ __launch_bounds__(256) void zero_int_kernel(int* __restrict__ a, long n) {
    long i = (long)blockIdx.x * 256 + threadIdx.x;
    long stride = (long)gridDim.x * 256;
    for (; i < n; i += stride) a[i] = 0;
}

// ---------------- H1(fp16) = X @ W1^T + b1  [n,16] ----------------
__global__ __launch_bounds__(256) void dense1_half_kernel(
    const float* __restrict__ X, const float* __restrict__ W1,
    const float* __restrict__ b1, __half2* __restrict__ H1, int n) {
    __shared__ float w[IN_SIZE * WSTR];  // w[k*20+h] = W1[h][k], 20 KB
    for (int i = threadIdx.x; i < HIDDEN * IN_SIZE; i += 256) {
        int h = i >> 8;
        int k = i & 255;
        w[k * WSTR + h] = W1[i];
    }
    __syncthreads();
    int node = blockIdx.x * 64 + (threadIdx.x >> 2);
    int q = threadIdx.x & 3;
    if (node >= n) return;
    float acc[16];
#pragma unroll
    for (int h = 0; h < 16; ++h) acc[h] = 0.f;
    const float4* xr = reinterpret_cast<const float4*>(X + (size_t)node * IN_SIZE);
#pragma unroll 4
    for (int kk = 0; kk < 16; ++kk) {
        float4 x = xr[q + 4 * kk];
        const float* wr = &w[(kk * 16 + q * 4) * WSTR];
#pragma unroll
        for (int j = 0; j < 4; ++j) {
            float xs = (j == 0) ? x.x : (j == 1) ? x.y : (j == 2) ? x.z : x.w;
            const float* wj = wr + j * WSTR;
#pragma unroll
            for (int h = 0; h < 16; ++h)
                acc[h] += xs * wj[h];
        }
    }
#pragma unroll
    for (int h = 0; h < 16; ++h) {
        acc[h] += __shfl_xor(acc[h], 1, 4);
        acc[h] += __shfl_xor(acc[h], 2, 4);
    }
    const float4 bb = reinterpret_cast<const float4*>(b1)[q];
    int hb = q * 4;
    __half2 o0 = __floats2half2_rn(acc[hb] + bb.x, acc[hb + 1] + bb.y);
    __half2 o1 = __floats2half2_rn(acc[hb + 2] + bb.z, acc[hb + 3] + bb.w);
    uint2 pk;
    pk.x = *reinterpret_cast<unsigned int*>(&o0);
    pk.y = *reinterpret_cast<unsigned int*>(&o1);
    reinterpret_cast<uint2*>(H1)[(size_t)node * 4 + q] = pk;
}

// ---------------- fp32 dense1 (fallback path only) ----------------
__global__ __launch_bounds__(256) void dense1_kernel(
    const float* __restrict__ X, const float* __restrict__ W1,
    const float* __restrict__ b1, float* __restrict__ H1, int n) {
    __shared__ float w[HIDDEN * IN_SIZE];
    for (int i = threadIdx.x; i < HIDDEN * IN_SIZE; i += 256) {
        int h = i >> 8;
        int k = i & 255;
        w[k * HIDDEN + h] = W1[i];
    }
    __syncthreads();
    int t = threadIdx.x;
    int node = blockIdx.x * 16 + (t >> 4);
    int h = t & 15;
    if (node >= n) return;
    const float4* xr = reinterpret_cast<const float4*>(X + (size_t)node * IN_SIZE);
    float acc = b1[h];
#pragma unroll 8
    for (int kk = 0; kk < IN_SIZE / 4; ++kk) {
        float4 x = xr[kk];
        const float* wr = &w[(kk * 4) * HIDDEN + h];
        acc += x.x * wr[0] + x.y * wr[HIDDEN] + x.z * wr[2 * HIDDEN] + x.w * wr[3 * HIDDEN];
    }
    H1[(size_t)node * HIDDEN + h] = acc;
}

// ---------------- bucket histogram (LDS-merged, int4 loads) ----------------
__global__ __launch_bounds__(256) void bhist_kernel(
    const int* __restrict__ row, int* __restrict__ bcnt, long nedges) {
    __shared__ int bh[NBUCK];
    for (int i = threadIdx.x; i < NBUCK; i += 256) bh[i] = 0;
    __syncthreads();
    long base = (long)blockIdx.x * EBH;
    long end = base + EBH;
    if (end > nedges) end = nedges;
    long e = base + (long)threadIdx.x * 4;
    for (; e + 4 <= end; e += 1024) {
        int4 rr = *reinterpret_cast<const int4*>(row + e);
        atomicAdd(&bh[rr.x >> BSHIFT], 1);
        atomicAdd(&bh[rr.y >> BSHIFT], 1);
        atomicAdd(&bh[rr.z >> BSHIFT], 1);
        atomicAdd(&bh[rr.w >> BSHIFT], 1);
    }
    if (e < end) {
        long lim = e + 4 < end ? e + 4 : end;
        for (long x = e; x < lim; ++x) atomicAdd(&bh[row[x] >> BSHIFT], 1);
    }
    __syncthreads();
    for (int i = threadIdx.x; i < NBUCK; i += 256)
        if (bh[i]) atomicAdd(&bcnt[i], bh[i]);
}

// ---------------- bucket exclusive scan (1024 wide, pairwise) --------------
__global__ __launch_bounds__(512) void bucket_scan_kernel(
    const int* __restrict__ bcnt, int* __restrict__ bstart,
    int* __restrict__ bcur, long nedges) {
    __shared__ int s[512];
    int tid = threadIdx.x;
    int a = bcnt[2 * tid], b = bcnt[2 * tid + 1];
    int ps = a + b;
    s[tid] = ps;
    __syncthreads();
    for (int off = 1; off < 512; off <<= 1) {
        int t = (tid >= off) ? s[tid - off] : 0;
        __syncthreads();
        s[tid] += t;
        __syncthreads();
    }
    int excl = s[tid] - ps;
    bstart[2 * tid] = excl;      bcur[2 * tid] = excl;
    bstart[2 * tid + 1] = excl + a; bcur[2 * tid + 1] = excl + a;
    if (tid == 511) bstart[NBUCK] = (int)nedges;
}

// ---------------- bin edges bucket-major, vectorized single read ----------
// record: x = (local_row<<24)|col ; y = val bits
// meta: lr<<25 | bb<<12 | slot   (slot < 4096, bb < 1024, lr < 128)
__global__ __launch_bounds__(BINBLK) void bin_kernel(
    const int* __restrict__ row, const int* __restrict__ col,
    const float* __restrict__ val, int* __restrict__ bcur,
    unsigned int* __restrict__ bin, long nedges) {
    __shared__ int hist[NBUCK];
    __shared__ int lbase[NBUCK];
    __shared__ int shiftr[NBUCK];
    __shared__ int s[BINBLK];
    __shared__ unsigned int staged[EB * 2];        // 32 KB
    __shared__ unsigned short sbuck[EB];           // 8 KB
    long base = (long)blockIdx.x * EB;
    int ecount = (int)((nedges - base < (long)EB) ? (nedges - base) : (long)EB);
    int tid = threadIdx.x;
    for (int i = tid; i < NBUCK; i += BINBLK) hist[i] = 0;
    __syncthreads();

    unsigned int meta[EPT], cc[EPT], vv[EPT];
    if (ecount == EB) {
        long e8 = base + (long)tid * EPT;
        int4 ra = *reinterpret_cast<const int4*>(row + e8);
        int4 rb = *reinterpret_cast<const int4*>(row + e8 + 4);
        int4 ca = *reinterpret_cast<const int4*>(col + e8);
        int4 cb = *reinterpret_cast<const int4*>(col + e8 + 4);
        float4 va = *reinterpret_cast<const float4*>(val + e8);
        float4 vb = *reinterpret_cast<const float4*>(val + e8 + 4);
        int rr[8] = {ra.x, ra.y, ra.z, ra.w, rb.x, rb.y, rb.z, rb.w};
        int cr[8] = {ca.x, ca.y, ca.z, ca.w, cb.x, cb.y, cb.z, cb.w};
        float vr[8] = {va.x, va.y, va.z, va.w, vb.x, vb.y, vb.z, vb.w};
#pragma unroll
        for (int i = 0; i < EPT; ++i) {
            int r = rr[i];
            int bb = r >> BSHIFT;
            int slot = atomicAdd(&hist[bb], 1);
            meta[i] = ((unsigned int)(r & (BROWS - 1)) << 25) |
                      ((unsigned int)bb << 12) | (unsigned int)slot;
            cc[i] = (unsigned int)cr[i];
            vv[i] = __float_as_uint(vr[i]);
        }
    } else {
#pragma unroll
        for (int i = 0; i < EPT; ++i) {
            int k = tid * EPT + i;
            meta[i] = 0xFFFFFFFFu;
            if (k < ecount) {
                int r = row[base + k];
                cc[i] = (unsigned int)col[base + k];
                vv[i] = __float_as_uint(val[base + k]);
                int bb = r >> BSHIFT;
                int slot = atomicAdd(&hist[bb], 1);
                meta[i] = ((unsigned int)(r & (BROWS - 1)) << 25) |
                          ((unsigned int)bb << 12) | (unsigned int)slot;
            }
        }
    }
    __syncthreads();
    // pairwise scan of 1024 buckets with 512 threads; reserve global space
    int a = hist[2 * tid], b = hist[2 * tid + 1];
    int ps = a + b;
    s[tid] = ps;
    __syncthreads();
    for (int off = 1; off < BINBLK; off <<= 1) {
        int t = (tid >= off) ? s[tid - off] : 0;
        __syncthreads();
        s[tid] += t;
        __syncthreads();
    }
    int excl = s[tid] - ps;
    lbase[2 * tid] = excl;
    lbase[2 * tid + 1] = excl + a;
    if (a > 0) {
        int g = atomicAdd(&bcur[2 * tid], a);
        shiftr[2 * tid] = g - excl;
    }
    if (b > 0) {
        int g = atomicAdd(&bcur[2 * tid + 1], b);
        shiftr[2 * tid + 1] = g - (excl + a);
    }
    __syncthreads();
    // place into LDS staged (bucket-major within block)
#pragma unroll
    for (int i = 0; i < EPT; ++i) {
        if (meta[i] != 0xFFFFFFFFu) {
            int bb = (meta[i] >> 12) & 0x3FF;
            int p = lbase[bb] + (int)(meta[i] & 0xFFF);
            staged[2 * p]     = ((meta[i] >> 25) << 24) | cc[i];
            staged[2 * p + 1] = vv[i];
            sbuck[p] = (unsigned short)bb;
        }
    }
    __syncthreads();
    // copy LDS -> global as 8B records at reserved offsets (coalesced runs)
    uint2* bout = reinterpret_cast<uint2*>(bin);
    for (int j = tid; j < ecount; j += BINBLK) {
        int bb = sbuck[j];
        uint2 rec = make_uint2(staged[2 * j], staged[2 * j + 1]);
        bout[(long)j + shiftr[bb]] = rec;
    }
}

// ---------------- fused: per-bucket counting sort + spmm pass 1 ------------
// One 512-thread block per 128-row bucket. Sort records into LDS, write
// row_ptr + contiguous epack (for pass 2), then pull-spmm from LDS:
// Ah = relu(spmm(H1h)) fp16, deg.
__device__ __forceinline__ void fma_h(float4& a, uint2 h, float v) {
    __half2 lo = *reinterpret_cast<const __half2*>(&h.x);
    __half2 hi = *reinterpret_cast<const __half2*>(&h.y);
    float2 f0 = __half22float2(lo), f1 = __half22float2(hi);
    a.x += v * f0.x; a.y += v * f0.y; a.z += v * f1.x; a.w += v * f1.y;
}

__global__ __launch_bounds__(512) void csort_spmm1_kernel(
    const uint2* __restrict__ bin, const int* __restrict__ bstart,
    int* __restrict__ row_ptr, uint2* __restrict__ epack,
    const uint2* __restrict__ Hin, __half2* __restrict__ Ah,
    float* __restrict__ deg, int n, long nedges) {
    __shared__ int cnt[BROWS];
    __shared__ int cur[BROWS];
    __shared__ int sbase[BROWS];
    __shared__ int s[BROWS];
    __shared__ uint2 eld[CAP];                     // 48 KB
    int b = blockIdx.x, tid = threadIdx.x;
    int e0 = bstart[b], e1 = bstart[b + 1];
    int m = e1 - e0;
    bool fits = (m <= CAP);
    if (tid < BROWS) cnt[tid] = 0;
    __syncthreads();
    for (int e = e0 + tid; e < e1; e += 512)
        atomicAdd(&cnt[bin[e].x >> 24], 1);
    __syncthreads();
    int x = (tid < BROWS) ? cnt[tid] : 0;
    if (tid < BROWS) s[tid] = x;
    __syncthreads();
    for (int off = 1; off < BROWS; off <<= 1) {
        int t = (tid >= off && tid < BROWS) ? s[tid - off] : 0;
        __syncthreads();
        if (tid < BROWS) s[tid] += t;
        __syncthreads();
    }
    if (tid < BROWS) {
        int excl = s[tid] - x;
        sbase[tid] = excl;
        int grow = (b << BSHIFT) + tid;
        if (grow < n) row_ptr[grow] = e0 + excl;
        cur[tid] = fits ? excl : (e0 + excl);
    }
    if (b == 0 && tid == 0) row_ptr[n] = (int)nedges;
    __syncthreads();
    // scatter into LDS (or directly to global epack if oversized bucket)
    for (int e = e0 + tid; e < e1; e += 512) {
        uint2 rec = bin[e];                        // 32KB segment, L2-hot
        int lr = rec.x >> 24;
        int p = atomicAdd(&cur[lr], 1);
        uint2 o = make_uint2(rec.x & 0xFFFFFF, rec.y);
        if (fits) eld[p] = o; else epack[p] = o;
    }
    __syncthreads();
    // contiguous coalesced copy LDS -> global epack (needed by pass 2)
    if (fits)
        for (int j = tid; j < m; j += 512) epack[e0 + j] = eld[j];
    // ---- spmm for this bucket's 128 rows, 4 lanes per row ----
    int lr = tid >> 2, q = tid & 3;
    int r = (b << BSHIFT) + lr;
    if (r >= n) return;
    int s0 = sbase[lr];
    int s1 = s0 + cnt[lr];
    float4 a0 = {0,0,0,0}, a1 = {0,0,0,0}, a2 = {0,0,0,0}, a3 = {0,0,0,0};
    float d = 0.f;
    if (fits) {
        int e = s0;
        for (; e + 4 <= s1; e += 4) {
            uint2 r0 = eld[e], r1 = eld[e + 1], r2 = eld[e + 2], r3 = eld[e + 3];
            uint2 h0 = Hin[(size_t)r0.x * 4 + q];
            uint2 h1 = Hin[(size_t)r1.x * 4 + q];
            uint2 h2 = Hin[(size_t)r2.x * 4 + q];
            uint2 h3 = Hin[(size_t)r3.x * 4 + q];
            float v0 = __uint_as_float(r0.y), v1 = __uint_as_float(r1.y);
            float v2 = __uint_as_float(r2.y), v3 = __uint_as_float(r3.y);
            fma_h(a0, h0, v0); fma_h(a1, h1, v1);
            fma_h(a2, h2, v2); fma_h(a3, h3, v3);
            d += v0 + v1 + v2 + v3;
        }
        for (; e < s1; ++e) {
            uint2 rr = eld[e];
            uint2 h = Hin[(size_t)rr.x * 4 + q];
            float v = __uint_as_float(rr.y);
            fma_h(a0, h, v);
            d += v;
        }
    } else {
        for (int e = e0 + s0; e < e0 + s1; ++e) {
            uint2 rr = epack[e];
            uint2 h = Hin[(size_t)rr.x * 4 + q];
            float v = __uint_as_float(rr.y);
            fma_h(a0, h, v);
            d += v;
        }
    }
    a0.x += a1.x + a2.x + a3.x;
    a0.y += a1.y + a2.y + a3.y;
    a0.z += a1.z + a2.z + a3.z;
    a0.w += a1.w + a2.w + a3.w;
    a0.x = fmaxf(a0.x, 0.f); a0.y = fmaxf(a0.y, 0.f);
    a0.z = fmaxf(a0.z, 0.f); a0.w = fmaxf(a0.w, 0.f);
    __half2 o0 = __floats2half2_rn(a0.x, a0.y);
    __half2 o1 = __floats2half2_rn(a0.z, a0.w);
    uint2 pk;
    pk.x = *reinterpret_cast<unsigned int*>(&o0);
    pk.y = *reinterpret_cast<unsigned int*>(&o1);
    reinterpret_cast<uint2*>(Ah)[(size_t)r * 4 + q] = pk;
    if (q == 0) deg[r] = d;
}

// ---------------- fused pass 2: out = relu(spmm(Ah) @ W2^T + deg*b2) ------
__global__ __launch_bounds__(256) void spmm2_out_kernel(
    const int* __restrict__ row_ptr, const uint2* __restrict__ epack,
    const uint2* __restrict__ Hin, const float* __restrict__ W2,
    const float* __restrict__ b2, const float* __restrict__ deg,
    float* __restrict__ out, int n) {
    __shared__ float w2[HIDDEN * OUT_SIZE];   // w2[h*64+o] = W2[o][h], 4 KB
    __shared__ float b2s[OUT_SIZE];
    __shared__ float tT[64 * WSTR];           // 5 KB, b128-aligned rows
    int tid = threadIdx.x;
    for (int i = tid; i < HIDDEN * OUT_SIZE; i += 256)
        w2[(i & 15) * OUT_SIZE + (i >> 4)] = W2[i];
    if (tid < OUT_SIZE) b2s[tid] = b2[tid];
    int t = blockIdx.x * 256 + tid;
    int r = t >> 2, q = t & 3, lr = tid >> 2;
    if (r < n) {
        int e0 = row_ptr[r], e1 = row_ptr[r + 1];
        float4 a0 = {0,0,0,0}, a1 = {0,0,0,0}, a2 = {0,0,0,0}, a3 = {0,0,0,0};
        int e = e0;
        for (; e + 4 <= e1; e += 4) {
            uint2 r0 = epack[e], r1 = epack[e + 1], r2 = epack[e + 2], r3 = epack[e + 3];
            uint2 h0 = Hin[(size_t)r0.x * 4 + q];
            uint2 h1 = Hin[(size_t)r1.x * 4 + q];
            uint2 h2 = Hin[(size_t)r2.x * 4 + q];
            uint2 h3 = Hin[(size_t)r3.x * 4 + q];
            fma_h(a0, h0, __uint_as_float(r0.y));
            fma_h(a1, h1, __uint_as_float(r1.y));
            fma_h(a2, h2, __uint_as_float(r2.y));
            fma_h(a3, h3, __uint_as_float(r3.y));
        }
        for (; e < e1; ++e) {
            uint2 rr = epack[e];
            uint2 h = Hin[(size_t)rr.x * 4 + q];
            fma_h(a0, h, __uint_as_float(rr.y));
        }
        a0.x += a1.x + a2.x + a3.x;
        a0.y += a1.y + a2.y + a3.y;
        a0.z += a1.z + a2.z + a3.z;
        a0.w += a1.w + a2.w + a3.w;
        *reinterpret_cast<float4*>(&tT[lr * WSTR + 4 * q]) = a0;
    }
    __syncthreads();
    if (r < n) {
        float dg = deg[r];
        int ob = q * 16;
        const float4* bp = reinterpret_cast<const float4*>(&b2s[ob]);
        float4 c0 = bp[0], c1 = bp[1], c2 = bp[2], c3 = bp[3];
        c0.x *= dg; c0.y *= dg; c0.z *= dg; c0.w *= dg;
        c1.x *= dg; c1.y *= dg; c1.z *= dg; c1.w *= dg;
        c2.x *= dg; c2.y *= dg; c2.z *= dg; c2.w *= dg;
        c3.x *= dg; c3.y *= dg; c3.z *= dg; c3.w *= dg;
#pragma unroll
        for (int h = 0; h < 16; ++h) {
            float th = tT[lr * WSTR + h];
            const float4* wp = reinterpret_cast<const float4*>(&w2[h * OUT_SIZE + ob]);
            float4 w0 = wp[0], w1 = wp[1], w2v = wp[2], w3 = wp[3];
            c0.x += th * w0.x; c0.y += th * w0.y; c0.z += th * w0.z; c0.w += th * w0.w;
            c1.x += th * w1.x; c1.y += th * w1.y; c1.z += th * w1.z; c1.w += th * w1.w;
            c2.x += th * w2v.x; c2.y += th * w2v.y; c2.z += th * w2v.z; c2.w += th * w2v.w;
            c3.x += th * w3.x; c3.y += th * w3.y; c3.z += th * w3.z; c3.w += th * w3.w;
        }
        c0.x = fmaxf(c0.x, 0.f); c0.y = fmaxf(c0.y, 0.f); c0.z = fmaxf(c0.z, 0.f); c0.w = fmaxf(c0.w, 0.f);
        c1.x = fmaxf(c1.x, 0.f); c1.y = fmaxf(c1.y, 0.f); c1.z = fmaxf(c1.z, 0.f); c1.w = fmaxf(c1.w, 0.f);
        c2.x = fmaxf(c2.x, 0.f); c2.y = fmaxf(c2.y, 0.f); c2.z = fmaxf(c2.z, 0.f); c2.w = fmaxf(c2.w, 0.f);
        c3.x = fmaxf(c3.x, 0.f); c3.y = fmaxf(c3.y, 0.f); c3.z = fmaxf(c3.z, 0.f); c3.w = fmaxf(c3.w, 0.f);
        float4* op = reinterpret_cast<float4*>(out + (size_t)r * OUT_SIZE + ob);
        op[0] = c0; op[1] = c1; op[2] = c2; op[3] = c3;
    }
}

// ---------------- atomic push spmm (fallback only) ----------------
__global__ __launch_bounds__(256) void spmm16_kernel(
    const int* __restrict__ row, const int* __restrict__ col,
    const float* __restrict__ val, const float* __restrict__ Hin,
    float* __restrict__ Sout, float* __restrict__ deg, long nedges, int relu_in) {
    long t = (long)blockIdx.x * 256 + threadIdx.x;
    long e = t >> 4;
    if (e >= nedges) return;
    int k = (int)(t & 15);
    int r = row[e];
    int c = col[e];
    float v = val[e];
    float x = Hin[(size_t)c * HIDDEN + k];
    if (relu_in) x = fmaxf(x, 0.0f);
    atomicAdd(&Sout[(size_t)r * HIDDEN + k], v * x);
    if (deg != nullptr && k == 0) atomicAdd(&deg[r], v);
}

// ---------------- out = relu(T @ W2^T + deg*b2)  (fallback only) ----------
__global__ __launch_bounds__(256) void dense2_kernel(
    const float* __restrict__ T, const float* __restrict__ deg,
    const float* __restrict__ W2, const float* __restrict__ b2,
    float* __restrict__ out, int n) {
    __shared__ float w[OUT_SIZE * HIDDEN];
    for (int i = threadIdx.x; i < OUT_SIZE * HIDDEN; i += 256) {
        int o = i / HIDDEN;
        int h = i % HIDDEN;
        w[h * OUT_SIZE + o] = W2[i];
    }
    __syncthreads();
    int node = blockIdx.x * 4 + (threadIdx.x >> 6);
    int o = threadIdx.x & 63;
    if (node >= n) return;
    float acc = deg[node] * b2[o];
#pragma unroll
    for (int h = 0; h < HIDDEN; ++h)
        acc += T[(size_t)node * HIDDEN + h] * w[h * OUT_SIZE + o];
    out[(size_t)node * OUT_SIZE + o] = fmaxf(acc, 0.0f);
}

static inline char* align_up(char* p, size_t a) {
    return (char*)(((uintptr_t)p + a - 1) & ~(uintptr_t)(a - 1));
}

extern "C" void kernel_launch(void* const* d_in, const int* in_sizes, int n_in,
                              void* d_out, int out_size, void* d_ws, size_t ws_size,
                              hipStream_t stream) {
    const int*   index = (const int*)d_in[0];
    const float* value = (const float*)d_in[1];
    const float* X     = (const float*)d_in[4];
    const float* W1    = (const float*)d_in[5];
    const float* b1    = (const float*)d_in[6];
    const float* W2    = (const float*)d_in[7];
    const float* b2    = (const float*)d_in[8];
    float* out = (float*)d_out;

    long nedges = in_sizes[1];
    int  n      = in_sizes[4] / IN_SIZE;
    const int* row = index;
    const int* col = index + nedges;

    // ws: bin[8B*E] | epack[8B*E] | bcnt[NBUCK] bstart[NBUCK+1] bcur[NBUCK] |
    //     row_ptr[n+1] | H1h[32n] | Ah[32n] | deg[4n]
    size_t need = (size_t)nedges * 16 + (size_t)(3 * NBUCK + 1) * 4 +
                  (size_t)(n + 1) * 4 + (size_t)n * (32 + 32 + 4) + 1024;

    if (ws_size >= need && n <= (NBUCK << BSHIFT)) {
        char* p = (char*)d_ws;
        unsigned int* bin = (unsigned int*)p;  p += (size_t)nedges * 8;
        uint2* epack = (uint2*)p;              p += (size_t)nedges * 8;
        int* bcnt   = (int*)p;   p += NBUCK * 4;
        int* bstart = (int*)p;   p += (NBUCK + 1) * 4;
        int* bcur   = (int*)p;   p += NBUCK * 4;
        int* row_ptr = (int*)p;  p += (size_t)(n + 1) * 4;
        p = align_up(p, 64);
        __half2* H1h = (__half2*)p;  p += (size_t)n * 32;
        __half2* Ah  = (__half2*)p;  p += (size_t)n * 32;
        float* deg   = (float*)p;

        int nbuck_used = (n + BROWS - 1) >> BSHIFT;

        zero_int_kernel<<<1, 256, 0, stream>>>(bcnt, NBUCK);
        bhist_kernel<<<(int)((nedges + EBH - 1) / EBH), 256, 0, stream>>>(row, bcnt, nedges);
        bucket_scan_kernel<<<1, 512, 0, stream>>>(bcnt, bstart, bcur, nedges);
        bin_kernel<<<(int)((nedges + EB - 1) / EB), BINBLK, 0, stream>>>(
            row, col, value, bcur, bin, nedges);

        dense1_half_kernel<<<(n + 63) / 64, 256, 0, stream>>>(X, W1, b1, H1h, n);

        // fused counting-sort + spmm pass 1
        csort_spmm1_kernel<<<nbuck_used, 512, 0, stream>>>(
            (const uint2*)bin, bstart, row_ptr, epack,
            (const uint2*)H1h, Ah, deg, n, nedges);

        // pass 2 fused with dense2: out = relu(spmm(Ah) @ W2^T + deg*b2)
        int sblocks = ((n * 4) + 255) / 256;
        spmm2_out_kernel<<<sblocks, 256, 0, stream>>>(
            row_ptr, epack, (const uint2*)Ah, W2, b2, deg, out, n);
    } else {
        // atomic push fallback (fp32 end-to-end)
        float* ws = (float*)d_ws;
        float* H1  = ws;
        float* S1  = H1 + (size_t)n * HIDDEN;
        float* T   = S1 + (size_t)n * HIDDEN;
        float* deg = T + (size_t)n * HIDDEN;
        zero_int_kernel<<<2048, 256, 0, stream>>>((int*)S1, (long)n * (2 * HIDDEN + 1));
        dense1_kernel<<<(n + 15) / 16, 256, 0, stream>>>(X, W1, b1, H1, n);
        long thr1 = nedges * HIDDEN;
        spmm16_kernel<<<(int)((thr1 + 255) / 256), 256, 0, stream>>>(
            row, col, value, H1, S1, deg, nedges, 0);
        spmm16_kernel<<<(int)((thr1 + 255) / 256), 256, 0, stream>>>(
            row, col, value, S1, T, nullptr, nedges, 1);
        dense2_kernel<<<(n + 3) / 4, 256, 0, stream>>>(T, deg, W2, b2, out, n);
    }
}

// Round 11
// 154.741 us; speedup vs baseline: 6.0254x; 1.0540x over previous
//
#include <hip/hip_runtime.h>
#include <hip/hip_fp16.h>

#define IN_SIZE 256
#define HIDDEN 16
#define OUT_SIZE 64
#define BSHIFT 7            // bucket = row >> 7 (128 rows)
#define BROWS 128
#define NBUCK 1024          // supports n <= 131072
#define EB 8192             // edges per bin block
#define BINBLK 1024
#define EPT 8
#define NBLK_MAX 512        // supports nedges <= 4.19M
#define WSTR 20
#define CAP 4416            // LDS-resident records per 128-row bucket (mean 4096 + 5 sigma)

// ---------------- zero (fallback path) ----------------
__global__ __launch_bounds__(256) void zero_int_kernel(int* __restrict__ a, long n) {
    long i = (long)blockIdx.x * 256 + threadIdx.x;
    long stride = (long)gridDim.x * 256;
    for (; i < n; i += stride) a[i] = 0;
}

// ---------------- H1(fp16) = X @ W1^T + b1  [n,16] ----------------
__global__ __launch_bounds__(256) void dense1_half_kernel(
    const float* __restrict__ X, const float* __restrict__ W1,
    const float* __restrict__ b1, __half2* __restrict__ H1, int n) {
    __shared__ float w[IN_SIZE * WSTR];  // w[k*20+h] = W1[h][k]
    for (int i = threadIdx.x; i < HIDDEN * IN_SIZE; i += 256) {
        int h = i >> 8;
        int k = i & 255;
        w[k * WSTR + h] = W1[i];
    }
    __syncthreads();
    int node = blockIdx.x * 64 + (threadIdx.x >> 2);
    int q = threadIdx.x & 3;
    if (node >= n) return;
    float acc[16];
#pragma unroll
    for (int h = 0; h < 16; ++h) acc[h] = 0.f;
    const float4* xr = reinterpret_cast<const float4*>(X + (size_t)node * IN_SIZE);
#pragma unroll 8
    for (int kk = 0; kk < 16; ++kk) {
        float4 x = xr[q + 4 * kk];
        const float* wr = &w[(kk * 16 + q * 4) * WSTR];
#pragma unroll
        for (int j = 0; j < 4; ++j) {
            float xs = (j == 0) ? x.x : (j == 1) ? x.y : (j == 2) ? x.z : x.w;
            const float* wj = wr + j * WSTR;
#pragma unroll
            for (int h = 0; h < 16; ++h)
                acc[h] += xs * wj[h];
        }
    }
#pragma unroll
    for (int h = 0; h < 16; ++h) {
        acc[h] += __shfl_xor(acc[h], 1, 4);
        acc[h] += __shfl_xor(acc[h], 2, 4);
    }
    const float4 bb = reinterpret_cast<const float4*>(b1)[q];
    int hb = q * 4;
    __half2 o0 = __floats2half2_rn(acc[hb] + bb.x, acc[hb + 1] + bb.y);
    __half2 o1 = __floats2half2_rn(acc[hb + 2] + bb.z, acc[hb + 3] + bb.w);
    uint2 pk;
    pk.x = *reinterpret_cast<unsigned int*>(&o0);
    pk.y = *reinterpret_cast<unsigned int*>(&o1);
    reinterpret_cast<uint2*>(H1)[(size_t)node * 4 + q] = pk;
}

// ---------------- fp32 dense1 (fallback only) ----------------
__global__ __launch_bounds__(256) void dense1_kernel(
    const float* __restrict__ X, const float* __restrict__ W1,
    const float* __restrict__ b1, float* __restrict__ H1, int n) {
    __shared__ float w[HIDDEN * IN_SIZE];
    for (int i = threadIdx.x; i < HIDDEN * IN_SIZE; i += 256) {
        int h = i >> 8;
        int k = i & 255;
        w[k * HIDDEN + h] = W1[i];
    }
    __syncthreads();
    int t = threadIdx.x;
    int node = blockIdx.x * 16 + (t >> 4);
    int h = t & 15;
    if (node >= n) return;
    const float4* xr = reinterpret_cast<const float4*>(X + (size_t)node * IN_SIZE);
    float acc = b1[h];
#pragma unroll 8
    for (int kk = 0; kk < IN_SIZE / 4; ++kk) {
        float4 x = xr[kk];
        const float* wr = &w[(kk * 4) * HIDDEN + h];
        acc += x.x * wr[0] + x.y * wr[HIDDEN] + x.z * wr[2 * HIDDEN] + x.w * wr[3 * HIDDEN];
    }
    H1[(size_t)node * HIDDEN + h] = acc;
}

// ---------------- bin: block-major bucket sort + directory ----------------
// bin[blk*EB + j] holds block blk's records in bucket-major order (coalesced
// write, no global reservation). dirT[i*nblk + blk] = start of bucket i
// within block blk (row NBUCK = ecount).
// record: x = (local_row<<24)|col ; y = val bits
// meta: lr<<25 | bb<<13 | slot  (slot<8192:13b, bb<1024:10b, lr<128:7b;
//       bits 23-24 are 0 for valid metas -> 0xFFFFFFFF sentinel unambiguous)
__global__ __launch_bounds__(BINBLK) void bin_kernel(
    const int* __restrict__ row, const int* __restrict__ col,
    const float* __restrict__ val, uint2* __restrict__ bin,
    int* __restrict__ dirT, int nblk, long nedges) {
    __shared__ int hist[NBUCK];
    __shared__ int lbase[NBUCK];
    __shared__ int s[BINBLK];
    __shared__ unsigned int staged[EB * 2];   // 64 KB
    int blk = blockIdx.x, tid = threadIdx.x;
    long base = (long)blk * EB;
    int ecount = (int)(((nedges - base) < (long)EB) ? (nedges - base) : (long)EB);
    hist[tid] = 0;
    __syncthreads();
    unsigned int meta[EPT], cc[EPT], vv[EPT];
    if (ecount == EB) {
        long e8 = base + (long)tid * EPT;
        int4 ra = *reinterpret_cast<const int4*>(row + e8);
        int4 rb = *reinterpret_cast<const int4*>(row + e8 + 4);
        int4 ca = *reinterpret_cast<const int4*>(col + e8);
        int4 cb = *reinterpret_cast<const int4*>(col + e8 + 4);
        float4 va = *reinterpret_cast<const float4*>(val + e8);
        float4 vb = *reinterpret_cast<const float4*>(val + e8 + 4);
        int rr[8] = {ra.x, ra.y, ra.z, ra.w, rb.x, rb.y, rb.z, rb.w};
        int cr[8] = {ca.x, ca.y, ca.z, ca.w, cb.x, cb.y, cb.z, cb.w};
        float vr[8] = {va.x, va.y, va.z, va.w, vb.x, vb.y, vb.z, vb.w};
#pragma unroll
        for (int i = 0; i < EPT; ++i) {
            int r = rr[i];
            int bb = r >> BSHIFT;
            int slot = atomicAdd(&hist[bb], 1);
            meta[i] = ((unsigned int)(r & (BROWS - 1)) << 25) |
                      ((unsigned int)bb << 13) | (unsigned int)slot;
            cc[i] = (unsigned int)cr[i];
            vv[i] = __float_as_uint(vr[i]);
        }
    } else {
#pragma unroll
        for (int i = 0; i < EPT; ++i) {
            int k = tid * EPT + i;
            meta[i] = 0xFFFFFFFFu;
            if (k < ecount) {
                int r = row[base + k];
                cc[i] = (unsigned int)col[base + k];
                vv[i] = __float_as_uint(val[base + k]);
                int bb = r >> BSHIFT;
                int slot = atomicAdd(&hist[bb], 1);
                meta[i] = ((unsigned int)(r & (BROWS - 1)) << 25) |
                          ((unsigned int)bb << 13) | (unsigned int)slot;
            }
        }
    }
    __syncthreads();
    int x = hist[tid];
    s[tid] = x;
    __syncthreads();
    for (int off = 1; off < BINBLK; off <<= 1) {
        int t = (tid >= off) ? s[tid - off] : 0;
        __syncthreads();
        s[tid] += t;
        __syncthreads();
    }
    lbase[tid] = s[tid] - x;
    __syncthreads();
    for (int i = tid; i <= NBUCK; i += BINBLK)
        dirT[(size_t)i * nblk + blk] = (i < NBUCK) ? lbase[i] : ecount;
#pragma unroll
    for (int i = 0; i < EPT; ++i) {
        if (meta[i] != 0xFFFFFFFFu) {
            int bb = (meta[i] >> 13) & 0x3FF;
            int p = lbase[bb] + (int)(meta[i] & 0x1FFF);
            staged[2 * p]     = ((meta[i] >> 25) << 24) | cc[i];
            staged[2 * p + 1] = vv[i];
        }
    }
    __syncthreads();
    for (int j = tid; j < ecount; j += BINBLK)
        bin[base + j] = make_uint2(staged[2 * j], staged[2 * j + 1]);
}

// ---------------- shared helpers ----------------
__device__ __forceinline__ int bsearch_pfx(const int* pfx, int p) {
    int lo = 0;
#pragma unroll
    for (int sh = 8; sh >= 0; --sh) {
        int mid = lo + (1 << sh);
        if (mid < NBLK_MAX && pfx[mid] <= p) lo = mid;
    }
    return lo;  // last index with pfx[lo] <= p
}

__device__ __forceinline__ void fma_h(float4& a, uint2 h, float v) {
    __half2 lo = *reinterpret_cast<const __half2*>(&h.x);
    __half2 hi = *reinterpret_cast<const __half2*>(&h.y);
    float2 f0 = __half22float2(lo), f1 = __half22float2(hi);
    a.x += v * f0.x; a.y += v * f0.y; a.z += v * f1.x; a.w += v * f1.y;
}

// ---------------- fused dir-gather + sort + spmm1: Ah = relu(spmm(H1h)), deg
__global__ __launch_bounds__(512) void csort_spmm1_kernel(
    const uint2* __restrict__ bin, const int* __restrict__ dirT,
    const uint2* __restrict__ Hin, __half2* __restrict__ Ah,
    float* __restrict__ deg, int n, int nblk) {
    __shared__ int gs[NBLK_MAX];
    __shared__ unsigned short rl[NBLK_MAX];
    __shared__ int pfx[NBLK_MAX];
    __shared__ int s[NBLK_MAX];
    __shared__ int cnt[BROWS], sbase[BROWS], cur[BROWS];
    __shared__ float dacc[BROWS];
    __shared__ int mTot;
    __shared__ uint2 eld[CAP];
    int d = blockIdx.x, tid = threadIdx.x;
    // 1. load runs (coalesced rows of dirT)
    if (tid < nblk) {
        int a = dirT[(size_t)d * nblk + tid];
        int b = dirT[(size_t)(d + 1) * nblk + tid];
        gs[tid] = tid * EB + a;
        rl[tid] = (unsigned short)(b - a);
    } else { gs[tid] = 0; rl[tid] = 0; }
    __syncthreads();
    // 2. scan rl -> pfx (exclusive)
    int x = (int)rl[tid];
    s[tid] = x;
    __syncthreads();
    for (int off = 1; off < NBLK_MAX; off <<= 1) {
        int t = (tid >= off) ? s[tid - off] : 0;
        __syncthreads();
        s[tid] += t;
        __syncthreads();
    }
    pfx[tid] = s[tid] - x;
    if (tid == NBLK_MAX - 1) mTot = s[NBLK_MAX - 1];
    if (tid < BROWS) { cnt[tid] = 0; dacc[tid] = 0.f; }
    __syncthreads();
    int m = mTot;
    bool fits = (m <= CAP);
    float* accf = (float*)eld;  // overflow accumulator overlay (128*17 floats)
    if (!fits) {
        for (int i = tid; i < BROWS * 17; i += 512) accf[i] = 0.f;
    } else {
        for (int p = tid; p < m; p += 512) {
            int blk = bsearch_pfx(pfx, p);
            uint2 rec = bin[(size_t)gs[blk] + (p - pfx[blk])];
            atomicAdd(&cnt[rec.x >> 24], 1);
        }
    }
    __syncthreads();
    // 3. scan cnt (128)
    int cx = (tid < BROWS) ? cnt[tid] : 0;
    if (tid < BROWS) s[tid] = cx;
    __syncthreads();
    for (int off = 1; off < BROWS; off <<= 1) {
        int t = (tid >= off && tid < BROWS) ? s[tid - off] : 0;
        __syncthreads();
        if (tid < BROWS) s[tid] += t;
        __syncthreads();
    }
    if (tid < BROWS) {
        sbase[tid] = s[tid] - cx;
        cur[tid] = s[tid] - cx;
    }
    __syncthreads();
    // 4. sort into LDS (or LDS-atomic accumulate if oversized)
    if (fits) {
        for (int p = tid; p < m; p += 512) {
            int blk = bsearch_pfx(pfx, p);
            uint2 rec = bin[(size_t)gs[blk] + (p - pfx[blk])];
            int lr = rec.x >> 24;
            int pos = atomicAdd(&cur[lr], 1);
            eld[pos] = make_uint2(rec.x & 0xFFFFFF, rec.y);
        }
    } else {
        for (int p = tid; p < m; p += 512) {
            int blk = bsearch_pfx(pfx, p);
            uint2 rec = bin[(size_t)gs[blk] + (p - pfx[blk])];
            int lr = rec.x >> 24;
            int c = rec.x & 0xFFFFFF;
            float v = __uint_as_float(rec.y);
            const __half2* hp = reinterpret_cast<const __half2*>(Hin + (size_t)c * 4);
#pragma unroll
            for (int j = 0; j < 8; ++j) {
                float2 f = __half22float2(hp[j]);
                atomicAdd(&accf[lr * 17 + 2 * j], v * f.x);
                atomicAdd(&accf[lr * 17 + 2 * j + 1], v * f.y);
            }
            atomicAdd(&dacc[lr], v);
        }
    }
    __syncthreads();
    // 5. spmm: one 4-lane quad per row
    int lr = tid >> 2, q = tid & 3;
    int r = (d << BSHIFT) + lr;
    if (r >= n) return;
    float4 a0 = {0,0,0,0};
    float dg = 0.f;
    if (fits) {
        float4 a1 = {0,0,0,0}, a2 = {0,0,0,0}, a3 = {0,0,0,0};
        int e = sbase[lr], e1 = e + cnt[lr];
        for (; e + 4 <= e1; e += 4) {
            uint2 r0 = eld[e], r1 = eld[e + 1], r2 = eld[e + 2], r3 = eld[e + 3];
            uint2 h0 = Hin[(size_t)r0.x * 4 + q];
            uint2 h1 = Hin[(size_t)r1.x * 4 + q];
            uint2 h2 = Hin[(size_t)r2.x * 4 + q];
            uint2 h3 = Hin[(size_t)r3.x * 4 + q];
            float v0 = __uint_as_float(r0.y), v1 = __uint_as_float(r1.y);
            float v2 = __uint_as_float(r2.y), v3 = __uint_as_float(r3.y);
            fma_h(a0, h0, v0); fma_h(a1, h1, v1);
            fma_h(a2, h2, v2); fma_h(a3, h3, v3);
            dg += v0 + v1 + v2 + v3;
        }
        for (; e < e1; ++e) {
            uint2 rr = eld[e];
            uint2 h = Hin[(size_t)rr.x * 4 + q];
            float v = __uint_as_float(rr.y);
            fma_h(a0, h, v);
            dg += v;
        }
        a0.x += a1.x + a2.x + a3.x;
        a0.y += a1.y + a2.y + a3.y;
        a0.z += a1.z + a2.z + a3.z;
        a0.w += a1.w + a2.w + a3.w;
    } else {
        a0.x = accf[lr * 17 + 4 * q];
        a0.y = accf[lr * 17 + 4 * q + 1];
        a0.z = accf[lr * 17 + 4 * q + 2];
        a0.w = accf[lr * 17 + 4 * q + 3];
        dg = dacc[lr];
    }
    a0.x = fmaxf(a0.x, 0.f); a0.y = fmaxf(a0.y, 0.f);
    a0.z = fmaxf(a0.z, 0.f); a0.w = fmaxf(a0.w, 0.f);
    __half2 o0 = __floats2half2_rn(a0.x, a0.y);
    __half2 o1 = __floats2half2_rn(a0.z, a0.w);
    uint2 pk;
    pk.x = *reinterpret_cast<unsigned int*>(&o0);
    pk.y = *reinterpret_cast<unsigned int*>(&o1);
    reinterpret_cast<uint2*>(Ah)[(size_t)r * 4 + q] = pk;
    if (q == 0) deg[r] = dg;
}

// ---------------- fused dir-gather + sort + spmm2 + dense2 -----------------
// out = relu(spmm(Ah) @ W2^T + deg*b2); T never materialized (quad shfl).
__global__ __launch_bounds__(512) void spmm2_out_kernel(
    const uint2* __restrict__ bin, const int* __restrict__ dirT,
    const uint2* __restrict__ Hin, const float* __restrict__ W2,
    const float* __restrict__ b2, const float* __restrict__ deg,
    float* __restrict__ out, int n, int nblk) {
    __shared__ int gs[NBLK_MAX];
    __shared__ unsigned short rl[NBLK_MAX];
    __shared__ int pfx[NBLK_MAX];
    __shared__ int s[NBLK_MAX];
    __shared__ int cnt[BROWS], sbase[BROWS], cur[BROWS];
    __shared__ int mTot;
    __shared__ float w2[HIDDEN * OUT_SIZE];   // w2[h*64+o] = W2[o][h]
    __shared__ float b2s[OUT_SIZE];
    __shared__ uint2 eld[CAP];
    int d = blockIdx.x, tid = threadIdx.x;
    for (int i = tid; i < HIDDEN * OUT_SIZE; i += 512)
        w2[(i & 15) * OUT_SIZE + (i >> 4)] = W2[i];
    if (tid < OUT_SIZE) b2s[tid] = b2[tid];
    if (tid < nblk) {
        int a = dirT[(size_t)d * nblk + tid];
        int b = dirT[(size_t)(d + 1) * nblk + tid];
        gs[tid] = tid * EB + a;
        rl[tid] = (unsigned short)(b - a);
    } else { gs[tid] = 0; rl[tid] = 0; }
    __syncthreads();
    int x = (int)rl[tid];
    s[tid] = x;
    __syncthreads();
    for (int off = 1; off < NBLK_MAX; off <<= 1) {
        int t = (tid >= off) ? s[tid - off] : 0;
        __syncthreads();
        s[tid] += t;
        __syncthreads();
    }
    pfx[tid] = s[tid] - x;
    if (tid == NBLK_MAX - 1) mTot = s[NBLK_MAX - 1];
    if (tid < BROWS) cnt[tid] = 0;
    __syncthreads();
    int m = mTot;
    bool fits = (m <= CAP);
    float* accf = (float*)eld;
    if (!fits) {
        for (int i = tid; i < BROWS * 17; i += 512) accf[i] = 0.f;
    } else {
        for (int p = tid; p < m; p += 512) {
            int blk = bsearch_pfx(pfx, p);
            uint2 rec = bin[(size_t)gs[blk] + (p - pfx[blk])];
            atomicAdd(&cnt[rec.x >> 24], 1);
        }
    }
    __syncthreads();
    int cx = (tid < BROWS) ? cnt[tid] : 0;
    if (tid < BROWS) s[tid] = cx;
    __syncthreads();
    for (int off = 1; off < BROWS; off <<= 1) {
        int t = (tid >= off && tid < BROWS) ? s[tid - off] : 0;
        __syncthreads();
        if (tid < BROWS) s[tid] += t;
        __syncthreads();
    }
    if (tid < BROWS) {
        sbase[tid] = s[tid] - cx;
        cur[tid] = s[tid] - cx;
    }
    __syncthreads();
    if (fits) {
        for (int p = tid; p < m; p += 512) {
            int blk = bsearch_pfx(pfx, p);
            uint2 rec = bin[(size_t)gs[blk] + (p - pfx[blk])];
            int lr = rec.x >> 24;
            int pos = atomicAdd(&cur[lr], 1);
            eld[pos] = make_uint2(rec.x & 0xFFFFFF, rec.y);
        }
    } else {
        for (int p = tid; p < m; p += 512) {
            int blk = bsearch_pfx(pfx, p);
            uint2 rec = bin[(size_t)gs[blk] + (p - pfx[blk])];
            int lr = rec.x >> 24;
            int c = rec.x & 0xFFFFFF;
            float v = __uint_as_float(rec.y);
            const __half2* hp = reinterpret_cast<const __half2*>(Hin + (size_t)c * 4);
#pragma unroll
            for (int j = 0; j < 8; ++j) {
                float2 f = __half22float2(hp[j]);
                atomicAdd(&accf[lr * 17 + 2 * j], v * f.x);
                atomicAdd(&accf[lr * 17 + 2 * j + 1], v * f.y);
            }
        }
    }
    __syncthreads();
    int lr = tid >> 2, q = tid & 3;
    int r = (d << BSHIFT) + lr;
    if (r >= n) return;
    float4 a0 = {0,0,0,0};
    if (fits) {
        float4 a1 = {0,0,0,0}, a2 = {0,0,0,0}, a3 = {0,0,0,0};
        int e = sbase[lr], e1 = e + cnt[lr];
        for (; e + 4 <= e1; e += 4) {
            uint2 r0 = eld[e], r1 = eld[e + 1], r2 = eld[e + 2], r3 = eld[e + 3];
            uint2 h0 = Hin[(size_t)r0.x * 4 + q];
            uint2 h1 = Hin[(size_t)r1.x * 4 + q];
            uint2 h2 = Hin[(size_t)r2.x * 4 + q];
            uint2 h3 = Hin[(size_t)r3.x * 4 + q];
            fma_h(a0, h0, __uint_as_float(r0.y));
            fma_h(a1, h1, __uint_as_float(r1.y));
            fma_h(a2, h2, __uint_as_float(r2.y));
            fma_h(a3, h3, __uint_as_float(r3.y));
        }
        for (; e < e1; ++e) {
            uint2 rr = eld[e];
            uint2 h = Hin[(size_t)rr.x * 4 + q];
            fma_h(a0, h, __uint_as_float(rr.y));
        }
        a0.x += a1.x + a2.x + a3.x;
        a0.y += a1.y + a2.y + a3.y;
        a0.z += a1.z + a2.z + a3.z;
        a0.w += a1.w + a2.w + a3.w;
    } else {
        a0.x = accf[lr * 17 + 4 * q];
        a0.y = accf[lr * 17 + 4 * q + 1];
        a0.z = accf[lr * 17 + 4 * q + 2];
        a0.w = accf[lr * 17 + 4 * q + 3];
    }
    // dense2 epilogue: quad shfl-exchange of T row, W2 from LDS
    float dg = deg[r];
    int ob = q * 16;
    const float4* bp = reinterpret_cast<const float4*>(&b2s[ob]);
    float4 c0 = bp[0], c1 = bp[1], c2 = bp[2], c3 = bp[3];
    c0.x *= dg; c0.y *= dg; c0.z *= dg; c0.w *= dg;
    c1.x *= dg; c1.y *= dg; c1.z *= dg; c1.w *= dg;
    c2.x *= dg; c2.y *= dg; c2.z *= dg; c2.w *= dg;
    c3.x *= dg; c3.y *= dg; c3.z *= dg; c3.w *= dg;
#pragma unroll
    for (int sq = 0; sq < 4; ++sq) {
        float tv[4];
        tv[0] = __shfl(a0.x, sq, 4);
        tv[1] = __shfl(a0.y, sq, 4);
        tv[2] = __shfl(a0.z, sq, 4);
        tv[3] = __shfl(a0.w, sq, 4);
#pragma unroll
        for (int j = 0; j < 4; ++j) {
            int h = 4 * sq + j;
            const float4* wp = reinterpret_cast<const float4*>(&w2[h * OUT_SIZE + ob]);
            float4 w0 = wp[0], w1 = wp[1], w2v = wp[2], w3 = wp[3];
            float th = tv[j];
            c0.x += th * w0.x; c0.y += th * w0.y; c0.z += th * w0.z; c0.w += th * w0.w;
            c1.x += th * w1.x; c1.y += th * w1.y; c1.z += th * w1.z; c1.w += th * w1.w;
            c2.x += th * w2v.x; c2.y += th * w2v.y; c2.z += th * w2v.z; c2.w += th * w2v.w;
            c3.x += th * w3.x; c3.y += th * w3.y; c3.z += th * w3.z; c3.w += th * w3.w;
        }
    }
    c0.x = fmaxf(c0.x, 0.f); c0.y = fmaxf(c0.y, 0.f); c0.z = fmaxf(c0.z, 0.f); c0.w = fmaxf(c0.w, 0.f);
    c1.x = fmaxf(c1.x, 0.f); c1.y = fmaxf(c1.y, 0.f); c1.z = fmaxf(c1.z, 0.f); c1.w = fmaxf(c1.w, 0.f);
    c2.x = fmaxf(c2.x, 0.f); c2.y = fmaxf(c2.y, 0.f); c2.z = fmaxf(c2.z, 0.f); c2.w = fmaxf(c2.w, 0.f);
    c3.x = fmaxf(c3.x, 0.f); c3.y = fmaxf(c3.y, 0.f); c3.z = fmaxf(c3.z, 0.f); c3.w = fmaxf(c3.w, 0.f);
    float4* op = reinterpret_cast<float4*>(out + (size_t)r * OUT_SIZE + ob);
    op[0] = c0; op[1] = c1; op[2] = c2; op[3] = c3;
}

// ---------------- atomic push spmm (fallback only) ----------------
__global__ __launch_bounds__(256) void spmm16_kernel(
    const int* __restrict__ row, const int* __restrict__ col,
    const float* __restrict__ val, const float* __restrict__ Hin,
    float* __restrict__ Sout, float* __restrict__ deg, long nedges, int relu_in) {
    long t = (long)blockIdx.x * 256 + threadIdx.x;
    long e = t >> 4;
    if (e >= nedges) return;
    int k = (int)(t & 15);
    int r = row[e];
    int c = col[e];
    float v = val[e];
    float x = Hin[(size_t)c * HIDDEN + k];
    if (relu_in) x = fmaxf(x, 0.0f);
    atomicAdd(&Sout[(size_t)r * HIDDEN + k], v * x);
    if (deg != nullptr && k == 0) atomicAdd(&deg[r], v);
}

// ---------------- dense2 (fallback only) ----------------
__global__ __launch_bounds__(256) void dense2_kernel(
    const float* __restrict__ T, const float* __restrict__ deg,
    const float* __restrict__ W2, const float* __restrict__ b2,
    float* __restrict__ out, int n) {
    __shared__ float w[OUT_SIZE * HIDDEN];
    for (int i = threadIdx.x; i < OUT_SIZE * HIDDEN; i += 256) {
        int o = i / HIDDEN;
        int h = i % HIDDEN;
        w[h * OUT_SIZE + o] = W2[i];
    }
    __syncthreads();
    int node = blockIdx.x * 4 + (threadIdx.x >> 6);
    int o = threadIdx.x & 63;
    if (node >= n) return;
    float acc = deg[node] * b2[o];
#pragma unroll
    for (int h = 0; h < HIDDEN; ++h)
        acc += T[(size_t)node * HIDDEN + h] * w[h * OUT_SIZE + o];
    out[(size_t)node * OUT_SIZE + o] = fmaxf(acc, 0.0f);
}

static inline char* align_up(char* p, size_t a) {
    return (char*)(((uintptr_t)p + a - 1) & ~(uintptr_t)(a - 1));
}

extern "C" void kernel_launch(void* const* d_in, const int* in_sizes, int n_in,
                              void* d_out, int out_size, void* d_ws, size_t ws_size,
                              hipStream_t stream) {
    const int*   index = (const int*)d_in[0];
    const float* value = (const float*)d_in[1];
    const float* X     = (const float*)d_in[4];
    const float* W1    = (const float*)d_in[5];
    const float* b1    = (const float*)d_in[6];
    const float* W2    = (const float*)d_in[7];
    const float* b2    = (const float*)d_in[8];
    float* out = (float*)d_out;

    long nedges = in_sizes[1];
    int  n      = in_sizes[4] / IN_SIZE;
    const int* row = index;
    const int* col = index + nedges;

    int nblk = (int)((nedges + EB - 1) / EB);

    // ws: bin[8B*E] | dirT[(NBUCK+1)*nblk*4B] | H1h[32n] | Ah[32n] | deg[4n]
    size_t need = (size_t)nedges * 8 + (size_t)(NBUCK + 1) * nblk * 4 +
                  (size_t)n * (32 + 32 + 4) + 1024;

    if (ws_size >= need && n <= (NBUCK << BSHIFT) && nblk <= NBLK_MAX) {
        char* p = (char*)d_ws;
        uint2* bin = (uint2*)p;       p += (size_t)nedges * 8;
        int* dirT  = (int*)p;         p += (size_t)(NBUCK + 1) * nblk * 4;
        p = align_up(p, 64);
        __half2* H1h = (__half2*)p;   p += (size_t)n * 32;
        __half2* Ah  = (__half2*)p;   p += (size_t)n * 32;
        float* deg   = (float*)p;

        int ncs = (n + BROWS - 1) >> BSHIFT;

        bin_kernel<<<nblk, BINBLK, 0, stream>>>(row, col, value, bin, dirT, nblk, nedges);
        dense1_half_kernel<<<(n + 63) / 64, 256, 0, stream>>>(X, W1, b1, H1h, n);
        csort_spmm1_kernel<<<ncs, 512, 0, stream>>>(
            bin, dirT, (const uint2*)H1h, Ah, deg, n, nblk);
        spmm2_out_kernel<<<ncs, 512, 0, stream>>>(
            bin, dirT, (const uint2*)Ah, W2, b2, deg, out, n, nblk);
    } else {
        // atomic push fallback (fp32 end-to-end)
        float* ws = (float*)d_ws;
        float* H1  = ws;
        float* S1  = H1 + (size_t)n * HIDDEN;
        float* T   = S1 + (size_t)n * HIDDEN;
        float* deg = T + (size_t)n * HIDDEN;
        zero_int_kernel<<<2048, 256, 0, stream>>>((int*)S1, (long)n * (2 * HIDDEN + 1));
        dense1_kernel<<<(n + 15) / 16, 256, 0, stream>>>(X, W1, b1, H1, n);
        long thr1 = nedges * HIDDEN;
        spmm16_kernel<<<(int)((thr1 + 255) / 256), 256, 0, stream>>>(
            row, col, value, H1, S1, deg, nedges, 0);
        spmm16_kernel<<<(int)((thr1 + 255) / 256), 256, 0, stream>>>(
            row, col, value, S1, T, nullptr, nedges, 1);
        dense2_kernel<<<(n + 3) / 4, 256, 0, stream>>>(T, deg, W2, b2, out, n);
    }
}

// Round 12
// 133.568 us; speedup vs baseline: 6.9805x; 1.1585x over previous
//
#include <hip/hip_runtime.h>
#include <hip/hip_fp16.h>

#define IN_SIZE 256
#define HIDDEN 16
#define OUT_SIZE 64
#define BSHIFT 7            // bucket = row >> 7 (128 rows)
#define BROWS 128
#define NBUCK 1024          // supports n <= 131072
#define EB 8192             // edges per bin block
#define BINBLK 1024
#define EPT 8
#define NBLK_MAX 512        // supports nedges <= 4.19M
#define WSTR 20
#define CAP 4416            // LDS-resident records per 128-row bucket
#define KPT 9               // ceil(CAP/512) records per thread (register-staged)

// ---------------- zero (fallback path) ----------------
__global__ __launch_bounds__(256) void zero_int_kernel(int* __restrict__ a, long n) {
    long i = (long)blockIdx.x * 256 + threadIdx.x;
    long stride = (long)gridDim.x * 256;
    for (; i < n; i += stride) a[i] = 0;
}

// ---------------- H1(fp16) = X @ W1^T + b1  [n,16] ----------------
__global__ __launch_bounds__(256) void dense1_half_kernel(
    const float* __restrict__ X, const float* __restrict__ W1,
    const float* __restrict__ b1, __half2* __restrict__ H1, int n) {
    __shared__ float w[IN_SIZE * WSTR];  // w[k*20+h] = W1[h][k]
    for (int i = threadIdx.x; i < HIDDEN * IN_SIZE; i += 256) {
        int h = i >> 8;
        int k = i & 255;
        w[k * WSTR + h] = W1[i];
    }
    __syncthreads();
    int node = blockIdx.x * 64 + (threadIdx.x >> 2);
    int q = threadIdx.x & 3;
    if (node >= n) return;
    float acc[16];
#pragma unroll
    for (int h = 0; h < 16; ++h) acc[h] = 0.f;
    const float4* xr = reinterpret_cast<const float4*>(X + (size_t)node * IN_SIZE);
#pragma unroll 8
    for (int kk = 0; kk < 16; ++kk) {
        float4 x = xr[q + 4 * kk];
        const float* wr = &w[(kk * 16 + q * 4) * WSTR];
#pragma unroll
        for (int j = 0; j < 4; ++j) {
            float xs = (j == 0) ? x.x : (j == 1) ? x.y : (j == 2) ? x.z : x.w;
            const float* wj = wr + j * WSTR;
#pragma unroll
            for (int h = 0; h < 16; ++h)
                acc[h] += xs * wj[h];
        }
    }
#pragma unroll
    for (int h = 0; h < 16; ++h) {
        acc[h] += __shfl_xor(acc[h], 1, 4);
        acc[h] += __shfl_xor(acc[h], 2, 4);
    }
    const float4 bb = reinterpret_cast<const float4*>(b1)[q];
    int hb = q * 4;
    __half2 o0 = __floats2half2_rn(acc[hb] + bb.x, acc[hb + 1] + bb.y);
    __half2 o1 = __floats2half2_rn(acc[hb + 2] + bb.z, acc[hb + 3] + bb.w);
    uint2 pk;
    pk.x = *reinterpret_cast<unsigned int*>(&o0);
    pk.y = *reinterpret_cast<unsigned int*>(&o1);
    reinterpret_cast<uint2*>(H1)[(size_t)node * 4 + q] = pk;
}

// ---------------- fp32 dense1 (fallback only) ----------------
__global__ __launch_bounds__(256) void dense1_kernel(
    const float* __restrict__ X, const float* __restrict__ W1,
    const float* __restrict__ b1, float* __restrict__ H1, int n) {
    __shared__ float w[HIDDEN * IN_SIZE];
    for (int i = threadIdx.x; i < HIDDEN * IN_SIZE; i += 256) {
        int h = i >> 8;
        int k = i & 255;
        w[k * HIDDEN + h] = W1[i];
    }
    __syncthreads();
    int t = threadIdx.x;
    int node = blockIdx.x * 16 + (t >> 4);
    int h = t & 15;
    if (node >= n) return;
    const float4* xr = reinterpret_cast<const float4*>(X + (size_t)node * IN_SIZE);
    float acc = b1[h];
#pragma unroll 8
    for (int kk = 0; kk < IN_SIZE / 4; ++kk) {
        float4 x = xr[kk];
        const float* wr = &w[(kk * 4) * HIDDEN + h];
        acc += x.x * wr[0] + x.y * wr[HIDDEN] + x.z * wr[2 * HIDDEN] + x.w * wr[3 * HIDDEN];
    }
    H1[(size_t)node * HIDDEN + h] = acc;
}

// ---------------- bin: block-major bucket sort + directory ----------------
__global__ __launch_bounds__(BINBLK) void bin_kernel(
    const int* __restrict__ row, const int* __restrict__ col,
    const float* __restrict__ val, uint2* __restrict__ bin,
    int* __restrict__ dirT, int nblk, long nedges) {
    __shared__ int hist[NBUCK];
    __shared__ int lbase[NBUCK];
    __shared__ int s[BINBLK];
    __shared__ unsigned int staged[EB * 2];   // 64 KB
    int blk = blockIdx.x, tid = threadIdx.x;
    long base = (long)blk * EB;
    int ecount = (int)(((nedges - base) < (long)EB) ? (nedges - base) : (long)EB);
    hist[tid] = 0;
    __syncthreads();
    unsigned int meta[EPT], cc[EPT], vv[EPT];
    if (ecount == EB) {
        long e8 = base + (long)tid * EPT;
        int4 ra = *reinterpret_cast<const int4*>(row + e8);
        int4 rb = *reinterpret_cast<const int4*>(row + e8 + 4);
        int4 ca = *reinterpret_cast<const int4*>(col + e8);
        int4 cb = *reinterpret_cast<const int4*>(col + e8 + 4);
        float4 va = *reinterpret_cast<const float4*>(val + e8);
        float4 vb = *reinterpret_cast<const float4*>(val + e8 + 4);
        int rr[8] = {ra.x, ra.y, ra.z, ra.w, rb.x, rb.y, rb.z, rb.w};
        int cr[8] = {ca.x, ca.y, ca.z, ca.w, cb.x, cb.y, cb.z, cb.w};
        float vr[8] = {va.x, va.y, va.z, va.w, vb.x, vb.y, vb.z, vb.w};
#pragma unroll
        for (int i = 0; i < EPT; ++i) {
            int r = rr[i];
            int bb = r >> BSHIFT;
            int slot = atomicAdd(&hist[bb], 1);
            meta[i] = ((unsigned int)(r & (BROWS - 1)) << 25) |
                      ((unsigned int)bb << 13) | (unsigned int)slot;
            cc[i] = (unsigned int)cr[i];
            vv[i] = __float_as_uint(vr[i]);
        }
    } else {
#pragma unroll
        for (int i = 0; i < EPT; ++i) {
            int k = tid * EPT + i;
            meta[i] = 0xFFFFFFFFu;
            if (k < ecount) {
                int r = row[base + k];
                cc[i] = (unsigned int)col[base + k];
                vv[i] = __float_as_uint(val[base + k]);
                int bb = r >> BSHIFT;
                int slot = atomicAdd(&hist[bb], 1);
                meta[i] = ((unsigned int)(r & (BROWS - 1)) << 25) |
                          ((unsigned int)bb << 13) | (unsigned int)slot;
            }
        }
    }
    __syncthreads();
    int x = hist[tid];
    s[tid] = x;
    __syncthreads();
    for (int off = 1; off < BINBLK; off <<= 1) {
        int t = (tid >= off) ? s[tid - off] : 0;
        __syncthreads();
        s[tid] += t;
        __syncthreads();
    }
    lbase[tid] = s[tid] - x;
    __syncthreads();
    for (int i = tid; i <= NBUCK; i += BINBLK)
        dirT[(size_t)i * nblk + blk] = (i < NBUCK) ? lbase[i] : ecount;
#pragma unroll
    for (int i = 0; i < EPT; ++i) {
        if (meta[i] != 0xFFFFFFFFu) {
            int bb = (meta[i] >> 13) & 0x3FF;
            int p = lbase[bb] + (int)(meta[i] & 0x1FFF);
            staged[2 * p]     = ((meta[i] >> 25) << 24) | cc[i];
            staged[2 * p + 1] = vv[i];
        }
    }
    __syncthreads();
    for (int j = tid; j < ecount; j += BINBLK)
        bin[base + j] = make_uint2(staged[2 * j], staged[2 * j + 1]);
}

// ---------------- shared helpers ----------------
__device__ __forceinline__ int bsearch_pfx(const int* pfx, int p) {
    int lo = 0;
#pragma unroll
    for (int sh = 8; sh >= 0; --sh) {
        int mid = lo + (1 << sh);
        if (mid < NBLK_MAX && pfx[mid] <= p) lo = mid;
    }
    return lo;
}

__device__ __forceinline__ void fma_h(float4& a, uint2 h, float v) {
    __half2 lo = *reinterpret_cast<const __half2*>(&h.x);
    __half2 hi = *reinterpret_cast<const __half2*>(&h.y);
    float2 f0 = __half22float2(lo), f1 = __half22float2(hi);
    a.x += v * f0.x; a.y += v * f0.y; a.z += v * f1.x; a.w += v * f1.y;
}

// ---------------- fused dir-gather + reg-staged sort + spmm1 ---------------
// Ah = relu(spmm(H1h)) fp16, deg. Single bin read, single bsearch per record.
__global__ __launch_bounds__(512) void csort_spmm1_kernel(
    const uint2* __restrict__ bin, const int* __restrict__ dirT,
    const uint2* __restrict__ Hin, __half2* __restrict__ Ah,
    float* __restrict__ deg, int n, int nblk) {
    __shared__ int gs[NBLK_MAX];
    __shared__ unsigned short rl[NBLK_MAX];
    __shared__ int pfx[NBLK_MAX];
    __shared__ int s[NBLK_MAX];
    __shared__ int cnt[BROWS], sbase[BROWS];
    __shared__ float dacc[BROWS];
    __shared__ int mTot;
    __shared__ uint2 eld[CAP];
    int d = blockIdx.x, tid = threadIdx.x;
    if (tid < nblk) {
        int a = dirT[(size_t)d * nblk + tid];
        int b = dirT[(size_t)(d + 1) * nblk + tid];
        gs[tid] = tid * EB + a;
        rl[tid] = (unsigned short)(b - a);
    } else { gs[tid] = 0; rl[tid] = 0; }
    __syncthreads();
    int x = (int)rl[tid];
    s[tid] = x;
    __syncthreads();
    for (int off = 1; off < NBLK_MAX; off <<= 1) {
        int t = (tid >= off) ? s[tid - off] : 0;
        __syncthreads();
        s[tid] += t;
        __syncthreads();
    }
    pfx[tid] = s[tid] - x;
    if (tid == NBLK_MAX - 1) mTot = s[NBLK_MAX - 1];
    if (tid < BROWS) { cnt[tid] = 0; dacc[tid] = 0.f; }
    __syncthreads();
    int m = mTot;
    bool fits = (m <= CAP);
    float* accf = (float*)eld;  // overflow accumulator overlay
    if (fits) {
        // pass A: single read -> registers; reserve slot per row
        uint2 regs[KPT];
        unsigned short slot_[KPT];
        unsigned char lr_[KPT];
#pragma unroll
        for (int k = 0; k < KPT; ++k) {
            int p = tid + k * 512;
            if (p < m) {
                int blk = bsearch_pfx(pfx, p);
                uint2 rec = bin[(size_t)gs[blk] + (p - pfx[blk])];
                int lr = rec.x >> 24;
                regs[k] = make_uint2(rec.x & 0xFFFFFF, rec.y);
                slot_[k] = (unsigned short)atomicAdd(&cnt[lr], 1);
                lr_[k] = (unsigned char)lr;
            }
        }
        __syncthreads();
        int cx = (tid < BROWS) ? cnt[tid] : 0;
        if (tid < BROWS) s[tid] = cx;
        __syncthreads();
        for (int off = 1; off < BROWS; off <<= 1) {
            int t = (tid >= off && tid < BROWS) ? s[tid - off] : 0;
            __syncthreads();
            if (tid < BROWS) s[tid] += t;
            __syncthreads();
        }
        if (tid < BROWS) sbase[tid] = s[tid] - cx;
        __syncthreads();
        // pass B: write sorted from registers
#pragma unroll
        for (int k = 0; k < KPT; ++k) {
            int p = tid + k * 512;
            if (p < m) eld[sbase[lr_[k]] + slot_[k]] = regs[k];
        }
    } else {
        for (int i = tid; i < BROWS * 17; i += 512) accf[i] = 0.f;
        __syncthreads();
        for (int p = tid; p < m; p += 512) {
            int blk = bsearch_pfx(pfx, p);
            uint2 rec = bin[(size_t)gs[blk] + (p - pfx[blk])];
            int lr = rec.x >> 24;
            int c = rec.x & 0xFFFFFF;
            float v = __uint_as_float(rec.y);
            const __half2* hp = reinterpret_cast<const __half2*>(Hin + (size_t)c * 4);
#pragma unroll
            for (int j = 0; j < 8; ++j) {
                float2 f = __half22float2(hp[j]);
                atomicAdd(&accf[lr * 17 + 2 * j], v * f.x);
                atomicAdd(&accf[lr * 17 + 2 * j + 1], v * f.y);
            }
            atomicAdd(&dacc[lr], v);
        }
    }
    __syncthreads();
    // spmm: one 4-lane quad per row
    int lr = tid >> 2, q = tid & 3;
    int r = (d << BSHIFT) + lr;
    if (r >= n) return;
    float4 a0 = {0,0,0,0};
    float dg = 0.f;
    if (fits) {
        float4 a1 = {0,0,0,0}, a2 = {0,0,0,0}, a3 = {0,0,0,0};
        int e = sbase[lr], e1 = e + cnt[lr];
        for (; e + 4 <= e1; e += 4) {
            uint2 r0 = eld[e], r1 = eld[e + 1], r2 = eld[e + 2], r3 = eld[e + 3];
            uint2 h0 = Hin[(size_t)r0.x * 4 + q];
            uint2 h1 = Hin[(size_t)r1.x * 4 + q];
            uint2 h2 = Hin[(size_t)r2.x * 4 + q];
            uint2 h3 = Hin[(size_t)r3.x * 4 + q];
            float v0 = __uint_as_float(r0.y), v1 = __uint_as_float(r1.y);
            float v2 = __uint_as_float(r2.y), v3 = __uint_as_float(r3.y);
            fma_h(a0, h0, v0); fma_h(a1, h1, v1);
            fma_h(a2, h2, v2); fma_h(a3, h3, v3);
            dg += v0 + v1 + v2 + v3;
        }
        for (; e < e1; ++e) {
            uint2 rr = eld[e];
            uint2 h = Hin[(size_t)rr.x * 4 + q];
            float v = __uint_as_float(rr.y);
            fma_h(a0, h, v);
            dg += v;
        }
        a0.x += a1.x + a2.x + a3.x;
        a0.y += a1.y + a2.y + a3.y;
        a0.z += a1.z + a2.z + a3.z;
        a0.w += a1.w + a2.w + a3.w;
    } else {
        a0.x = accf[lr * 17 + 4 * q];
        a0.y = accf[lr * 17 + 4 * q + 1];
        a0.z = accf[lr * 17 + 4 * q + 2];
        a0.w = accf[lr * 17 + 4 * q + 3];
        dg = dacc[lr];
    }
    a0.x = fmaxf(a0.x, 0.f); a0.y = fmaxf(a0.y, 0.f);
    a0.z = fmaxf(a0.z, 0.f); a0.w = fmaxf(a0.w, 0.f);
    __half2 o0 = __floats2half2_rn(a0.x, a0.y);
    __half2 o1 = __floats2half2_rn(a0.z, a0.w);
    uint2 pk;
    pk.x = *reinterpret_cast<unsigned int*>(&o0);
    pk.y = *reinterpret_cast<unsigned int*>(&o1);
    reinterpret_cast<uint2*>(Ah)[(size_t)r * 4 + q] = pk;
    if (q == 0) deg[r] = dg;
}

// ---------------- fused dir-gather + reg-staged sort + spmm2 + dense2 ------
__global__ __launch_bounds__(512) void spmm2_out_kernel(
    const uint2* __restrict__ bin, const int* __restrict__ dirT,
    const uint2* __restrict__ Hin, const float* __restrict__ W2,
    const float* __restrict__ b2, const float* __restrict__ deg,
    float* __restrict__ out, int n, int nblk) {
    __shared__ int gs[NBLK_MAX];
    __shared__ unsigned short rl[NBLK_MAX];
    __shared__ int pfx[NBLK_MAX];
    __shared__ int s[NBLK_MAX];
    __shared__ int cnt[BROWS], sbase[BROWS];
    __shared__ int mTot;
    __shared__ float w2[HIDDEN * OUT_SIZE];
    __shared__ float b2s[OUT_SIZE];
    __shared__ uint2 eld[CAP];
    int d = blockIdx.x, tid = threadIdx.x;
    for (int i = tid; i < HIDDEN * OUT_SIZE; i += 512)
        w2[(i & 15) * OUT_SIZE + (i >> 4)] = W2[i];
    if (tid < OUT_SIZE) b2s[tid] = b2[tid];
    if (tid < nblk) {
        int a = dirT[(size_t)d * nblk + tid];
        int b = dirT[(size_t)(d + 1) * nblk + tid];
        gs[tid] = tid * EB + a;
        rl[tid] = (unsigned short)(b - a);
    } else { gs[tid] = 0; rl[tid] = 0; }
    __syncthreads();
    int x = (int)rl[tid];
    s[tid] = x;
    __syncthreads();
    for (int off = 1; off < NBLK_MAX; off <<= 1) {
        int t = (tid >= off) ? s[tid - off] : 0;
        __syncthreads();
        s[tid] += t;
        __syncthreads();
    }
    pfx[tid] = s[tid] - x;
    if (tid == NBLK_MAX - 1) mTot = s[NBLK_MAX - 1];
    if (tid < BROWS) cnt[tid] = 0;
    __syncthreads();
    int m = mTot;
    bool fits = (m <= CAP);
    float* accf = (float*)eld;
    if (fits) {
        uint2 regs[KPT];
        unsigned short slot_[KPT];
        unsigned char lr_[KPT];
#pragma unroll
        for (int k = 0; k < KPT; ++k) {
            int p = tid + k * 512;
            if (p < m) {
                int blk = bsearch_pfx(pfx, p);
                uint2 rec = bin[(size_t)gs[blk] + (p - pfx[blk])];
                int lr = rec.x >> 24;
                regs[k] = make_uint2(rec.x & 0xFFFFFF, rec.y);
                slot_[k] = (unsigned short)atomicAdd(&cnt[lr], 1);
                lr_[k] = (unsigned char)lr;
            }
        }
        __syncthreads();
        int cx = (tid < BROWS) ? cnt[tid] : 0;
        if (tid < BROWS) s[tid] = cx;
        __syncthreads();
        for (int off = 1; off < BROWS; off <<= 1) {
            int t = (tid >= off && tid < BROWS) ? s[tid - off] : 0;
            __syncthreads();
            if (tid < BROWS) s[tid] += t;
            __syncthreads();
        }
        if (tid < BROWS) sbase[tid] = s[tid] - cx;
        __syncthreads();
#pragma unroll
        for (int k = 0; k < KPT; ++k) {
            int p = tid + k * 512;
            if (p < m) eld[sbase[lr_[k]] + slot_[k]] = regs[k];
        }
    } else {
        for (int i = tid; i < BROWS * 17; i += 512) accf[i] = 0.f;
        __syncthreads();
        for (int p = tid; p < m; p += 512) {
            int blk = bsearch_pfx(pfx, p);
            uint2 rec = bin[(size_t)gs[blk] + (p - pfx[blk])];
            int lr = rec.x >> 24;
            int c = rec.x & 0xFFFFFF;
            float v = __uint_as_float(rec.y);
            const __half2* hp = reinterpret_cast<const __half2*>(Hin + (size_t)c * 4);
#pragma unroll
            for (int j = 0; j < 8; ++j) {
                float2 f = __half22float2(hp[j]);
                atomicAdd(&accf[lr * 17 + 2 * j], v * f.x);
                atomicAdd(&accf[lr * 17 + 2 * j + 1], v * f.y);
            }
        }
    }
    __syncthreads();
    int lr = tid >> 2, q = tid & 3;
    int r = (d << BSHIFT) + lr;
    if (r >= n) return;
    float4 a0 = {0,0,0,0};
    if (fits) {
        float4 a1 = {0,0,0,0}, a2 = {0,0,0,0}, a3 = {0,0,0,0};
        int e = sbase[lr], e1 = e + cnt[lr];
        for (; e + 4 <= e1; e += 4) {
            uint2 r0 = eld[e], r1 = eld[e + 1], r2 = eld[e + 2], r3 = eld[e + 3];
            uint2 h0 = Hin[(size_t)r0.x * 4 + q];
            uint2 h1 = Hin[(size_t)r1.x * 4 + q];
            uint2 h2 = Hin[(size_t)r2.x * 4 + q];
            uint2 h3 = Hin[(size_t)r3.x * 4 + q];
            fma_h(a0, h0, __uint_as_float(r0.y));
            fma_h(a1, h1, __uint_as_float(r1.y));
            fma_h(a2, h2, __uint_as_float(r2.y));
            fma_h(a3, h3, __uint_as_float(r3.y));
        }
        for (; e < e1; ++e) {
            uint2 rr = eld[e];
            uint2 h = Hin[(size_t)rr.x * 4 + q];
            fma_h(a0, h, __uint_as_float(rr.y));
        }
        a0.x += a1.x + a2.x + a3.x;
        a0.y += a1.y + a2.y + a3.y;
        a0.z += a1.z + a2.z + a3.z;
        a0.w += a1.w + a2.w + a3.w;
    } else {
        a0.x = accf[lr * 17 + 4 * q];
        a0.y = accf[lr * 17 + 4 * q + 1];
        a0.z = accf[lr * 17 + 4 * q + 2];
        a0.w = accf[lr * 17 + 4 * q + 3];
    }
    float dg = deg[r];
    int ob = q * 16;
    const float4* bp = reinterpret_cast<const float4*>(&b2s[ob]);
    float4 c0 = bp[0], c1 = bp[1], c2 = bp[2], c3 = bp[3];
    c0.x *= dg; c0.y *= dg; c0.z *= dg; c0.w *= dg;
    c1.x *= dg; c1.y *= dg; c1.z *= dg; c1.w *= dg;
    c2.x *= dg; c2.y *= dg; c2.z *= dg; c2.w *= dg;
    c3.x *= dg; c3.y *= dg; c3.z *= dg; c3.w *= dg;
#pragma unroll
    for (int sq = 0; sq < 4; ++sq) {
        float tv[4];
        tv[0] = __shfl(a0.x, sq, 4);
        tv[1] = __shfl(a0.y, sq, 4);
        tv[2] = __shfl(a0.z, sq, 4);
        tv[3] = __shfl(a0.w, sq, 4);
#pragma unroll
        for (int j = 0; j < 4; ++j) {
            int h = 4 * sq + j;
            const float4* wp = reinterpret_cast<const float4*>(&w2[h * OUT_SIZE + ob]);
            float4 w0 = wp[0], w1 = wp[1], w2v = wp[2], w3 = wp[3];
            float th = tv[j];
            c0.x += th * w0.x; c0.y += th * w0.y; c0.z += th * w0.z; c0.w += th * w0.w;
            c1.x += th * w1.x; c1.y += th * w1.y; c1.z += th * w1.z; c1.w += th * w1.w;
            c2.x += th * w2v.x; c2.y += th * w2v.y; c2.z += th * w2v.z; c2.w += th * w2v.w;
            c3.x += th * w3.x; c3.y += th * w3.y; c3.z += th * w3.z; c3.w += th * w3.w;
        }
    }
    c0.x = fmaxf(c0.x, 0.f); c0.y = fmaxf(c0.y, 0.f); c0.z = fmaxf(c0.z, 0.f); c0.w = fmaxf(c0.w, 0.f);
    c1.x = fmaxf(c1.x, 0.f); c1.y = fmaxf(c1.y, 0.f); c1.z = fmaxf(c1.z, 0.f); c1.w = fmaxf(c1.w, 0.f);
    c2.x = fmaxf(c2.x, 0.f); c2.y = fmaxf(c2.y, 0.f); c2.z = fmaxf(c2.z, 0.f); c2.w = fmaxf(c2.w, 0.f);
    c3.x = fmaxf(c3.x, 0.f); c3.y = fmaxf(c3.y, 0.f); c3.z = fmaxf(c3.z, 0.f); c3.w = fmaxf(c3.w, 0.f);
    float4* op = reinterpret_cast<float4*>(out + (size_t)r * OUT_SIZE + ob);
    op[0] = c0; op[1] = c1; op[2] = c2; op[3] = c3;
}

// ---------------- atomic push spmm (fallback only) ----------------
__global__ __launch_bounds__(256) void spmm16_kernel(
    const int* __restrict__ row, const int* __restrict__ col,
    const float* __restrict__ val, const float* __restrict__ Hin,
    float* __restrict__ Sout, float* __restrict__ deg, long nedges, int relu_in) {
    long t = (long)blockIdx.x * 256 + threadIdx.x;
    long e = t >> 4;
    if (e >= nedges) return;
    int k = (int)(t & 15);
    int r = row[e];
    int c = col[e];
    float v = val[e];
    float x = Hin[(size_t)c * HIDDEN + k];
    if (relu_in) x = fmaxf(x, 0.0f);
    atomicAdd(&Sout[(size_t)r * HIDDEN + k], v * x);
    if (deg != nullptr && k == 0) atomicAdd(&deg[r], v);
}

// ---------------- dense2 (fallback only) ----------------
__global__ __launch_bounds__(256) void dense2_kernel(
    const float* __restrict__ T, const float* __restrict__ deg,
    const float* __restrict__ W2, const float* __restrict__ b2,
    float* __restrict__ out, int n) {
    __shared__ float w[OUT_SIZE * HIDDEN];
    for (int i = threadIdx.x; i < OUT_SIZE * HIDDEN; i += 256) {
        int o = i / HIDDEN;
        int h = i % HIDDEN;
        w[h * OUT_SIZE + o] = W2[i];
    }
    __syncthreads();
    int node = blockIdx.x * 4 + (threadIdx.x >> 6);
    int o = threadIdx.x & 63;
    if (node >= n) return;
    float acc = deg[node] * b2[o];
#pragma unroll
    for (int h = 0; h < HIDDEN; ++h)
        acc += T[(size_t)node * HIDDEN + h] * w[h * OUT_SIZE + o];
    out[(size_t)node * OUT_SIZE + o] = fmaxf(acc, 0.0f);
}

static inline char* align_up(char* p, size_t a) {
    return (char*)(((uintptr_t)p + a - 1) & ~(uintptr_t)(a - 1));
}

extern "C" void kernel_launch(void* const* d_in, const int* in_sizes, int n_in,
                              void* d_out, int out_size, void* d_ws, size_t ws_size,
                              hipStream_t stream) {
    const int*   index = (const int*)d_in[0];
    const float* value = (const float*)d_in[1];
    const float* X     = (const float*)d_in[4];
    const float* W1    = (const float*)d_in[5];
    const float* b1    = (const float*)d_in[6];
    const float* W2    = (const float*)d_in[7];
    const float* b2    = (const float*)d_in[8];
    float* out = (float*)d_out;

    long nedges = in_sizes[1];
    int  n      = in_sizes[4] / IN_SIZE;
    const int* row = index;
    const int* col = index + nedges;

    int nblk = (int)((nedges + EB - 1) / EB);

    size_t need = (size_t)nedges * 8 + (size_t)(NBUCK + 1) * nblk * 4 +
                  (size_t)n * (32 + 32 + 4) + 1024;

    if (ws_size >= need && n <= (NBUCK << BSHIFT) && nblk <= NBLK_MAX) {
        char* p = (char*)d_ws;
        uint2* bin = (uint2*)p;       p += (size_t)nedges * 8;
        int* dirT  = (int*)p;         p += (size_t)(NBUCK + 1) * nblk * 4;
        p = align_up(p, 64);
        __half2* H1h = (__half2*)p;   p += (size_t)n * 32;
        __half2* Ah  = (__half2*)p;   p += (size_t)n * 32;
        float* deg   = (float*)p;

        int ncs = (n + BROWS - 1) >> BSHIFT;

        bin_kernel<<<nblk, BINBLK, 0, stream>>>(row, col, value, bin, dirT, nblk, nedges);
        dense1_half_kernel<<<(n + 63) / 64, 256, 0, stream>>>(X, W1, b1, H1h, n);
        csort_spmm1_kernel<<<ncs, 512, 0, stream>>>(
            bin, dirT, (const uint2*)H1h, Ah, deg, n, nblk);
        spmm2_out_kernel<<<ncs, 512, 0, stream>>>(
            bin, dirT, (const uint2*)Ah, W2, b2, deg, out, n, nblk);
    } else {
        // atomic push fallback (fp32 end-to-end)
        float* ws = (float*)d_ws;
        float* H1  = ws;
        float* S1  = H1 + (size_t)n * HIDDEN;
        float* T   = S1 + (size_t)n * HIDDEN;
        float* deg = T + (size_t)n * HIDDEN;
        zero_int_kernel<<<2048, 256, 0, stream>>>((int*)S1, (long)n * (2 * HIDDEN + 1));
        dense1_kernel<<<(n + 15) / 16, 256, 0, stream>>>(X, W1, b1, H1, n);
        long thr1 = nedges * HIDDEN;
        spmm16_kernel<<<(int)((thr1 + 255) / 256), 256, 0, stream>>>(
            row, col, value, H1, S1, deg, nedges, 0);
        spmm16_kernel<<<(int)((thr1 + 255) / 256), 256, 0, stream>>>(
            row, col, value, S1, T, nullptr, nedges, 1);
        dense2_kernel<<<(n + 3) / 4, 256, 0, stream>>>(T, deg, W2, b2, out, n);
    }
}

// Round 13
// 123.402 us; speedup vs baseline: 7.5556x; 1.0824x over previous
//
#include <hip/hip_runtime.h>
#include <hip/hip_fp16.h>

#define IN_SIZE 256
#define HIDDEN 16
#define OUT_SIZE 64
#define BSHIFT 7            // bucket = row >> 7 (128 rows)
#define BROWS 128
#define NBUCK 1024          // supports n <= 131072
#define EB 8192             // edges per bin block
#define BINBLK 1024
#define EPT 8
#define NBLK_MAX 512        // supports nedges <= 4.19M
#define WSTR 20
#define CAP 4416            // LDS-resident records per 128-row bucket
#define KPT 9               // ceil(CAP/512) records per thread (register-staged)

// ---------------- zero (fallback path) ----------------
__global__ __launch_bounds__(256) void zero_int_kernel(int* __restrict__ a, long n) {
    long i = (long)blockIdx.x * 256 + threadIdx.x;
    long stride = (long)gridDim.x * 256;
    for (; i < n; i += stride) a[i] = 0;
}

// ---------------- H1(fp16) = X @ W1^T + b1  [n,16] ----------------
__global__ __launch_bounds__(256) void dense1_half_kernel(
    const float* __restrict__ X, const float* __restrict__ W1,
    const float* __restrict__ b1, __half2* __restrict__ H1, int n) {
    __shared__ float w[IN_SIZE * WSTR];  // w[k*20+h] = W1[h][k]
    for (int i = threadIdx.x; i < HIDDEN * IN_SIZE; i += 256) {
        int h = i >> 8;
        int k = i & 255;
        w[k * WSTR + h] = W1[i];
    }
    __syncthreads();
    int node = blockIdx.x * 64 + (threadIdx.x >> 2);
    int q = threadIdx.x & 3;
    if (node >= n) return;
    float acc[16];
#pragma unroll
    for (int h = 0; h < 16; ++h) acc[h] = 0.f;
    const float4* xr = reinterpret_cast<const float4*>(X + (size_t)node * IN_SIZE);
#pragma unroll 8
    for (int kk = 0; kk < 16; ++kk) {
        float4 x = xr[q + 4 * kk];
        const float* wr = &w[(kk * 16 + q * 4) * WSTR];
#pragma unroll
        for (int j = 0; j < 4; ++j) {
            float xs = (j == 0) ? x.x : (j == 1) ? x.y : (j == 2) ? x.z : x.w;
            const float* wj = wr + j * WSTR;
#pragma unroll
            for (int h = 0; h < 16; ++h)
                acc[h] += xs * wj[h];
        }
    }
#pragma unroll
    for (int h = 0; h < 16; ++h) {
        acc[h] += __shfl_xor(acc[h], 1, 4);
        acc[h] += __shfl_xor(acc[h], 2, 4);
    }
    const float4 bb = reinterpret_cast<const float4*>(b1)[q];
    int hb = q * 4;
    __half2 o0 = __floats2half2_rn(acc[hb] + bb.x, acc[hb + 1] + bb.y);
    __half2 o1 = __floats2half2_rn(acc[hb + 2] + bb.z, acc[hb + 3] + bb.w);
    uint2 pk;
    pk.x = *reinterpret_cast<unsigned int*>(&o0);
    pk.y = *reinterpret_cast<unsigned int*>(&o1);
    reinterpret_cast<uint2*>(H1)[(size_t)node * 4 + q] = pk;
}

// ---------------- fp32 dense1 (fallback only) ----------------
__global__ __launch_bounds__(256) void dense1_kernel(
    const float* __restrict__ X, const float* __restrict__ W1,
    const float* __restrict__ b1, float* __restrict__ H1, int n) {
    __shared__ float w[HIDDEN * IN_SIZE];
    for (int i = threadIdx.x; i < HIDDEN * IN_SIZE; i += 256) {
        int h = i >> 8;
        int k = i & 255;
        w[k * HIDDEN + h] = W1[i];
    }
    __syncthreads();
    int t = threadIdx.x;
    int node = blockIdx.x * 16 + (t >> 4);
    int h = t & 15;
    if (node >= n) return;
    const float4* xr = reinterpret_cast<const float4*>(X + (size_t)node * IN_SIZE);
    float acc = b1[h];
#pragma unroll 8
    for (int kk = 0; kk < IN_SIZE / 4; ++kk) {
        float4 x = xr[kk];
        const float* wr = &w[(kk * 4) * HIDDEN + h];
        acc += x.x * wr[0] + x.y * wr[HIDDEN] + x.z * wr[2 * HIDDEN] + x.w * wr[3 * HIDDEN];
    }
    H1[(size_t)node * HIDDEN + h] = acc;
}

// ---------------- bin: block-major bucket sort + directory ----------------
__global__ __launch_bounds__(BINBLK) void bin_kernel(
    const int* __restrict__ row, const int* __restrict__ col,
    const float* __restrict__ val, uint2* __restrict__ bin,
    int* __restrict__ dirT, int nblk, long nedges) {
    __shared__ int hist[NBUCK];
    __shared__ int lbase[NBUCK];
    __shared__ int s[BINBLK];
    __shared__ unsigned int staged[EB * 2];   // 64 KB
    int blk = blockIdx.x, tid = threadIdx.x;
    long base = (long)blk * EB;
    int ecount = (int)(((nedges - base) < (long)EB) ? (nedges - base) : (long)EB);
    hist[tid] = 0;
    __syncthreads();
    unsigned int meta[EPT], cc[EPT], vv[EPT];
    if (ecount == EB) {
        long e8 = base + (long)tid * EPT;
        int4 ra = *reinterpret_cast<const int4*>(row + e8);
        int4 rb = *reinterpret_cast<const int4*>(row + e8 + 4);
        int4 ca = *reinterpret_cast<const int4*>(col + e8);
        int4 cb = *reinterpret_cast<const int4*>(col + e8 + 4);
        float4 va = *reinterpret_cast<const float4*>(val + e8);
        float4 vb = *reinterpret_cast<const float4*>(val + e8 + 4);
        int rr[8] = {ra.x, ra.y, ra.z, ra.w, rb.x, rb.y, rb.z, rb.w};
        int cr[8] = {ca.x, ca.y, ca.z, ca.w, cb.x, cb.y, cb.z, cb.w};
        float vr[8] = {va.x, va.y, va.z, va.w, vb.x, vb.y, vb.z, vb.w};
#pragma unroll
        for (int i = 0; i < EPT; ++i) {
            int r = rr[i];
            int bb = r >> BSHIFT;
            int slot = atomicAdd(&hist[bb], 1);
            meta[i] = ((unsigned int)(r & (BROWS - 1)) << 25) |
                      ((unsigned int)bb << 13) | (unsigned int)slot;
            cc[i] = (unsigned int)cr[i];
            vv[i] = __float_as_uint(vr[i]);
        }
    } else {
#pragma unroll
        for (int i = 0; i < EPT; ++i) {
            int k = tid * EPT + i;
            meta[i] = 0xFFFFFFFFu;
            if (k < ecount) {
                int r = row[base + k];
                cc[i] = (unsigned int)col[base + k];
                vv[i] = __float_as_uint(val[base + k]);
                int bb = r >> BSHIFT;
                int slot = atomicAdd(&hist[bb], 1);
                meta[i] = ((unsigned int)(r & (BROWS - 1)) << 25) |
                          ((unsigned int)bb << 13) | (unsigned int)slot;
            }
        }
    }
    __syncthreads();
    int x = hist[tid];
    s[tid] = x;
    __syncthreads();
    for (int off = 1; off < BINBLK; off <<= 1) {
        int t = (tid >= off) ? s[tid - off] : 0;
        __syncthreads();
        s[tid] += t;
        __syncthreads();
    }
    lbase[tid] = s[tid] - x;
    __syncthreads();
    for (int i = tid; i <= NBUCK; i += BINBLK)
        dirT[(size_t)i * nblk + blk] = (i < NBUCK) ? lbase[i] : ecount;
#pragma unroll
    for (int i = 0; i < EPT; ++i) {
        if (meta[i] != 0xFFFFFFFFu) {
            int bb = (meta[i] >> 13) & 0x3FF;
            int p = lbase[bb] + (int)(meta[i] & 0x1FFF);
            staged[2 * p]     = ((meta[i] >> 25) << 24) | cc[i];
            staged[2 * p + 1] = vv[i];
        }
    }
    __syncthreads();
    for (int j = tid; j < ecount; j += BINBLK)
        bin[base + j] = make_uint2(staged[2 * j], staged[2 * j + 1]);
}

// ---------------- shared helpers ----------------
__device__ __forceinline__ int bsearch_pfx(const int* pfx, int p) {
    int lo = 0;
#pragma unroll
    for (int sh = 8; sh >= 0; --sh) {
        int mid = lo + (1 << sh);
        if (mid < NBLK_MAX && pfx[mid] <= p) lo = mid;
    }
    return lo;
}

__device__ __forceinline__ void fma_h(float4& a, uint2 h, float v) {
    __half2 lo = *reinterpret_cast<const __half2*>(&h.x);
    __half2 hi = *reinterpret_cast<const __half2*>(&h.y);
    float2 f0 = __half22float2(lo), f1 = __half22float2(hi);
    a.x += v * f0.x; a.y += v * f0.y; a.z += v * f1.x; a.w += v * f1.y;
}

// ---------------- fused dir-gather + reg-staged sort + spmm1 ---------------
// Ah = relu(spmm(H1h)) fp16, deg. Also exports sorted records (epackS) +
// per-row (sbase,cnt) (mcnt) + m (minfo) so pass 2 can skip the sort.
__global__ __launch_bounds__(512) void csort_spmm1_kernel(
    const uint2* __restrict__ bin, const int* __restrict__ dirT,
    const uint2* __restrict__ Hin, __half2* __restrict__ Ah,
    float* __restrict__ deg, uint2* __restrict__ epackS,
    unsigned int* __restrict__ mcnt, int* __restrict__ minfo,
    int n, int nblk) {
    __shared__ int gs[NBLK_MAX];
    __shared__ unsigned short rl[NBLK_MAX];
    __shared__ int pfx[NBLK_MAX];
    __shared__ int s[NBLK_MAX];
    __shared__ int cnt[BROWS], sbase[BROWS];
    __shared__ float dacc[BROWS];
    __shared__ int mTot;
    __shared__ uint2 eld[CAP];
    int d = blockIdx.x, tid = threadIdx.x;
    if (tid < nblk) {
        int a = dirT[(size_t)d * nblk + tid];
        int b = dirT[(size_t)(d + 1) * nblk + tid];
        gs[tid] = tid * EB + a;
        rl[tid] = (unsigned short)(b - a);
    } else { gs[tid] = 0; rl[tid] = 0; }
    __syncthreads();
    int x = (int)rl[tid];
    s[tid] = x;
    __syncthreads();
    for (int off = 1; off < NBLK_MAX; off <<= 1) {
        int t = (tid >= off) ? s[tid - off] : 0;
        __syncthreads();
        s[tid] += t;
        __syncthreads();
    }
    pfx[tid] = s[tid] - x;
    if (tid == NBLK_MAX - 1) mTot = s[NBLK_MAX - 1];
    if (tid < BROWS) { cnt[tid] = 0; dacc[tid] = 0.f; }
    __syncthreads();
    int m = mTot;
    bool fits = (m <= CAP);
    if (tid == 0) minfo[d] = m;
    float* accf = (float*)eld;  // overflow accumulator overlay
    if (fits) {
        // pass A: single read -> registers; reserve slot per row
        uint2 regs[KPT];
        unsigned short slot_[KPT];
        unsigned char lr_[KPT];
#pragma unroll
        for (int k = 0; k < KPT; ++k) {
            int p = tid + k * 512;
            if (p < m) {
                int blk = bsearch_pfx(pfx, p);
                uint2 rec = bin[(size_t)gs[blk] + (p - pfx[blk])];
                int lr = rec.x >> 24;
                regs[k] = make_uint2(rec.x & 0xFFFFFF, rec.y);
                slot_[k] = (unsigned short)atomicAdd(&cnt[lr], 1);
                lr_[k] = (unsigned char)lr;
            }
        }
        __syncthreads();
        int cx = (tid < BROWS) ? cnt[tid] : 0;
        if (tid < BROWS) s[tid] = cx;
        __syncthreads();
        for (int off = 1; off < BROWS; off <<= 1) {
            int t = (tid >= off && tid < BROWS) ? s[tid - off] : 0;
            __syncthreads();
            if (tid < BROWS) s[tid] += t;
            __syncthreads();
        }
        if (tid < BROWS) {
            int sb = s[tid] - cx;
            sbase[tid] = sb;
            mcnt[(size_t)d * BROWS + tid] =
                ((unsigned int)sb << 16) | (unsigned int)cx;
        }
        __syncthreads();
        // pass B: write sorted from registers
#pragma unroll
        for (int k = 0; k < KPT; ++k) {
            int p = tid + k * 512;
            if (p < m) eld[sbase[lr_[k]] + slot_[k]] = regs[k];
        }
        __syncthreads();
        // export sorted records for pass 2 (coalesced stream write)
        uint2* eg = epackS + (size_t)d * CAP;
        for (int j = tid; j < m; j += 512) eg[j] = eld[j];
    } else {
        for (int i = tid; i < BROWS * 17; i += 512) accf[i] = 0.f;
        __syncthreads();
        for (int p = tid; p < m; p += 512) {
            int blk = bsearch_pfx(pfx, p);
            uint2 rec = bin[(size_t)gs[blk] + (p - pfx[blk])];
            int lr = rec.x >> 24;
            int c = rec.x & 0xFFFFFF;
            float v = __uint_as_float(rec.y);
            const __half2* hp = reinterpret_cast<const __half2*>(Hin + (size_t)c * 4);
#pragma unroll
            for (int j = 0; j < 8; ++j) {
                float2 f = __half22float2(hp[j]);
                atomicAdd(&accf[lr * 17 + 2 * j], v * f.x);
                atomicAdd(&accf[lr * 17 + 2 * j + 1], v * f.y);
            }
            atomicAdd(&dacc[lr], v);
        }
        __syncthreads();
    }
    // spmm: one 4-lane quad per row
    int lr = tid >> 2, q = tid & 3;
    int r = (d << BSHIFT) + lr;
    if (r >= n) return;
    float4 a0 = {0,0,0,0};
    float dg = 0.f;
    if (fits) {
        float4 a1 = {0,0,0,0}, a2 = {0,0,0,0}, a3 = {0,0,0,0};
        int e = sbase[lr], e1 = e + cnt[lr];
        for (; e + 4 <= e1; e += 4) {
            uint2 r0 = eld[e], r1 = eld[e + 1], r2 = eld[e + 2], r3 = eld[e + 3];
            uint2 h0 = Hin[(size_t)r0.x * 4 + q];
            uint2 h1 = Hin[(size_t)r1.x * 4 + q];
            uint2 h2 = Hin[(size_t)r2.x * 4 + q];
            uint2 h3 = Hin[(size_t)r3.x * 4 + q];
            float v0 = __uint_as_float(r0.y), v1 = __uint_as_float(r1.y);
            float v2 = __uint_as_float(r2.y), v3 = __uint_as_float(r3.y);
            fma_h(a0, h0, v0); fma_h(a1, h1, v1);
            fma_h(a2, h2, v2); fma_h(a3, h3, v3);
            dg += v0 + v1 + v2 + v3;
        }
        for (; e < e1; ++e) {
            uint2 rr = eld[e];
            uint2 h = Hin[(size_t)rr.x * 4 + q];
            float v = __uint_as_float(rr.y);
            fma_h(a0, h, v);
            dg += v;
        }
        a0.x += a1.x + a2.x + a3.x;
        a0.y += a1.y + a2.y + a3.y;
        a0.z += a1.z + a2.z + a3.z;
        a0.w += a1.w + a2.w + a3.w;
    } else {
        a0.x = accf[lr * 17 + 4 * q];
        a0.y = accf[lr * 17 + 4 * q + 1];
        a0.z = accf[lr * 17 + 4 * q + 2];
        a0.w = accf[lr * 17 + 4 * q + 3];
        dg = dacc[lr];
    }
    a0.x = fmaxf(a0.x, 0.f); a0.y = fmaxf(a0.y, 0.f);
    a0.z = fmaxf(a0.z, 0.f); a0.w = fmaxf(a0.w, 0.f);
    __half2 o0 = __floats2half2_rn(a0.x, a0.y);
    __half2 o1 = __floats2half2_rn(a0.z, a0.w);
    uint2 pk;
    pk.x = *reinterpret_cast<unsigned int*>(&o0);
    pk.y = *reinterpret_cast<unsigned int*>(&o1);
    reinterpret_cast<uint2*>(Ah)[(size_t)r * 4 + q] = pk;
    if (q == 0) deg[r] = dg;
}

// ---------------- fused spmm2 + dense2 (sort-free fits path) ---------------
// out = relu(spmm(Ah) @ W2^T + deg*b2); reads pre-sorted epackS from pass 1.
__global__ __launch_bounds__(512) void spmm2_out_kernel(
    const uint2* __restrict__ bin, const int* __restrict__ dirT,
    const uint2* __restrict__ epackS, const unsigned int* __restrict__ mcnt,
    const int* __restrict__ minfo, const uint2* __restrict__ Hin,
    const float* __restrict__ W2, const float* __restrict__ b2,
    const float* __restrict__ deg, float* __restrict__ out,
    int n, int nblk) {
    __shared__ int gs[NBLK_MAX];
    __shared__ unsigned short rl[NBLK_MAX];
    __shared__ int pfx[NBLK_MAX];
    __shared__ int s[NBLK_MAX];
    __shared__ int cnt[BROWS], sbase[BROWS];
    __shared__ int sh_m;
    __shared__ float w2[HIDDEN * OUT_SIZE];
    __shared__ float b2s[OUT_SIZE];
    __shared__ uint2 eld[CAP];
    int d = blockIdx.x, tid = threadIdx.x;
    for (int i = tid; i < HIDDEN * OUT_SIZE; i += 512)
        w2[(i & 15) * OUT_SIZE + (i >> 4)] = W2[i];
    if (tid < OUT_SIZE) b2s[tid] = b2[tid];
    if (tid == 0) sh_m = minfo[d];
    __syncthreads();
    int m = sh_m;
    bool fits = (m <= CAP);
    float* accf = (float*)eld;
    if (fits) {
        // sort-free: per-row (sbase,cnt) + contiguous sorted records
        if (tid < BROWS) {
            unsigned int mc = mcnt[(size_t)d * BROWS + tid];
            sbase[tid] = (int)(mc >> 16);
            cnt[tid] = (int)(mc & 0xFFFF);
        }
        const uint2* eg = epackS + (size_t)d * CAP;
        for (int j = tid; j < m; j += 512) eld[j] = eg[j];
        __syncthreads();
    } else {
        // overflow: re-gather via directory, LDS-atomic accumulate
        if (tid < nblk) {
            int a = dirT[(size_t)d * nblk + tid];
            int b = dirT[(size_t)(d + 1) * nblk + tid];
            gs[tid] = tid * EB + a;
            rl[tid] = (unsigned short)(b - a);
        } else { gs[tid] = 0; rl[tid] = 0; }
        __syncthreads();
        int x = (int)rl[tid];
        s[tid] = x;
        __syncthreads();
        for (int off = 1; off < NBLK_MAX; off <<= 1) {
            int t = (tid >= off) ? s[tid - off] : 0;
            __syncthreads();
            s[tid] += t;
            __syncthreads();
        }
        pfx[tid] = s[tid] - x;
        __syncthreads();
        for (int i = tid; i < BROWS * 17; i += 512) accf[i] = 0.f;
        __syncthreads();
        for (int p = tid; p < m; p += 512) {
            int blk = bsearch_pfx(pfx, p);
            uint2 rec = bin[(size_t)gs[blk] + (p - pfx[blk])];
            int lr = rec.x >> 24;
            int c = rec.x & 0xFFFFFF;
            float v = __uint_as_float(rec.y);
            const __half2* hp = reinterpret_cast<const __half2*>(Hin + (size_t)c * 4);
#pragma unroll
            for (int j = 0; j < 8; ++j) {
                float2 f = __half22float2(hp[j]);
                atomicAdd(&accf[lr * 17 + 2 * j], v * f.x);
                atomicAdd(&accf[lr * 17 + 2 * j + 1], v * f.y);
            }
        }
        __syncthreads();
    }
    int lr = tid >> 2, q = tid & 3;
    int r = (d << BSHIFT) + lr;
    if (r >= n) return;
    float4 a0 = {0,0,0,0};
    if (fits) {
        float4 a1 = {0,0,0,0}, a2 = {0,0,0,0}, a3 = {0,0,0,0};
        int e = sbase[lr], e1 = e + cnt[lr];
        for (; e + 4 <= e1; e += 4) {
            uint2 r0 = eld[e], r1 = eld[e + 1], r2 = eld[e + 2], r3 = eld[e + 3];
            uint2 h0 = Hin[(size_t)r0.x * 4 + q];
            uint2 h1 = Hin[(size_t)r1.x * 4 + q];
            uint2 h2 = Hin[(size_t)r2.x * 4 + q];
            uint2 h3 = Hin[(size_t)r3.x * 4 + q];
            fma_h(a0, h0, __uint_as_float(r0.y));
            fma_h(a1, h1, __uint_as_float(r1.y));
            fma_h(a2, h2, __uint_as_float(r2.y));
            fma_h(a3, h3, __uint_as_float(r3.y));
        }
        for (; e < e1; ++e) {
            uint2 rr = eld[e];
            uint2 h = Hin[(size_t)rr.x * 4 + q];
            fma_h(a0, h, __uint_as_float(rr.y));
        }
        a0.x += a1.x + a2.x + a3.x;
        a0.y += a1.y + a2.y + a3.y;
        a0.z += a1.z + a2.z + a3.z;
        a0.w += a1.w + a2.w + a3.w;
    } else {
        a0.x = accf[lr * 17 + 4 * q];
        a0.y = accf[lr * 17 + 4 * q + 1];
        a0.z = accf[lr * 17 + 4 * q + 2];
        a0.w = accf[lr * 17 + 4 * q + 3];
    }
    float dg = deg[r];
    int ob = q * 16;
    const float4* bp = reinterpret_cast<const float4*>(&b2s[ob]);
    float4 c0 = bp[0], c1 = bp[1], c2 = bp[2], c3 = bp[3];
    c0.x *= dg; c0.y *= dg; c0.z *= dg; c0.w *= dg;
    c1.x *= dg; c1.y *= dg; c1.z *= dg; c1.w *= dg;
    c2.x *= dg; c2.y *= dg; c2.z *= dg; c2.w *= dg;
    c3.x *= dg; c3.y *= dg; c3.z *= dg; c3.w *= dg;
#pragma unroll
    for (int sq = 0; sq < 4; ++sq) {
        float tv[4];
        tv[0] = __shfl(a0.x, sq, 4);
        tv[1] = __shfl(a0.y, sq, 4);
        tv[2] = __shfl(a0.z, sq, 4);
        tv[3] = __shfl(a0.w, sq, 4);
#pragma unroll
        for (int j = 0; j < 4; ++j) {
            int h = 4 * sq + j;
            const float4* wp = reinterpret_cast<const float4*>(&w2[h * OUT_SIZE + ob]);
            float4 w0 = wp[0], w1 = wp[1], w2v = wp[2], w3 = wp[3];
            float th = tv[j];
            c0.x += th * w0.x; c0.y += th * w0.y; c0.z += th * w0.z; c0.w += th * w0.w;
            c1.x += th * w1.x; c1.y += th * w1.y; c1.z += th * w1.z; c1.w += th * w1.w;
            c2.x += th * w2v.x; c2.y += th * w2v.y; c2.z += th * w2v.z; c2.w += th * w2v.w;
            c3.x += th * w3.x; c3.y += th * w3.y; c3.z += th * w3.z; c3.w += th * w3.w;
        }
    }
    c0.x = fmaxf(c0.x, 0.f); c0.y = fmaxf(c0.y, 0.f); c0.z = fmaxf(c0.z, 0.f); c0.w = fmaxf(c0.w, 0.f);
    c1.x = fmaxf(c1.x, 0.f); c1.y = fmaxf(c1.y, 0.f); c1.z = fmaxf(c1.z, 0.f); c1.w = fmaxf(c1.w, 0.f);
    c2.x = fmaxf(c2.x, 0.f); c2.y = fmaxf(c2.y, 0.f); c2.z = fmaxf(c2.z, 0.f); c2.w = fmaxf(c2.w, 0.f);
    c3.x = fmaxf(c3.x, 0.f); c3.y = fmaxf(c3.y, 0.f); c3.z = fmaxf(c3.z, 0.f); c3.w = fmaxf(c3.w, 0.f);
    float4* op = reinterpret_cast<float4*>(out + (size_t)r * OUT_SIZE + ob);
    op[0] = c0; op[1] = c1; op[2] = c2; op[3] = c3;
}

// ---------------- atomic push spmm (fallback only) ----------------
__global__ __launch_bounds__(256) void spmm16_kernel(
    const int* __restrict__ row, const int* __restrict__ col,
    const float* __restrict__ val, const float* __restrict__ Hin,
    float* __restrict__ Sout, float* __restrict__ deg, long nedges, int relu_in) {
    long t = (long)blockIdx.x * 256 + threadIdx.x;
    long e = t >> 4;
    if (e >= nedges) return;
    int k = (int)(t & 15);
    int r = row[e];
    int c = col[e];
    float v = val[e];
    float x = Hin[(size_t)c * HIDDEN + k];
    if (relu_in) x = fmaxf(x, 0.0f);
    atomicAdd(&Sout[(size_t)r * HIDDEN + k], v * x);
    if (deg != nullptr && k == 0) atomicAdd(&deg[r], v);
}

// ---------------- dense2 (fallback only) ----------------
__global__ __launch_bounds__(256) void dense2_kernel(
    const float* __restrict__ T, const float* __restrict__ deg,
    const float* __restrict__ W2, const float* __restrict__ b2,
    float* __restrict__ out, int n) {
    __shared__ float w[OUT_SIZE * HIDDEN];
    for (int i = threadIdx.x; i < OUT_SIZE * HIDDEN; i += 256) {
        int o = i / HIDDEN;
        int h = i % HIDDEN;
        w[h * OUT_SIZE + o] = W2[i];
    }
    __syncthreads();
    int node = blockIdx.x * 4 + (threadIdx.x >> 6);
    int o = threadIdx.x & 63;
    if (node >= n) return;
    float acc = deg[node] * b2[o];
#pragma unroll
    for (int h = 0; h < HIDDEN; ++h)
        acc += T[(size_t)node * HIDDEN + h] * w[h * OUT_SIZE + o];
    out[(size_t)node * OUT_SIZE + o] = fmaxf(acc, 0.0f);
}

static inline char* align_up(char* p, size_t a) {
    return (char*)(((uintptr_t)p + a - 1) & ~(uintptr_t)(a - 1));
}

extern "C" void kernel_launch(void* const* d_in, const int* in_sizes, int n_in,
                              void* d_out, int out_size, void* d_ws, size_t ws_size,
                              hipStream_t stream) {
    const int*   index = (const int*)d_in[0];
    const float* value = (const float*)d_in[1];
    const float* X     = (const float*)d_in[4];
    const float* W1    = (const float*)d_in[5];
    const float* b1    = (const float*)d_in[6];
    const float* W2    = (const float*)d_in[7];
    const float* b2    = (const float*)d_in[8];
    float* out = (float*)d_out;

    long nedges = in_sizes[1];
    int  n      = in_sizes[4] / IN_SIZE;
    const int* row = index;
    const int* col = index + nedges;

    int nblk = (int)((nedges + EB - 1) / EB);
    int ncs  = (n + BROWS - 1) >> BSHIFT;

    // ws: bin | dirT | epackS[ncs*CAP u2] | mcnt[ncs*128] | minfo[ncs] |
    //     H1h | Ah | deg
    size_t need = (size_t)nedges * 8 + (size_t)(NBUCK + 1) * nblk * 4 +
                  (size_t)ncs * CAP * 8 + (size_t)ncs * BROWS * 4 +
                  (size_t)ncs * 4 + (size_t)n * (32 + 32 + 4) + 1024;

    if (ws_size >= need && n <= (NBUCK << BSHIFT) && nblk <= NBLK_MAX) {
        char* p = (char*)d_ws;
        uint2* bin = (uint2*)p;       p += (size_t)nedges * 8;
        int* dirT  = (int*)p;         p += (size_t)(NBUCK + 1) * nblk * 4;
        uint2* epackS = (uint2*)p;    p += (size_t)ncs * CAP * 8;
        unsigned int* mcnt = (unsigned int*)p;  p += (size_t)ncs * BROWS * 4;
        int* minfo = (int*)p;         p += (size_t)ncs * 4;
        p = align_up(p, 64);
        __half2* H1h = (__half2*)p;   p += (size_t)n * 32;
        __half2* Ah  = (__half2*)p;   p += (size_t)n * 32;
        float* deg   = (float*)p;

        bin_kernel<<<nblk, BINBLK, 0, stream>>>(row, col, value, bin, dirT, nblk, nedges);
        dense1_half_kernel<<<(n + 63) / 64, 256, 0, stream>>>(X, W1, b1, H1h, n);
        csort_spmm1_kernel<<<ncs, 512, 0, stream>>>(
            bin, dirT, (const uint2*)H1h, Ah, deg, epackS, mcnt, minfo, n, nblk);
        spmm2_out_kernel<<<ncs, 512, 0, stream>>>(
            bin, dirT, epackS, mcnt, minfo, (const uint2*)Ah, W2, b2, deg,
            out, n, nblk);
    } else {
        // atomic push fallback (fp32 end-to-end)
        float* ws = (float*)d_ws;
        float* H1  = ws;
        float* S1  = H1 + (size_t)n * HIDDEN;
        float* T   = S1 + (size_t)n * HIDDEN;
        float* deg = T + (size_t)n * HIDDEN;
        zero_int_kernel<<<2048, 256, 0, stream>>>((int*)S1, (long)n * (2 * HIDDEN + 1));
        dense1_kernel<<<(n + 15) / 16, 256, 0, stream>>>(X, W1, b1, H1, n);
        long thr1 = nedges * HIDDEN;
        spmm16_kernel<<<(int)((thr1 + 255) / 256), 256, 0, stream>>>(
            row, col, value, H1, S1, deg, nedges, 0);
        spmm16_kernel<<<(int)((thr1 + 255) / 256), 256, 0, stream>>>(
            row, col, value, S1, T, nullptr, nedges, 1);
        dense2_kernel<<<(n + 3) / 4, 256, 0, stream>>>(T, deg, W2, b2, out, n);
    }
}